// Round 13
// baseline (465.391 us; speedup 1.0000x reference)
//
#include <hip/hip_runtime.h>
#include <hip/hip_fp16.h>

#define LB __launch_bounds__(256)

typedef unsigned short u16;
typedef unsigned int   u32;
typedef __attribute__((ext_vector_type(8))) short bf16x8;   // 8 bf16 (4 VGPRs)
typedef __attribute__((ext_vector_type(4))) float f32x4;
typedef __attribute__((ext_vector_type(8))) u16  u16x8;

__device__ __forceinline__ u16 f2b(float f) {
    u32 u = __float_as_uint(f);
    u32 r = (u + 0x7fffu + ((u >> 16) & 1u)) >> 16;
    return (u16)r;
}
__device__ __forceinline__ float b2f(u16 h) {
    return __uint_as_float((u32)h << 16);
}

#define QSCALE 0.17677669529663687f

// ---------------------------------------------------------------------------
// B=2 N=256 C=256 HF=WF=64 ROI=15(225) HID=256 HEADS=8 Dh=32 DEPTH=3 FFN=1024
// NQ=16 -> seqs S=512, MT=8192. Linearity: K = sample(imgP@Wk^T) + ckv.
// Cross-attn (one block per seq,head), all-MFMA with fused Q-projection:
//   Q' = tgt@(s*Wq)^T + s*bq (16 mfma, k-split 4 waves) -> QT=Q'@Tk ->
//   S=QT@W^T -> shuffle-softmax -> PW=P@W (col16=rowsum carries cv) ->
//   O=PW@Tv^T.  Softmax scale folded into Wq/bq (exact).
// KV projections for all 3 layers hoisted into ONE N=1536 GEMM upfront.
// ---------------------------------------------------------------------------

// ---------- fused prep: mask detect + per-layer ck/cv + scaled bq ----------
__global__ void k_prep(const unsigned char* __restrict__ m, int* __restrict__ valid,
                       const float* __restrict__ pb,
                       const float* __restrict__ cqkv_w,
                       const float* __restrict__ cqkv_b,
                       float* __restrict__ ckv)
{
    if (blockIdx.x == 0) {
        __shared__ int flag;
        if (threadIdx.x == 0) flag = 0;
        __syncthreads();
        int loc = 0;
        for (int off = threadIdx.x; off < 512; off += 256)
            if ((off & 3) != 0 && m[off] != 0) loc = 1;
        if (loc) atomicOr(&flag, 1);
        __syncthreads();
        const bool bytelay = (flag != 0);
        for (int s = threadIdx.x; s < 512; s += 256)
            valid[s] = bytelay ? (int)(m[s] != 0) : (int)(((const int*)m)[s] != 0);
    } else {
        const int l = blockIdx.x - 1;   // 0..2
        const float* Wk = cqkv_w + (size_t)l * 196608 + 65536;
        const float* Wv = cqkv_w + (size_t)l * 196608 + 131072;
        const float* kb = cqkv_b + (size_t)l * 768 + 256;
        const float* vb = cqkv_b + (size_t)l * 768 + 512;
        const int o = threadIdx.x;
        float a = 0.f, c = 0.f;
        for (int cc = 0; cc < 256; cc += 4) {
            const float4 p4 = *(const float4*)(pb + cc);
            const float4 k4 = *(const float4*)(Wk + (size_t)o * 256 + cc);
            const float4 v4 = *(const float4*)(Wv + (size_t)o * 256 + cc);
            a += p4.x * k4.x + p4.y * k4.y + p4.z * k4.z + p4.w * k4.w;
            c += p4.x * v4.x + p4.y * v4.y + p4.z * v4.z + p4.w * v4.w;
        }
        ckv[l * 768 + o]       = a + kb[o];
        ckv[l * 768 + 256 + o] = c + vb[o];
        ckv[l * 768 + 512 + o] = cqkv_b[(size_t)l * 768 + o] * QSCALE;  // s*bq
    }
}

// ---------- weights fp32 -> bf16 arena (+ repack; Wq rows pre-scaled) ------
__global__ LB void k_wconv(const float* __restrict__ s0, const float* __restrict__ s1,
                           const float* __restrict__ s2, const float* __restrict__ s3,
                           const float* __restrict__ s4, const float* __restrict__ s5,
                           const float* __restrict__ s6, u16* __restrict__ dst)
{
    const int e = blockIdx.x * 256 + threadIdx.x;
    if (e >= 3604480) return;
    float v;
    int i = e;
    if (i < 65536) v = s0[i];
    else if ((i -= 65536) < 589824) v = s1[i];
    else if ((i -= 589824) < 196608) v = s2[i];
    else if ((i -= 196608) < 589824) {
        // cross_qkv: scale the Wq rows (row<256 of each layer) by QSCALE
        const int l = i / 196608;
        const int r = (i - l * 196608) >> 8;
        v = s3[i];
        if (r < 256) v *= QSCALE;
    }
    else if ((i -= 589824) < 196608) v = s4[i];
    else if ((i -= 196608) < 786432) v = s5[i];
    else if ((i -= 786432) < 786432) v = s6[i];
    else {  // wCKV3: [l][512 rows (Wk|Wv)][256] contiguous (unscaled)
        i -= 786432;
        const int l = i / 131072;
        const int r = (i - l * 131072) >> 8;
        const int c = i & 255;
        v = s3[(size_t)l * 196608 + (size_t)(256 + r) * 256 + c];
    }
    dst[e] = f2b(v);
}

// ---------- transpose image (B,C,64,64) -> (B,4096,C) bf16 -----------------
__global__ LB void k_transpose(const float* __restrict__ img, u16* __restrict__ imgTb)
{
    __shared__ float tile[64][65];
    const int b  = blockIdx.z;
    const int c0 = blockIdx.y * 64;
    const int p0 = blockIdx.x * 64;
    const int t  = threadIdx.x;
    const int tr = t >> 6, tc = t & 63;
#pragma unroll
    for (int p = 0; p < 16; ++p) {
        const int i = p * 4 + tr;
        tile[i][tc] = img[((size_t)(b * 256 + c0 + i)) * 4096 + p0 + tc];
    }
    __syncthreads();
#pragma unroll
    for (int p = 0; p < 16; ++p) {
        const int jj = p * 4 + tr;
        imgTb[((size_t)(b * 4096 + p0 + jj)) * 256 + c0 + tc] = f2b(tile[tc][jj]);
    }
}

// ---------- bf16 MFMA GEMM: C[M,N] = A[M,K](bf16) @ W[N,K](bf16)^T + bias --
template<int BM>
__global__ LB void gemm_mfma(const u16* __restrict__ A, const u16* __restrict__ W,
                             const float* __restrict__ bias,
                             float* __restrict__ Cf, u16* __restrict__ Cb,
                             int M, int N, int K, int relu)
{
    constexpr int BN = 128;
    __shared__ u16 lds[2][(BM + BN) * 64];
    const int t = threadIdx.x;
    const int wid = t >> 6, lane = t & 63;
    const int bm = blockIdx.y * BM, bn = blockIdx.x * BN;
    const int KT = K >> 6;

    auto stage = [&](int buf, int kt) {
        const int k0 = kt * 64;
        const int rr = t >> 3;
        const int u  = t & 7;
#pragma unroll
        for (int q = 0; q < BM / 32; ++q) {
            const int r = q * 32 + rr;
            const u16* src = A + (size_t)(bm + r) * K + k0 + ((u ^ (r & 7)) << 3);
            __builtin_amdgcn_global_load_lds(
                (const __attribute__((address_space(1))) void*)src,
                (__attribute__((address_space(3))) void*)&lds[buf][q * 2048 + wid * 512],
                16, 0, 0);
        }
#pragma unroll
        for (int q = 0; q < 4; ++q) {
            const int r = q * 32 + rr;
            const u16* src = W + (size_t)(bn + r) * K + k0 + ((u ^ (r & 7)) << 3);
            __builtin_amdgcn_global_load_lds(
                (const __attribute__((address_space(1))) void*)src,
                (__attribute__((address_space(3))) void*)&lds[buf][BM * 64 + q * 2048 + wid * 512],
                16, 0, 0);
        }
    };

    const int wr = wid >> 1, wc = wid & 1;
    constexpr int MR = BM / 32;
    f32x4 acc[MR][4];
    const f32x4 z = {0.f, 0.f, 0.f, 0.f};
#pragma unroll
    for (int mi = 0; mi < MR; ++mi)
#pragma unroll
        for (int ni = 0; ni < 4; ++ni) acc[mi][ni] = z;

    const int r16 = lane & 15, kg = lane >> 4;

    stage(0, 0);
    int cur = 0;
    for (int kt = 0; kt < KT; ++kt) {
        asm volatile("s_waitcnt vmcnt(0)" ::: "memory");
        __syncthreads();
        if (kt + 1 < KT) stage(cur ^ 1, kt + 1);
        const u16* pA = lds[cur];
        const u16* pB = lds[cur] + BM * 64;
#pragma unroll
        for (int kk = 0; kk < 2; ++kk) {
            const int s = kk * 4 + kg;
            bf16x8 afr[MR], bfr[4];
#pragma unroll
            for (int mi = 0; mi < MR; ++mi) {
                const int r = wr * (BM / 2) + mi * 16 + r16;
                afr[mi] = *(const bf16x8*)(pA + r * 64 + ((s ^ (r & 7)) << 3));
            }
#pragma unroll
            for (int ni = 0; ni < 4; ++ni) {
                const int c = wc * 64 + ni * 16 + r16;
                bfr[ni] = *(const bf16x8*)(pB + c * 64 + ((s ^ (c & 7)) << 3));
            }
#pragma unroll
            for (int mi = 0; mi < MR; ++mi)
#pragma unroll
                for (int ni = 0; ni < 4; ++ni)
                    acc[mi][ni] = __builtin_amdgcn_mfma_f32_16x16x32_bf16(
                        afr[mi], bfr[ni], acc[mi][ni], 0, 0, 0);
        }
        cur ^= 1;
    }

#pragma unroll
    for (int mi = 0; mi < MR; ++mi) {
#pragma unroll
        for (int ni = 0; ni < 4; ++ni) {
            const int col = bn + wc * 64 + ni * 16 + r16;
            const float bs = bias ? bias[col] : 0.0f;
#pragma unroll
            for (int rg = 0; rg < 4; ++rg) {
                const int row = bm + wr * (BM / 2) + mi * 16 + kg * 4 + rg;
                float v = acc[mi][ni][rg] + bs;
                if (relu) v = fmaxf(v, 0.0f);
                if (Cf) Cf[(size_t)row * N + col] = v;
                if (Cb) Cb[(size_t)row * N + col] = f2b(v);
            }
        }
    }
}

// ---------- init tgt (fp32 + bf16) -----------------------------------------
__global__ LB void k_init_tgt(float* __restrict__ tgt, u16* __restrict__ tgtb,
                              const float* __restrict__ qe)
{
    const int e = blockIdx.x * 256 + threadIdx.x;
    const int c = e & 255;
    const int row = e >> 8;
    const int i = row & 15;
    const float v = qe[(i << 8) | c];
    tgt[e] = v;
    tgtb[e] = f2b(v);
}

// ---------- self attention: per (seq, head), 16q x 16k, Dh=32; bf16 in/out -
__global__ LB void k_self_attn(const u16* __restrict__ QKV, u16* __restrict__ O)
{
    const int blk = blockIdx.x;
    const int s = blk >> 3, h = blk & 7;
    __shared__ float q_s[16][36], k_s[16][36], v_s[16][36];
    __shared__ float e_s[16][17];
    __shared__ float rsum[16];
    const int t = threadIdx.x;
    const int i = t >> 4, j = t & 15;

    const u16* basep = QKV + (size_t)(s * 16 + i) * 768 + h * 32;
    q_s[i][j]      = b2f(basep[j]);
    q_s[i][j + 16] = b2f(basep[j + 16]);
    k_s[i][j]      = b2f(basep[256 + j]);
    k_s[i][j + 16] = b2f(basep[256 + j + 16]);
    v_s[i][j]      = b2f(basep[512 + j]);
    v_s[i][j + 16] = b2f(basep[512 + j + 16]);
    __syncthreads();

    float acc = 0.0f;
#pragma unroll
    for (int d = 0; d < 32; d += 4) {
        const float4 q4 = *(const float4*)(&q_s[i][d]);
        const float4 k4 = *(const float4*)(&k_s[j][d]);
        acc += q4.x * k4.x + q4.y * k4.y + q4.z * k4.z + q4.w * k4.w;
    }
    const float sc = acc * QSCALE;
    e_s[i][j] = sc;
    __syncthreads();
    float mx = e_s[i][0];
#pragma unroll
    for (int x = 1; x < 16; ++x) mx = fmaxf(mx, e_s[i][x]);
    const float e = __expf(sc - mx);
    __syncthreads();
    e_s[i][j] = e;
    __syncthreads();
    if (j == 0) {
        float sm = 0.0f;
#pragma unroll
        for (int x = 0; x < 16; ++x) sm += e_s[i][x];
        rsum[i] = sm;
    }
    __syncthreads();

    const int oi = t >> 5;
    const int d  = t & 31;
#pragma unroll
    for (int pass = 0; pass < 2; ++pass) {
        const int r = oi + pass * 8;
        float o = 0.0f;
#pragma unroll
        for (int x = 0; x < 16; ++x) o += e_s[r][x] * v_s[x][d];
        O[(size_t)(s * 16 + r) * 256 + h * 32 + d] = f2b(o / rsum[r]);
    }
}

// ---------- fused cross attention: Q-proj + all-MFMA chain -----------------
// tgtb bf16 [8192][256]; wQ = scaled Wq' [256+][256] bf16 (this layer);
// KV bf16 [B*4096][kvs] (K at +0, V at +256); ckv = [768] this layer.
__global__ LB void k_cross_attn(const u16* __restrict__ tgtb,
                                const u16* __restrict__ wQ,
                                const u16* __restrict__ KV, int kvs,
                                const float* __restrict__ ckv,
                                const int* __restrict__ valid,
                                const float* __restrict__ kps,
                                u16* __restrict__ O)
{
    const int blk = blockIdx.x;
    const int s = blk >> 3, h = blk & 7;
    const int b = s >> 8, n = s & 255;

    // ---- LDS arena 52544 B (3 blocks/CU) ----
    __shared__ __align__(16) char arena[52544];
    u16*   Wm    = (u16*)arena;               // [225][32] k=cell, swizzled
    u16*   WmT   = (u16*)(arena + 14400);     // [32 cell][264 p]
    u16*   Tk    = (u16*)(arena + 31296);     // [32 cell][32 ch]
    u16*   TvT   = (u16*)(arena + 33344);     // [32 ch][32 cell]
    u16*   Qh    = (u16*)(arena + 35392);     // [16][40] fused Q'
    u16*   QP    = (u16*)(arena + 36672);     // [16][40] (QT, then PW)
    float* s2    = (float*)(arena + 37952);   // [16][225] f32
    u16*   p_b   = (u16*)(arena + 37952);     // [16][264] bf16 (overlays s2)
    float* pwp   = (float*)(arena + 46400);   // [2][16][32] f32 partials
    float* o_prt = (float*)(arena + 50496);   // [16][32] f32

    const int t = threadIdx.x;
    const int i = t >> 4, jj = t & 15;
    const int lane = t & 63, wid = t >> 6;
    const int r16 = lane & 15, kg = lane >> 4;

    // ---- base cell (same float chain as tap math) ----
    const float kpy = kps[(b * 256 + n) * 2 + 0];
    const float kpx = kps[(b * 256 + n) * 2 + 1];
    const float gx0 = rintf(kpx) + (float)(-7);
    const float gy0 = rintf(kpy) + (float)(-7);
    const float gxn0 = gx0 / 511.0f * 2.0f - 1.0f;
    const float gyn0 = gy0 / 511.0f * 2.0f - 1.0f;
    const float xb = ((gxn0 + 1.f) * 64.f - 1.f) * 0.5f;
    const float yb = ((gyn0 + 1.f) * 64.f - 1.f) * 0.5f;
    const int x0b = (int)floorf(xb);
    const int y0b = (int)floorf(yb);

    // ---- zero Wm / WmT / Tk / TvT ----
    for (int e = t; e < 3600; e += 256) ((u32*)Wm)[e] = 0;
    for (int e = t; e < 2112; e += 256) ((u32*)WmT)[e] = 0;
    for (int e = t; e < 512; e += 256) { ((u32*)Tk)[e] = 0; ((u32*)TvT)[e] = 0; }
    __syncthreads();

    // ---- W build (verified tap math) into Wm (swizzled) + WmT -------------
    if (t < 225) {
        const int iy = t / 15, ix = t - iy * 15;
        const float gy = rintf(kpy) + (float)(iy - 7);
        const float gx = rintf(kpx) + (float)(ix - 7);
        const float gxn = gx / 511.0f * 2.0f - 1.0f;
        const float gyn = gy / 511.0f * 2.0f - 1.0f;
        const bool inval = (gxn < -1.f) || (gyn < -1.f) || (gxn > 1.f) || (gyn > 1.f);
        const float x = ((gxn + 1.f) * 64.f - 1.f) * 0.5f;
        const float y = ((gyn + 1.f) * 64.f - 1.f) * 0.5f;
        const float x0f = floorf(x), y0f = floorf(y);
        const float wx = x - x0f, wy = y - y0f;
        const int x0 = (int)x0f, y0 = (int)y0f;
#pragma unroll
        for (int tt = 0; tt < 4; ++tt) {
            const int dy = tt >> 1, dx = tt & 1;
            const int yi = y0 + dy, xi = x0 + dx;
            const bool ok = (yi >= 0) && (yi < 64) && (xi >= 0) && (xi < 64) && !inval;
            const float w = (dy ? wy : 1.f - wy) * (dx ? wx : 1.f - wx);
            if (ok) {
                const int cell = (yi - y0b) * 4 + (xi - x0b);   // in [0,16)
                const u16 wb = f2b(w);
                Wm[t * 32 + ((((cell >> 3) ^ (t & 3)) << 3) | (cell & 7))] = wb;
                WmT[cell * 264 + t] = wb;
            }
        }
        Wm[t * 32 + ((2 ^ (t & 3)) << 3)] = (u16)0x3F80;   // cell 16: w = 1.0
        WmT[16 * 264 + t] = (u16)0x3F80;
    }
    // ---- texel tiles: Tk[cell][ch], TvT[ch][cell]; cell 16 = ck/cv --------
    if (t < 128) {
        const int cell = t >> 3, q4 = t & 7;
        const int cy = cell >> 2, cx = cell & 3;
        const int py = min(max(y0b + cy, 0), 63);
        const int px = min(max(x0b + cx, 0), 63);
        const u16* src = KV + ((size_t)(b * 4096 + py * 64 + px)) * kvs + h * 32 + q4 * 4;
#pragma unroll
        for (int j = 0; j < 4; ++j) {
            const int ch = q4 * 4 + j;
            Tk[cell * 32 + ch]  = src[j];
            TvT[ch * 32 + cell] = src[256 + j];
        }
    } else if (t < 160) {
        const int ch = t - 128;
        Tk[16 * 32 + ch]  = f2b(ckv[h * 32 + ch]);
        TvT[ch * 32 + 16] = f2b(ckv[256 + h * 32 + ch]);
    }
    const bool vld = valid[s] != 0;
    __syncthreads();

    // ---- fused Q-proj: Q' = tgt @ Wq'^T (+s*bq); k-split 2ct x 2kh --------
    {
        const int ct = wid & 1, kh = wid >> 1;
        f32x4 acc = {0.f, 0.f, 0.f, 0.f};
#pragma unroll
        for (int q = 0; q < 4; ++q) {
            const int ks = kh * 4 + q;
            const bf16x8 ta = *(const bf16x8*)(tgtb + (size_t)(s * 16 + r16) * 256 + ks * 32 + kg * 8);
            const bf16x8 wb = *(const bf16x8*)(wQ + (size_t)(h * 32 + ct * 16 + r16) * 256 + ks * 32 + kg * 8);
            acc = __builtin_amdgcn_mfma_f32_16x16x32_bf16(ta, wb, acc, 0, 0, 0);
        }
#pragma unroll
        for (int rg = 0; rg < 4; ++rg)
            pwp[kh * 512 + (kg * 4 + rg) * 32 + ct * 16 + r16] = acc[rg];
    }
    __syncthreads();
    // combine partials + scaled bias -> Qh bf16 [16][40] (cols 32-39 zero)
    {
        const int q = t >> 4;
#pragma unroll
        for (int pass = 0; pass < 2; ++pass) {
            const int c = (t & 15) + pass * 16;
            const float f = pwp[q * 32 + c] + pwp[512 + q * 32 + c]
                          + ckv[512 + h * 32 + c];
            Qh[q * 40 + c] = f2b(f);
        }
        if ((t & 15) < 8) Qh[q * 40 + 32 + (t & 15)] = 0;
    }
    __syncthreads();

    // ---- QT = Q' @ Tk : [16 q][32 cells] (2 MFMA; waves 0,1) --------------
    if (wid < 2) {
        const int ct = wid;
        const bf16x8 qfr = *(const bf16x8*)(Qh + r16 * 40 + kg * 8);
        const bf16x8 tfr = *(const bf16x8*)(Tk + (ct * 16 + r16) * 32 + kg * 8);
        f32x4 acc = {0.f, 0.f, 0.f, 0.f};
        acc = __builtin_amdgcn_mfma_f32_16x16x32_bf16(qfr, tfr, acc, 0, 0, 0);
#pragma unroll
        for (int rg = 0; rg < 4; ++rg)
            QP[(kg * 4 + rg) * 40 + ct * 16 + r16] = f2b(acc[rg]);
    }
    __syncthreads();

    // ---- scores = QT @ Wm^T : S[16][225] (15 MFMA; scale pre-folded) ------
    {
        const bf16x8 afr = *(const bf16x8*)(QP + r16 * 40 + kg * 8);   // A rows=q
        for (int tile = wid; tile < 15; tile += 4) {
            const int row = tile * 16 + r16;                  // p (output col)
            const int rc = row < 225 ? row : 224;
            const bf16x8 bfr = *(const bf16x8*)(Wm + rc * 32 + ((kg ^ (rc & 3)) << 3));
            f32x4 acc = {0.f, 0.f, 0.f, 0.f};
            acc = __builtin_amdgcn_mfma_f32_16x16x32_bf16(afr, bfr, acc, 0, 0, 0);
            if (row < 225) {
#pragma unroll
                for (int rg = 0; rg < 4; ++rg) {
                    const int qr = kg * 4 + rg;
                    float sv = acc[rg];
                    if (!vld && row > 0) sv = -1e30f;
                    s2[qr * 225 + row] = sv;
                }
            }
        }
    }
    __syncthreads();

    // ---- shuffle softmax: row i owned by its 16-lane group ----------------
    float ev[15];
    float mxl = -1e30f;
#pragma unroll
    for (int k = 0; k < 15; ++k) {
        const int col = jj + 16 * k;
        ev[k] = (col < 225) ? s2[i * 225 + col] : -1e30f;
        mxl = fmaxf(mxl, ev[k]);
    }
#pragma unroll
    for (int m = 1; m < 16; m <<= 1) mxl = fmaxf(mxl, __shfl_xor(mxl, m));
    float psl = 0.0f;
#pragma unroll
    for (int k = 0; k < 15; ++k) {
        ev[k] = __expf(ev[k] - mxl);
        psl += ev[k];
    }
#pragma unroll
    for (int m = 1; m < 16; m <<= 1) psl += __shfl_xor(psl, m);
    const float rowsum = psl;
    __syncthreads();                           // all s2 reads done

    // ---- P -> p_b bf16 [16][264] (overlay) + zero pad cols ----------------
#pragma unroll
    for (int k = 0; k < 15; ++k) {
        const int col = jj + 16 * k;
        if (col < 225) p_b[i * 264 + col] = f2b(ev[k]);
    }
    for (int c = 225 + jj; c < 264; c += 16) p_b[i * 264 + c] = 0;
    __syncthreads();

    // ---- PW = P @ W : k-split across 4 waves (2 ct x 2 kh) ----------------
    {
        const int ct = wid & 1, kh = wid >> 1;
        f32x4 acc = {0.f, 0.f, 0.f, 0.f};
#pragma unroll
        for (int q = 0; q < 4; ++q) {
            const int ks = kh * 4 + q;
            const bf16x8 pa = *(const bf16x8*)(p_b + r16 * 264 + ks * 32 + kg * 8);
            const bf16x8 wb = *(const bf16x8*)(WmT + (ct * 16 + r16) * 264 + ks * 32 + kg * 8);
            acc = __builtin_amdgcn_mfma_f32_16x16x32_bf16(pa, wb, acc, 0, 0, 0);
        }
#pragma unroll
        for (int rg = 0; rg < 4; ++rg)
            pwp[kh * 512 + (kg * 4 + rg) * 32 + ct * 16 + r16] = acc[rg];
    }
    __syncthreads();

    // ---- combine partials -> QP bf16 (cells >16 zeroed) -------------------
    {
        const int q = t >> 4;
#pragma unroll
        for (int pass = 0; pass < 2; ++pass) {
            const int cell = (t & 15) + pass * 16;
            const float f = pwp[q * 32 + cell] + pwp[512 + q * 32 + cell];
            QP[q * 40 + cell] = (cell <= 16) ? f2b(f) : (u16)0;
        }
    }
    __syncthreads();

    // ---- O = PW @ Tv^T : [16 q][32 ch] (2 MFMA; waves 0,1) ----------------
    if (wid < 2) {
        const int ct = wid;
        const bf16x8 pa = *(const bf16x8*)(QP + r16 * 40 + kg * 8);
        const bf16x8 vb = *(const bf16x8*)(TvT + (ct * 16 + r16) * 32 + kg * 8);
        f32x4 acc = {0.f, 0.f, 0.f, 0.f};
        acc = __builtin_amdgcn_mfma_f32_16x16x32_bf16(pa, vb, acc, 0, 0, 0);
#pragma unroll
        for (int rg = 0; rg < 4; ++rg)
            o_prt[(kg * 4 + rg) * 32 + ct * 16 + r16] = acc[rg];
    }
    __syncthreads();

    // ---- normalize + write (cv folded via cell 16; rowsum in registers) ---
    {
        const int d0 = jj * 2;
        const float inv = 1.0f / rowsum;
        const float o0 = o_prt[i * 32 + d0]     * inv;
        const float o1 = o_prt[i * 32 + d0 + 1] * inv;
        const u32 ob = (u32)f2b(o0) | ((u32)f2b(o1) << 16);
        *(u32*)(O + (size_t)(s * 16 + i) * 256 + h * 32 + d0) = ob;
    }
}

// ---------- residual add + LayerNorm; writes fp32 X and bf16 Xb ------------
__global__ LB void k_add_ln(float* __restrict__ X, u16* __restrict__ Xb,
                            const float* __restrict__ D,
                            const float* __restrict__ w, const float* __restrict__ b)
{
    const int row  = blockIdx.x * 4 + (threadIdx.x >> 6);
    const int lane = threadIdx.x & 63;
    float4 x = ((const float4*)(X + (size_t)row * 256))[lane];
    const float4 d = ((const float4*)(D + (size_t)row * 256))[lane];
    x.x += d.x; x.y += d.y; x.z += d.z; x.w += d.w;
    float s = x.x + x.y + x.z + x.w;
#pragma unroll
    for (int m = 1; m < 64; m <<= 1) s += __shfl_xor(s, m);
    const float mu = s * (1.0f / 256.0f);
    const float4 c = make_float4(x.x - mu, x.y - mu, x.z - mu, x.w - mu);
    float q = c.x * c.x + c.y * c.y + c.z * c.z + c.w * c.w;
#pragma unroll
    for (int m = 1; m < 64; m <<= 1) q += __shfl_xor(q, m);
    const float inv = 1.0f / sqrtf(q * (1.0f / 256.0f) + 1e-5f);
    const float4 w4 = ((const float4*)w)[lane];
    const float4 b4 = ((const float4*)b)[lane];
    float4 o;
    o.x = c.x * inv * w4.x + b4.x;
    o.y = c.y * inv * w4.y + b4.y;
    o.z = c.z * inv * w4.z + b4.z;
    o.w = c.w * inv * w4.w + b4.w;
    ((float4*)(X + (size_t)row * 256))[lane] = o;
    ushort4 ob;
    ob.x = f2b(o.x); ob.y = f2b(o.y); ob.z = f2b(o.z); ob.w = f2b(o.w);
    ((ushort4*)(Xb + (size_t)row * 256))[lane] = ob;
}

// ---------- output head: (8192,256) @ (4,256)^T + b ------------------------
__global__ LB void k_out(const float* __restrict__ X, const float* __restrict__ W,
                         const float* __restrict__ bias, float* __restrict__ O)
{
    __shared__ float w_s[4][260];
    const int t = threadIdx.x;
    for (int e = t; e < 1024; e += 256) w_s[e >> 8][e & 255] = W[e];
    __syncthreads();
    const int row = blockIdx.x * 64 + (t >> 2);
    const int j = t & 3;
    const float4* xr = (const float4*)(X + (size_t)row * 256);
    float acc = 0.0f;
#pragma unroll
    for (int k4 = 0; k4 < 64; ++k4) {
        const float4 x = xr[k4];
        acc += x.x * w_s[j][k4 * 4]     + x.y * w_s[j][k4 * 4 + 1]
             + x.z * w_s[j][k4 * 4 + 2] + x.w * w_s[j][k4 * 4 + 3];
    }
    O[(size_t)row * 4 + j] = acc + bias[j];
}

// ---------------------------------------------------------------------------
extern "C" void kernel_launch(void* const* d_in, const int* in_sizes, int n_in,
                              void* d_out, int out_size, void* d_ws, size_t ws_size,
                              hipStream_t stream)
{
    const float* img          = (const float*)d_in[0];
    const float* kps          = (const float*)d_in[1];
    const unsigned char* vmsk = (const unsigned char*)d_in[2];
    const float* proj_w       = (const float*)d_in[3];
    const float* proj_b       = (const float*)d_in[4];
    const float* query_embed  = (const float*)d_in[5];
    const float* self_qkv_w   = (const float*)d_in[6];
    const float* self_qkv_b   = (const float*)d_in[7];
    const float* self_out_w   = (const float*)d_in[8];
    const float* self_out_b   = (const float*)d_in[9];
    const float* cross_qkv_w  = (const float*)d_in[10];
    const float* cross_qkv_b  = (const float*)d_in[11];
    const float* cross_out_w  = (const float*)d_in[12];
    const float* cross_out_b  = (const float*)d_in[13];
    const float* ffn1_w       = (const float*)d_in[14];
    const float* ffn1_b       = (const float*)d_in[15];
    const float* ffn2_w       = (const float*)d_in[16];
    const float* ffn2_b       = (const float*)d_in[17];
    const float* ln1_w        = (const float*)d_in[18];
    const float* ln1_b        = (const float*)d_in[19];
    const float* ln2_w        = (const float*)d_in[20];
    const float* ln2_b        = (const float*)d_in[21];
    const float* ln3_w        = (const float*)d_in[22];
    const float* ln3_b        = (const float*)d_in[23];
    const float* out_w        = (const float*)d_in[24];
    const float* out_b        = (const float*)d_in[25];
    float* out = (float*)d_out;

    // ---- workspace layout (~96 MB) ----
    char* W8 = (char*)d_ws;
    size_t off = 0;
    auto alloc = [&](size_t bytes) { void* p = W8 + off; off += (bytes + 255) & ~(size_t)255; return p; };
    float* tgt   = (float*)alloc(2097152 * 4);
    float* Pbuf  = (float*)alloc(2097152 * 4);
    u16* Sb16    = (u16*)alloc(6291456 * 2);     // self-QKV bf16 [8192][768]
    float* ckv   = (float*)alloc(3 * 768 * 4);
    u16* imgTb   = (u16*)alloc(2097152 * 2);
    u16* imgPb   = (u16*)alloc(2097152 * 2);
    u16* KVb3    = (u16*)alloc(12582912 * 2);    // [8192][1536] all 3 layers K|V
    u16* tgtb    = (u16*)alloc(2097152 * 2);
    u16* Abuf    = (u16*)alloc(2097152 * 2);
    u16* Hbuf    = (u16*)alloc(8388608 * 2);
    u16* wAll    = (u16*)alloc(3604480 * 2);
    int* valid   = (int*)alloc(512 * 4);

    u16* wProj = wAll;             // 65536
    u16* wSQKV = wProj + 65536;    // 3*768*256
    u16* wSOut = wSQKV + 589824;   // 3*256*256
    u16* wCQKV = wSOut + 196608;   // 3*768*256 (Wq rows pre-scaled)
    u16* wCOut = wCQKV + 589824;   // 3*256*256
    u16* wF1   = wCOut + 196608;   // 3*1024*256
    u16* wF2   = wF1 + 786432;     // 3*256*1024
    u16* wCKV3 = wF2 + 786432;     // 3*512*256 contiguous cross K|V weights

    k_prep<<<4, 256, 0, stream>>>(vmsk, valid, proj_b, cross_qkv_w, cross_qkv_b, ckv);
    k_wconv<<<14080, 256, 0, stream>>>(proj_w, self_qkv_w, self_out_w, cross_qkv_w,
                                       cross_out_w, ffn1_w, ffn2_w, wAll);
    k_transpose<<<dim3(64, 4, 2), 256, 0, stream>>>(img, imgTb);
    gemm_mfma<64><<<dim3(2, 128), 256, 0, stream>>>(imgTb, wProj, nullptr,
                                                    nullptr, imgPb, 8192, 256, 256, 0);
    // all 3 layers' KV projections in one N=1536 GEMM (768 blocks = 3/CU)
    gemm_mfma<128><<<dim3(12, 64), 256, 0, stream>>>(imgPb, wCKV3, nullptr,
                                                     nullptr, KVb3, 8192, 1536, 256, 0);
    k_init_tgt<<<8192, 256, 0, stream>>>(tgt, tgtb, query_embed);

    for (int l = 0; l < 3; ++l) {
        // ---- self attention (QKV in bf16) ----
        gemm_mfma<128><<<dim3(6, 64), 256, 0, stream>>>(tgtb, wSQKV + (size_t)l * 196608,
            self_qkv_b + (size_t)l * 768, nullptr, Sb16, 8192, 768, 256, 0);
        k_self_attn<<<4096, 256, 0, stream>>>(Sb16, Abuf);
        gemm_mfma<64><<<dim3(2, 128), 256, 0, stream>>>(Abuf, wSOut + (size_t)l * 65536,
            self_out_b + (size_t)l * 256, Pbuf, nullptr, 8192, 256, 256, 0);
        k_add_ln<<<2048, 256, 0, stream>>>(tgt, tgtb, Pbuf,
            ln1_w + (size_t)l * 256, ln1_b + (size_t)l * 256);

        // ---- cross attention (Q-proj fused) ----
        k_cross_attn<<<4096, 256, 0, stream>>>(tgtb, wCQKV + (size_t)l * 196608,
                                               KVb3 + (size_t)l * 512, 1536,
                                               ckv + (size_t)l * 768, valid, kps, Abuf);
        gemm_mfma<64><<<dim3(2, 128), 256, 0, stream>>>(Abuf, wCOut + (size_t)l * 65536,
            cross_out_b + (size_t)l * 256, Pbuf, nullptr, 8192, 256, 256, 0);
        k_add_ln<<<2048, 256, 0, stream>>>(tgt, tgtb, Pbuf,
            ln2_w + (size_t)l * 256, ln2_b + (size_t)l * 256);

        // ---- FFN ----
        gemm_mfma<128><<<dim3(8, 64), 256, 0, stream>>>(tgtb, wF1 + (size_t)l * 262144,
            ffn1_b + (size_t)l * 1024, nullptr, Hbuf, 8192, 1024, 256, 1);
        gemm_mfma<64><<<dim3(2, 128), 256, 0, stream>>>(Hbuf, wF2 + (size_t)l * 262144,
            ffn2_b + (size_t)l * 256, Pbuf, nullptr, 8192, 256, 1024, 0);
        k_add_ln<<<2048, 256, 0, stream>>>(tgt, tgtb, Pbuf,
            ln3_w + (size_t)l * 256, ln3_b + (size_t)l * 256);
    }

    k_out<<<128, 256, 0, stream>>>(tgt, out_w, out_b, out);
}

// Round 14
// 448.236 us; speedup vs baseline: 1.0383x; 1.0383x over previous
//
#include <hip/hip_runtime.h>
#include <hip/hip_fp16.h>

#define LB __launch_bounds__(256)

typedef unsigned short u16;
typedef unsigned int   u32;
typedef __attribute__((ext_vector_type(8))) short bf16x8;   // 8 bf16 (4 VGPRs)
typedef __attribute__((ext_vector_type(4))) float f32x4;
typedef __attribute__((ext_vector_type(8))) u16  u16x8;

__device__ __forceinline__ u16 f2b(float f) {
    u32 u = __float_as_uint(f);
    u32 r = (u + 0x7fffu + ((u >> 16) & 1u)) >> 16;
    return (u16)r;
}
__device__ __forceinline__ float b2f(u16 h) {
    return __uint_as_float((u32)h << 16);
}

// ---------------------------------------------------------------------------
// B=2 N=256 C=256 HF=WF=64 ROI=15(225) HID=256 HEADS=8 Dh=32 DEPTH=3 FFN=1024
// NQ=16 -> seqs S=512, MT=8192. Linearity: K = sample(imgP@Wk^T) + ckv.
// Cross-attn: r12-verified all-MFMA chain (separate Q GEMM — r13 fusion
// regressed: no LDS staging for weights, 8x tgtb re-read).
// NEW: gemm_ln fuses producer GEMM + residual + LayerNorm (kills add_ln
// dispatches and the 8MB fp32 Pbuf round-trip).
// ---------------------------------------------------------------------------

// ---------- fused prep: mask dtype detect + per-layer ck/cv ----------------
__global__ void k_prep(const unsigned char* __restrict__ m, int* __restrict__ valid,
                       const float* __restrict__ pb,
                       const float* __restrict__ cqkv_w,
                       const float* __restrict__ cqkv_b,
                       float* __restrict__ ckv)
{
    if (blockIdx.x == 0) {
        __shared__ int flag;
        if (threadIdx.x == 0) flag = 0;
        __syncthreads();
        int loc = 0;
        for (int off = threadIdx.x; off < 512; off += 256)
            if ((off & 3) != 0 && m[off] != 0) loc = 1;
        if (loc) atomicOr(&flag, 1);
        __syncthreads();
        const bool bytelay = (flag != 0);
        for (int s = threadIdx.x; s < 512; s += 256)
            valid[s] = bytelay ? (int)(m[s] != 0) : (int)(((const int*)m)[s] != 0);
    } else {
        const int l = blockIdx.x - 1;   // 0..2
        const float* Wk = cqkv_w + (size_t)l * 196608 + 65536;
        const float* Wv = cqkv_w + (size_t)l * 196608 + 131072;
        const float* kb = cqkv_b + (size_t)l * 768 + 256;
        const float* vb = cqkv_b + (size_t)l * 768 + 512;
        const int o = threadIdx.x;
        float a = 0.f, c = 0.f;
        for (int cc = 0; cc < 256; cc += 4) {
            const float4 p4 = *(const float4*)(pb + cc);
            const float4 k4 = *(const float4*)(Wk + (size_t)o * 256 + cc);
            const float4 v4 = *(const float4*)(Wv + (size_t)o * 256 + cc);
            a += p4.x * k4.x + p4.y * k4.y + p4.z * k4.z + p4.w * k4.w;
            c += p4.x * v4.x + p4.y * v4.y + p4.z * v4.z + p4.w * v4.w;
        }
        ckv[l * 512 + o]       = a + kb[o];
        ckv[l * 512 + 256 + o] = c + vb[o];
    }
}

// ---------- weights fp32 -> bf16 arena (+ contiguous cross-KV repack) ------
__global__ LB void k_wconv(const float* __restrict__ s0, const float* __restrict__ s1,
                           const float* __restrict__ s2, const float* __restrict__ s3,
                           const float* __restrict__ s4, const float* __restrict__ s5,
                           const float* __restrict__ s6, u16* __restrict__ dst)
{
    const int e = blockIdx.x * 256 + threadIdx.x;
    if (e >= 3604480) return;
    float v;
    int i = e;
    if (i < 65536) v = s0[i];
    else if ((i -= 65536) < 589824) v = s1[i];
    else if ((i -= 589824) < 196608) v = s2[i];
    else if ((i -= 196608) < 589824) v = s3[i];
    else if ((i -= 589824) < 196608) v = s4[i];
    else if ((i -= 196608) < 786432) v = s5[i];
    else if ((i -= 786432) < 786432) v = s6[i];
    else {  // wCKV3: [l][512 rows (Wk|Wv)][256] contiguous
        i -= 786432;
        const int l = i / 131072;
        const int r = (i - l * 131072) >> 8;
        const int c = i & 255;
        v = s3[(size_t)l * 196608 + (size_t)(256 + r) * 256 + c];
    }
    dst[e] = f2b(v);
}

// ---------- transpose image (B,C,64,64) -> (B,4096,C) bf16 -----------------
__global__ LB void k_transpose(const float* __restrict__ img, u16* __restrict__ imgTb)
{
    __shared__ float tile[64][65];
    const int b  = blockIdx.z;
    const int c0 = blockIdx.y * 64;
    const int p0 = blockIdx.x * 64;
    const int t  = threadIdx.x;
    const int tr = t >> 6, tc = t & 63;
#pragma unroll
    for (int p = 0; p < 16; ++p) {
        const int i = p * 4 + tr;
        tile[i][tc] = img[((size_t)(b * 256 + c0 + i)) * 4096 + p0 + tc];
    }
    __syncthreads();
#pragma unroll
    for (int p = 0; p < 16; ++p) {
        const int jj = p * 4 + tr;
        imgTb[((size_t)(b * 4096 + p0 + jj)) * 256 + c0 + tc] = f2b(tile[tc][jj]);
    }
}

// ---------- bf16 MFMA GEMM: C[M,N] = A[M,K](bf16) @ W[N,K](bf16)^T + bias --
template<int BM>
__global__ LB void gemm_mfma(const u16* __restrict__ A, const u16* __restrict__ W,
                             const float* __restrict__ bias,
                             float* __restrict__ Cf, u16* __restrict__ Cb,
                             int M, int N, int K, int relu)
{
    constexpr int BN = 128;
    __shared__ u16 lds[2][(BM + BN) * 64];
    const int t = threadIdx.x;
    const int wid = t >> 6, lane = t & 63;
    const int bm = blockIdx.y * BM, bn = blockIdx.x * BN;
    const int KT = K >> 6;

    auto stage = [&](int buf, int kt) {
        const int k0 = kt * 64;
        const int rr = t >> 3;
        const int u  = t & 7;
#pragma unroll
        for (int q = 0; q < BM / 32; ++q) {
            const int r = q * 32 + rr;
            const u16* src = A + (size_t)(bm + r) * K + k0 + ((u ^ (r & 7)) << 3);
            __builtin_amdgcn_global_load_lds(
                (const __attribute__((address_space(1))) void*)src,
                (__attribute__((address_space(3))) void*)&lds[buf][q * 2048 + wid * 512],
                16, 0, 0);
        }
#pragma unroll
        for (int q = 0; q < 4; ++q) {
            const int r = q * 32 + rr;
            const u16* src = W + (size_t)(bn + r) * K + k0 + ((u ^ (r & 7)) << 3);
            __builtin_amdgcn_global_load_lds(
                (const __attribute__((address_space(1))) void*)src,
                (__attribute__((address_space(3))) void*)&lds[buf][BM * 64 + q * 2048 + wid * 512],
                16, 0, 0);
        }
    };

    const int wr = wid >> 1, wc = wid & 1;
    constexpr int MR = BM / 32;
    f32x4 acc[MR][4];
    const f32x4 z = {0.f, 0.f, 0.f, 0.f};
#pragma unroll
    for (int mi = 0; mi < MR; ++mi)
#pragma unroll
        for (int ni = 0; ni < 4; ++ni) acc[mi][ni] = z;

    const int r16 = lane & 15, kg = lane >> 4;

    stage(0, 0);
    int cur = 0;
    for (int kt = 0; kt < KT; ++kt) {
        asm volatile("s_waitcnt vmcnt(0)" ::: "memory");
        __syncthreads();
        if (kt + 1 < KT) stage(cur ^ 1, kt + 1);
        const u16* pA = lds[cur];
        const u16* pB = lds[cur] + BM * 64;
#pragma unroll
        for (int kk = 0; kk < 2; ++kk) {
            const int s = kk * 4 + kg;
            bf16x8 afr[MR], bfr[4];
#pragma unroll
            for (int mi = 0; mi < MR; ++mi) {
                const int r = wr * (BM / 2) + mi * 16 + r16;
                afr[mi] = *(const bf16x8*)(pA + r * 64 + ((s ^ (r & 7)) << 3));
            }
#pragma unroll
            for (int ni = 0; ni < 4; ++ni) {
                const int c = wc * 64 + ni * 16 + r16;
                bfr[ni] = *(const bf16x8*)(pB + c * 64 + ((s ^ (c & 7)) << 3));
            }
#pragma unroll
            for (int mi = 0; mi < MR; ++mi)
#pragma unroll
                for (int ni = 0; ni < 4; ++ni)
                    acc[mi][ni] = __builtin_amdgcn_mfma_f32_16x16x32_bf16(
                        afr[mi], bfr[ni], acc[mi][ni], 0, 0, 0);
        }
        cur ^= 1;
    }

#pragma unroll
    for (int mi = 0; mi < MR; ++mi) {
#pragma unroll
        for (int ni = 0; ni < 4; ++ni) {
            const int col = bn + wc * 64 + ni * 16 + r16;
            const float bs = bias ? bias[col] : 0.0f;
#pragma unroll
            for (int rg = 0; rg < 4; ++rg) {
                const int row = bm + wr * (BM / 2) + mi * 16 + kg * 4 + rg;
                float v = acc[mi][ni][rg] + bs;
                if (relu) v = fmaxf(v, 0.0f);
                if (Cf) Cf[(size_t)row * N + col] = v;
                if (Cb) Cb[(size_t)row * N + col] = f2b(v);
            }
        }
    }
}

// ---------- fused GEMM + residual + LayerNorm ------------------------------
// delta[M,256] = A@W^T + bias; tgt = LN(tgt + delta); writes tgt f32 + bf16.
// BM=32, BN=256 (full row per block). 4 waves = 2(M) x 2(N).
__global__ LB void gemm_ln(const u16* __restrict__ A, const u16* __restrict__ W,
                           const float* __restrict__ bias,
                           float* __restrict__ tgt, u16* __restrict__ tgtb,
                           const float* __restrict__ lnw, const float* __restrict__ lnb,
                           int K)
{
    __shared__ u16 lA[32 * 64];
    __shared__ u16 lB[256 * 64];
    __shared__ float psum[2][32];
    __shared__ float psq[2][32];
    const int t = threadIdx.x;
    const int wid = t >> 6, lane = t & 63;
    const int r16 = lane & 15, kg = lane >> 4;
    const int wr = wid >> 1, wc = wid & 1;
    const int bm = blockIdx.x * 32;
    const int KT = K >> 6;

    f32x4 acc[8];
    const f32x4 z = {0.f, 0.f, 0.f, 0.f};
#pragma unroll
    for (int ni = 0; ni < 8; ++ni) acc[ni] = z;

    for (int kt = 0; kt < KT; ++kt) {
        const int k0 = kt * 64;
        const int rr = t >> 3;
        const int u  = t & 7;
        {   // A: 32 rows, one issue
            const int r = rr;
            const u16* src = A + (size_t)(bm + r) * K + k0 + ((u ^ (r & 7)) << 3);
            __builtin_amdgcn_global_load_lds(
                (const __attribute__((address_space(1))) void*)src,
                (__attribute__((address_space(3))) void*)&lA[wid * 512],
                16, 0, 0);
        }
#pragma unroll
        for (int q = 0; q < 8; ++q) {   // W: 256 rows
            const int r = q * 32 + rr;
            const u16* src = W + (size_t)r * K + k0 + ((u ^ (r & 7)) << 3);
            __builtin_amdgcn_global_load_lds(
                (const __attribute__((address_space(1))) void*)src,
                (__attribute__((address_space(3))) void*)&lB[q * 2048 + wid * 512],
                16, 0, 0);
        }
        asm volatile("s_waitcnt vmcnt(0)" ::: "memory");
        __syncthreads();
#pragma unroll
        for (int kk = 0; kk < 2; ++kk) {
            const int s = kk * 4 + kg;
            const int ra = wr * 16 + r16;
            const bf16x8 afr = *(const bf16x8*)(lA + ra * 64 + ((s ^ (ra & 7)) << 3));
#pragma unroll
            for (int ni = 0; ni < 8; ++ni) {
                const int c = wc * 128 + ni * 16 + r16;
                const bf16x8 bfr = *(const bf16x8*)(lB + c * 64 + ((s ^ (c & 7)) << 3));
                acc[ni] = __builtin_amdgcn_mfma_f32_16x16x32_bf16(afr, bfr, acc[ni], 0, 0, 0);
            }
        }
        __syncthreads();   // protect LDS before next stage
    }

    // ---- epilogue: bias + residual, two-pass LN over 256 cols -------------
    // lane holds rows wr*16 + kg*4 + rg (rg 0..3), cols wc*128 + ni*16 + r16.
    float xv[4][8];
    float bcol[8], wcol[8], bncol[8];
#pragma unroll
    for (int ni = 0; ni < 8; ++ni) {
        const int c = wc * 128 + ni * 16 + r16;
        bcol[ni]  = bias[c];
        wcol[ni]  = lnw[c];
        bncol[ni] = lnb[c];
    }
#pragma unroll
    for (int rg = 0; rg < 4; ++rg) {
        const int row = bm + wr * 16 + kg * 4 + rg;
#pragma unroll
        for (int ni = 0; ni < 8; ++ni) {
            const int c = wc * 128 + ni * 16 + r16;
            xv[rg][ni] = tgt[(size_t)row * 256 + c] + acc[ni][rg] + bcol[ni];
        }
    }
    // pass 1: mean
#pragma unroll
    for (int rg = 0; rg < 4; ++rg) {
        float s = 0.f;
#pragma unroll
        for (int ni = 0; ni < 8; ++ni) s += xv[rg][ni];
#pragma unroll
        for (int m = 1; m < 16; m <<= 1) s += __shfl_xor(s, m);
        if (r16 == 0) psum[wc][wr * 16 + kg * 4 + rg] = s;
    }
    __syncthreads();
    float mu[4];
#pragma unroll
    for (int rg = 0; rg < 4; ++rg) {
        const int rl = wr * 16 + kg * 4 + rg;
        mu[rg] = (psum[0][rl] + psum[1][rl]) * (1.0f / 256.0f);
    }
    // pass 2: variance
#pragma unroll
    for (int rg = 0; rg < 4; ++rg) {
        float q = 0.f;
#pragma unroll
        for (int ni = 0; ni < 8; ++ni) {
            const float d = xv[rg][ni] - mu[rg];
            q += d * d;
        }
#pragma unroll
        for (int m = 1; m < 16; m <<= 1) q += __shfl_xor(q, m);
        if (r16 == 0) psq[wc][wr * 16 + kg * 4 + rg] = q;
    }
    __syncthreads();
#pragma unroll
    for (int rg = 0; rg < 4; ++rg) {
        const int rl = wr * 16 + kg * 4 + rg;
        const int row = bm + rl;
        const float var = (psq[0][rl] + psq[1][rl]) * (1.0f / 256.0f);
        const float inv = 1.0f / sqrtf(var + 1e-5f);
#pragma unroll
        for (int ni = 0; ni < 8; ++ni) {
            const int c = wc * 128 + ni * 16 + r16;
            const float o = (xv[rg][ni] - mu[rg]) * inv * wcol[ni] + bncol[ni];
            tgt[(size_t)row * 256 + c]  = o;
            tgtb[(size_t)row * 256 + c] = f2b(o);
        }
    }
}

// ---------- init tgt (fp32 + bf16) -----------------------------------------
__global__ LB void k_init_tgt(float* __restrict__ tgt, u16* __restrict__ tgtb,
                              const float* __restrict__ qe)
{
    const int e = blockIdx.x * 256 + threadIdx.x;
    const int c = e & 255;
    const int row = e >> 8;
    const int i = row & 15;
    const float v = qe[(i << 8) | c];
    tgt[e] = v;
    tgtb[e] = f2b(v);
}

// ---------- self attention: per (seq, head), 16q x 16k, Dh=32; bf16 in/out -
__global__ LB void k_self_attn(const u16* __restrict__ QKV, u16* __restrict__ O)
{
    const int blk = blockIdx.x;
    const int s = blk >> 3, h = blk & 7;
    __shared__ float q_s[16][36], k_s[16][36], v_s[16][36];
    __shared__ float e_s[16][17];
    __shared__ float rsum[16];
    const int t = threadIdx.x;
    const int i = t >> 4, j = t & 15;

    const u16* basep = QKV + (size_t)(s * 16 + i) * 768 + h * 32;
    q_s[i][j]      = b2f(basep[j]);
    q_s[i][j + 16] = b2f(basep[j + 16]);
    k_s[i][j]      = b2f(basep[256 + j]);
    k_s[i][j + 16] = b2f(basep[256 + j + 16]);
    v_s[i][j]      = b2f(basep[512 + j]);
    v_s[i][j + 16] = b2f(basep[512 + j + 16]);
    __syncthreads();

    float acc = 0.0f;
#pragma unroll
    for (int d = 0; d < 32; d += 4) {
        const float4 q4 = *(const float4*)(&q_s[i][d]);
        const float4 k4 = *(const float4*)(&k_s[j][d]);
        acc += q4.x * k4.x + q4.y * k4.y + q4.z * k4.z + q4.w * k4.w;
    }
    const float sc = acc * 0.17677669529663687f;
    e_s[i][j] = sc;
    __syncthreads();
    float mx = e_s[i][0];
#pragma unroll
    for (int x = 1; x < 16; ++x) mx = fmaxf(mx, e_s[i][x]);
    const float e = __expf(sc - mx);
    __syncthreads();
    e_s[i][j] = e;
    __syncthreads();
    if (j == 0) {
        float sm = 0.0f;
#pragma unroll
        for (int x = 0; x < 16; ++x) sm += e_s[i][x];
        rsum[i] = sm;
    }
    __syncthreads();

    const int oi = t >> 5;
    const int d  = t & 31;
#pragma unroll
    for (int pass = 0; pass < 2; ++pass) {
        const int r = oi + pass * 8;
        float o = 0.0f;
#pragma unroll
        for (int x = 0; x < 16; ++x) o += e_s[r][x] * v_s[x][d];
        O[(size_t)(s * 16 + r) * 256 + h * 32 + d] = f2b(o / rsum[r]);
    }
}

// ---------- fused cross attention: reassociated all-MFMA, shuffle softmax --
// Qb bf16 [8192][256]; KV bf16 [B*4096][kvs] (K at +0, V at +256).
__global__ LB void k_cross_attn(const u16* __restrict__ Qb,
                                const u16* __restrict__ KV, int kvs,
                                const float* __restrict__ ckv,
                                const int* __restrict__ valid,
                                const float* __restrict__ kps,
                                u16* __restrict__ O)
{
    const int blk = blockIdx.x;
    const int s = blk >> 3, h = blk & 7;
    const int b = s >> 8, n = s & 255;

    // ---- LDS arena 51280 B (3 blocks/CU) ----
    __shared__ __align__(16) char arena[51280];
    u16*   Wm    = (u16*)arena;               // [225][32] k=cell, swizzled
    u16*   WmT   = (u16*)(arena + 14400);     // [32 cell][264 p]
    u16*   Tk    = (u16*)(arena + 31296);     // [32 cell][32 ch]
    u16*   TvT   = (u16*)(arena + 33344);     // [32 ch][32 cell]
    u16*   QP    = (u16*)(arena + 35392);     // [16][40] (QT, then PW)
    float* s2    = (float*)(arena + 36672);   // [16][225] f32
    u16*   p_b   = (u16*)(arena + 36672);     // [16][264] bf16 (overlays s2)
    float* pwp   = (float*)(arena + 45120);   // [2][16][32] f32 partials
    float* o_prt = (float*)(arena + 49216);   // [16][32] f32

    const int t = threadIdx.x;
    const int i = t >> 4, jj = t & 15;
    const int lane = t & 63, wid = t >> 6;
    const int r16 = lane & 15, kg = lane >> 4;

    // ---- base cell (same float chain as tap math) ----
    const float kpy = kps[(b * 256 + n) * 2 + 0];
    const float kpx = kps[(b * 256 + n) * 2 + 1];
    const float gx0 = rintf(kpx) + (float)(-7);
    const float gy0 = rintf(kpy) + (float)(-7);
    const float gxn0 = gx0 / 511.0f * 2.0f - 1.0f;
    const float gyn0 = gy0 / 511.0f * 2.0f - 1.0f;
    const float xb = ((gxn0 + 1.f) * 64.f - 1.f) * 0.5f;
    const float yb = ((gyn0 + 1.f) * 64.f - 1.f) * 0.5f;
    const int x0b = (int)floorf(xb);
    const int y0b = (int)floorf(yb);

    // ---- zero Wm / WmT / Tk / TvT ----
    for (int e = t; e < 3600; e += 256) ((u32*)Wm)[e] = 0;
    for (int e = t; e < 2112; e += 256) ((u32*)WmT)[e] = 0;
    for (int e = t; e < 512; e += 256) { ((u32*)Tk)[e] = 0; ((u32*)TvT)[e] = 0; }
    __syncthreads();

    // ---- W build (verified tap math) into Wm (swizzled) + WmT -------------
    if (t < 225) {
        const int iy = t / 15, ix = t - iy * 15;
        const float gy = rintf(kpy) + (float)(iy - 7);
        const float gx = rintf(kpx) + (float)(ix - 7);
        const float gxn = gx / 511.0f * 2.0f - 1.0f;
        const float gyn = gy / 511.0f * 2.0f - 1.0f;
        const bool inval = (gxn < -1.f) || (gyn < -1.f) || (gxn > 1.f) || (gyn > 1.f);
        const float x = ((gxn + 1.f) * 64.f - 1.f) * 0.5f;
        const float y = ((gyn + 1.f) * 64.f - 1.f) * 0.5f;
        const float x0f = floorf(x), y0f = floorf(y);
        const float wx = x - x0f, wy = y - y0f;
        const int x0 = (int)x0f, y0 = (int)y0f;
#pragma unroll
        for (int tt = 0; tt < 4; ++tt) {
            const int dy = tt >> 1, dx = tt & 1;
            const int yi = y0 + dy, xi = x0 + dx;
            const bool ok = (yi >= 0) && (yi < 64) && (xi >= 0) && (xi < 64) && !inval;
            const float w = (dy ? wy : 1.f - wy) * (dx ? wx : 1.f - wx);
            if (ok) {
                const int cell = (yi - y0b) * 4 + (xi - x0b);   // in [0,16)
                const u16 wb = f2b(w);
                Wm[t * 32 + ((((cell >> 3) ^ (t & 3)) << 3) | (cell & 7))] = wb;
                WmT[cell * 264 + t] = wb;
            }
        }
        Wm[t * 32 + ((2 ^ (t & 3)) << 3)] = (u16)0x3F80;   // cell 16: w = 1.0
        WmT[16 * 264 + t] = (u16)0x3F80;
    }
    // ---- texel tiles: Tk[cell][ch], TvT[ch][cell]; cell 16 = ck/cv --------
    if (t < 128) {
        const int cell = t >> 3, q4 = t & 7;
        const int cy = cell >> 2, cx = cell & 3;
        const int py = min(max(y0b + cy, 0), 63);
        const int px = min(max(x0b + cx, 0), 63);
        const u16* src = KV + ((size_t)(b * 4096 + py * 64 + px)) * kvs + h * 32 + q4 * 4;
#pragma unroll
        for (int j = 0; j < 4; ++j) {
            const int ch = q4 * 4 + j;
            Tk[cell * 32 + ch]  = src[j];
            TvT[ch * 32 + cell] = src[256 + j];
        }
    } else if (t < 160) {
        const int ch = t - 128;
        Tk[16 * 32 + ch]  = f2b(ckv[h * 32 + ch]);
        TvT[ch * 32 + 16] = f2b(ckv[256 + h * 32 + ch]);
    }
    const bool vld = valid[s] != 0;
    __syncthreads();

    // ---- QT = Q @ Tk : [16 q][32 cells] (2 MFMA; waves 0,1) ---------------
    if (wid < 2) {
        const int ct = wid;
        const bf16x8 qfr = *(const bf16x8*)(Qb + (size_t)(s * 16 + r16) * 256 + h * 32 + kg * 8);
        const bf16x8 tfr = *(const bf16x8*)(Tk + (ct * 16 + r16) * 32 + kg * 8);
        f32x4 acc = {0.f, 0.f, 0.f, 0.f};
        acc = __builtin_amdgcn_mfma_f32_16x16x32_bf16(qfr, tfr, acc, 0, 0, 0);
#pragma unroll
        for (int rg = 0; rg < 4; ++rg)
            QP[(kg * 4 + rg) * 40 + ct * 16 + r16] = f2b(acc[rg]);
    }
    __syncthreads();

    // ---- scores = QT @ Wm^T : S[16][225] (15 MFMA) ------------------------
    {
        const bf16x8 afr = *(const bf16x8*)(QP + r16 * 40 + kg * 8);   // A rows=q
        for (int tile = wid; tile < 15; tile += 4) {
            const int row = tile * 16 + r16;                  // p (output col)
            const int rc = row < 225 ? row : 224;
            const bf16x8 bfr = *(const bf16x8*)(Wm + rc * 32 + ((kg ^ (rc & 3)) << 3));
            f32x4 acc = {0.f, 0.f, 0.f, 0.f};
            acc = __builtin_amdgcn_mfma_f32_16x16x32_bf16(afr, bfr, acc, 0, 0, 0);
            if (row < 225) {
#pragma unroll
                for (int rg = 0; rg < 4; ++rg) {
                    const int qr = kg * 4 + rg;
                    float sv = acc[rg] * 0.17677669529663687f;
                    if (!vld && row > 0) sv = -1e30f;
                    s2[qr * 225 + row] = sv;
                }
            }
        }
    }
    __syncthreads();

    // ---- shuffle softmax: row i owned by its 16-lane group ----------------
    float ev[15];
    float mxl = -1e30f;
#pragma unroll
    for (int k = 0; k < 15; ++k) {
        const int col = jj + 16 * k;
        ev[k] = (col < 225) ? s2[i * 225 + col] : -1e30f;
        mxl = fmaxf(mxl, ev[k]);
    }
#pragma unroll
    for (int m = 1; m < 16; m <<= 1) mxl = fmaxf(mxl, __shfl_xor(mxl, m));
    float psl = 0.0f;
#pragma unroll
    for (int k = 0; k < 15; ++k) {
        ev[k] = __expf(ev[k] - mxl);
        psl += ev[k];
    }
#pragma unroll
    for (int m = 1; m < 16; m <<= 1) psl += __shfl_xor(psl, m);
    const float rowsum = psl;
    __syncthreads();                           // all s2 reads done

    // ---- P -> p_b bf16 [16][264] (overlay) + zero pad cols ----------------
#pragma unroll
    for (int k = 0; k < 15; ++k) {
        const int col = jj + 16 * k;
        if (col < 225) p_b[i * 264 + col] = f2b(ev[k]);
    }
    for (int c = 225 + jj; c < 264; c += 16) p_b[i * 264 + c] = 0;
    __syncthreads();

    // ---- PW = P @ W : k-split across 4 waves (2 ct x 2 kh) ----------------
    {
        const int ct = wid & 1, kh = wid >> 1;
        f32x4 acc = {0.f, 0.f, 0.f, 0.f};
#pragma unroll
        for (int q = 0; q < 4; ++q) {
            const int ks = kh * 4 + q;
            const bf16x8 pa = *(const bf16x8*)(p_b + r16 * 264 + ks * 32 + kg * 8);
            const bf16x8 wb = *(const bf16x8*)(WmT + (ct * 16 + r16) * 264 + ks * 32 + kg * 8);
            acc = __builtin_amdgcn_mfma_f32_16x16x32_bf16(pa, wb, acc, 0, 0, 0);
        }
#pragma unroll
        for (int rg = 0; rg < 4; ++rg)
            pwp[kh * 512 + (kg * 4 + rg) * 32 + ct * 16 + r16] = acc[rg];
    }
    __syncthreads();

    // ---- combine partials -> QP bf16 (cells >16 zeroed) -------------------
    {
        const int q = t >> 4;
#pragma unroll
        for (int pass = 0; pass < 2; ++pass) {
            const int cell = (t & 15) + pass * 16;
            const float f = pwp[q * 32 + cell] + pwp[512 + q * 32 + cell];
            QP[q * 40 + cell] = (cell <= 16) ? f2b(f) : (u16)0;
        }
    }
    __syncthreads();

    // ---- O = PW @ Tv^T : [16 q][32 ch] (2 MFMA; waves 0,1) ----------------
    if (wid < 2) {
        const int ct = wid;
        const bf16x8 pa = *(const bf16x8*)(QP + r16 * 40 + kg * 8);
        const bf16x8 vb = *(const bf16x8*)(TvT + (ct * 16 + r16) * 32 + kg * 8);
        f32x4 acc = {0.f, 0.f, 0.f, 0.f};
        acc = __builtin_amdgcn_mfma_f32_16x16x32_bf16(pa, vb, acc, 0, 0, 0);
#pragma unroll
        for (int rg = 0; rg < 4; ++rg)
            o_prt[(kg * 4 + rg) * 32 + ct * 16 + r16] = acc[rg];
    }
    __syncthreads();

    // ---- normalize + write (cv folded via cell 16; rowsum in registers) ---
    {
        const int d0 = jj * 2;
        const float inv = 1.0f / rowsum;
        const float o0 = o_prt[i * 32 + d0]     * inv;
        const float o1 = o_prt[i * 32 + d0 + 1] * inv;
        const u32 ob = (u32)f2b(o0) | ((u32)f2b(o1) << 16);
        *(u32*)(O + (size_t)(s * 16 + i) * 256 + h * 32 + d0) = ob;
    }
}

// ---------- output head: (8192,256) @ (4,256)^T + b ------------------------
__global__ LB void k_out(const float* __restrict__ X, const float* __restrict__ W,
                         const float* __restrict__ bias, float* __restrict__ O)
{
    __shared__ float w_s[4][260];
    const int t = threadIdx.x;
    for (int e = t; e < 1024; e += 256) w_s[e >> 8][e & 255] = W[e];
    __syncthreads();
    const int row = blockIdx.x * 64 + (t >> 2);
    const int j = t & 3;
    const float4* xr = (const float4*)(X + (size_t)row * 256);
    float acc = 0.0f;
#pragma unroll
    for (int k4 = 0; k4 < 64; ++k4) {
        const float4 x = xr[k4];
        acc += x.x * w_s[j][k4 * 4]     + x.y * w_s[j][k4 * 4 + 1]
             + x.z * w_s[j][k4 * 4 + 2] + x.w * w_s[j][k4 * 4 + 3];
    }
    O[(size_t)row * 4 + j] = acc + bias[j];
}

// ---------------------------------------------------------------------------
extern "C" void kernel_launch(void* const* d_in, const int* in_sizes, int n_in,
                              void* d_out, int out_size, void* d_ws, size_t ws_size,
                              hipStream_t stream)
{
    const float* img          = (const float*)d_in[0];
    const float* kps          = (const float*)d_in[1];
    const unsigned char* vmsk = (const unsigned char*)d_in[2];
    const float* proj_w       = (const float*)d_in[3];
    const float* proj_b       = (const float*)d_in[4];
    const float* query_embed  = (const float*)d_in[5];
    const float* self_qkv_w   = (const float*)d_in[6];
    const float* self_qkv_b   = (const float*)d_in[7];
    const float* self_out_w   = (const float*)d_in[8];
    const float* self_out_b   = (const float*)d_in[9];
    const float* cross_qkv_w  = (const float*)d_in[10];
    const float* cross_qkv_b  = (const float*)d_in[11];
    const float* cross_out_w  = (const float*)d_in[12];
    const float* cross_out_b  = (const float*)d_in[13];
    const float* ffn1_w       = (const float*)d_in[14];
    const float* ffn1_b       = (const float*)d_in[15];
    const float* ffn2_w       = (const float*)d_in[16];
    const float* ffn2_b       = (const float*)d_in[17];
    const float* ln1_w        = (const float*)d_in[18];
    const float* ln1_b        = (const float*)d_in[19];
    const float* ln2_w        = (const float*)d_in[20];
    const float* ln2_b        = (const float*)d_in[21];
    const float* ln3_w        = (const float*)d_in[22];
    const float* ln3_b        = (const float*)d_in[23];
    const float* out_w        = (const float*)d_in[24];
    const float* out_b        = (const float*)d_in[25];
    float* out = (float*)d_out;

    // ---- workspace layout (~88 MB) ----
    char* W8 = (char*)d_ws;
    size_t off = 0;
    auto alloc = [&](size_t bytes) { void* p = W8 + off; off += (bytes + 255) & ~(size_t)255; return p; };
    float* tgt   = (float*)alloc(2097152 * 4);
    u16* Qb      = (u16*)alloc(2097152 * 2);     // cross-Q bf16
    u16* Sb16    = (u16*)alloc(6291456 * 2);     // self-QKV bf16 [8192][768]
    float* ckv   = (float*)alloc(3 * 512 * 4);
    u16* imgTb   = (u16*)alloc(2097152 * 2);
    u16* imgPb   = (u16*)alloc(2097152 * 2);
    u16* KVb3    = (u16*)alloc(12582912 * 2);    // [8192][1536] all 3 layers K|V
    u16* tgtb    = (u16*)alloc(2097152 * 2);
    u16* Abuf    = (u16*)alloc(2097152 * 2);
    u16* Hbuf    = (u16*)alloc(8388608 * 2);
    u16* wAll    = (u16*)alloc(3604480 * 2);
    int* valid   = (int*)alloc(512 * 4);

    u16* wProj = wAll;             // 65536
    u16* wSQKV = wProj + 65536;    // 3*768*256
    u16* wSOut = wSQKV + 589824;   // 3*256*256
    u16* wCQKV = wSOut + 196608;   // 3*768*256
    u16* wCOut = wCQKV + 589824;   // 3*256*256
    u16* wF1   = wCOut + 196608;   // 3*1024*256
    u16* wF2   = wF1 + 786432;     // 3*256*1024
    u16* wCKV3 = wF2 + 786432;     // 3*512*256 contiguous cross K|V weights

    k_prep<<<4, 256, 0, stream>>>(vmsk, valid, proj_b, cross_qkv_w, cross_qkv_b, ckv);
    k_wconv<<<14080, 256, 0, stream>>>(proj_w, self_qkv_w, self_out_w, cross_qkv_w,
                                       cross_out_w, ffn1_w, ffn2_w, wAll);
    k_transpose<<<dim3(64, 4, 2), 256, 0, stream>>>(img, imgTb);
    gemm_mfma<64><<<dim3(2, 128), 256, 0, stream>>>(imgTb, wProj, nullptr,
                                                    nullptr, imgPb, 8192, 256, 256, 0);
    // all 3 layers' KV projections in one N=1536 GEMM (768 blocks = 3/CU)
    gemm_mfma<128><<<dim3(12, 64), 256, 0, stream>>>(imgPb, wCKV3, nullptr,
                                                     nullptr, KVb3, 8192, 1536, 256, 0);
    k_init_tgt<<<8192, 256, 0, stream>>>(tgt, tgtb, query_embed);

    for (int l = 0; l < 3; ++l) {
        // ---- self attention (QKV in bf16) ----
        gemm_mfma<128><<<dim3(6, 64), 256, 0, stream>>>(tgtb, wSQKV + (size_t)l * 196608,
            self_qkv_b + (size_t)l * 768, nullptr, Sb16, 8192, 768, 256, 0);
        k_self_attn<<<4096, 256, 0, stream>>>(Sb16, Abuf);
        gemm_ln<<<256, 256, 0, stream>>>(Abuf, wSOut + (size_t)l * 65536,
            self_out_b + (size_t)l * 256, tgt, tgtb,
            ln1_w + (size_t)l * 256, ln1_b + (size_t)l * 256, 256);

        // ---- cross attention ----
        gemm_mfma<64><<<dim3(2, 128), 256, 0, stream>>>(tgtb, wCQKV + (size_t)l * 196608,
            cross_qkv_b + (size_t)l * 768, nullptr, Qb, 8192, 256, 256, 0);
        k_cross_attn<<<4096, 256, 0, stream>>>(Qb, KVb3 + (size_t)l * 512, 1536,
                                               ckv + (size_t)l * 512, valid, kps, Abuf);
        gemm_ln<<<256, 256, 0, stream>>>(Abuf, wCOut + (size_t)l * 65536,
            cross_out_b + (size_t)l * 256, tgt, tgtb,
            ln2_w + (size_t)l * 256, ln2_b + (size_t)l * 256, 256);

        // ---- FFN ----
        gemm_mfma<128><<<dim3(8, 64), 256, 0, stream>>>(tgtb, wF1 + (size_t)l * 262144,
            ffn1_b + (size_t)l * 1024, nullptr, Hbuf, 8192, 1024, 256, 1);
        gemm_ln<<<256, 256, 0, stream>>>(Hbuf, wF2 + (size_t)l * 262144,
            ffn2_b + (size_t)l * 256, tgt, tgtb,
            ln3_w + (size_t)l * 256, ln3_b + (size_t)l * 256, 1024);
    }

    k_out<<<128, 256, 0, stream>>>(tgt, out_w, out_b, out);
}

// Round 15
// 407.081 us; speedup vs baseline: 1.1432x; 1.1011x over previous
//
#include <hip/hip_runtime.h>
#include <hip/hip_fp16.h>

#define LB __launch_bounds__(256)

typedef unsigned short u16;
typedef unsigned int   u32;
typedef __attribute__((ext_vector_type(8))) short bf16x8;   // 8 bf16 (4 VGPRs)
typedef __attribute__((ext_vector_type(4))) float f32x4;
typedef __attribute__((ext_vector_type(8))) u16  u16x8;

__device__ __forceinline__ u16 f2b(float f) {
    u32 u = __float_as_uint(f);
    u32 r = (u + 0x7fffu + ((u >> 16) & 1u)) >> 16;
    return (u16)r;
}
__device__ __forceinline__ float b2f(u16 h) {
    return __uint_as_float((u32)h << 16);
}

#define QSCALE 0.17677669529663687f

// ---------------------------------------------------------------------------
// B=2 N=256 C=256 HF=WF=64 ROI=15(225) HID=256 HEADS=8 Dh=32 DEPTH=3 FFN=1024
// NQ=16 -> seqs S=512, MT=8192.
// Cross-attn v2: wave-per-head. Block = (s, head-group of 4). W built ONCE
// per block (2 barriers total); each wave runs its head chain fully in-wave:
//   QT=Q@Tk (1 mfma) -> S=QT@Wm^T (15) -> in-register softmax (16-lane
//   shuffles on D-frags) -> PW=P@W (8-chain) -> O=PW@Tv^T (2) -> /rowsum +cv.
// ck dropped (softmax shift-invariant, exact); cv added in epilogue.
// LDS overlays: QP inside p_b; Tk/TvT share one buffer; pads re-zeroed
// at each phase transition (choreography audited).
// ---------------------------------------------------------------------------

// ---------- fused prep: mask dtype detect + per-layer ck/cv ----------------
__global__ void k_prep(const unsigned char* __restrict__ m, int* __restrict__ valid,
                       const float* __restrict__ pb,
                       const float* __restrict__ cqkv_w,
                       const float* __restrict__ cqkv_b,
                       float* __restrict__ ckv)
{
    if (blockIdx.x == 0) {
        __shared__ int flag;
        if (threadIdx.x == 0) flag = 0;
        __syncthreads();
        int loc = 0;
        for (int off = threadIdx.x; off < 512; off += 256)
            if ((off & 3) != 0 && m[off] != 0) loc = 1;
        if (loc) atomicOr(&flag, 1);
        __syncthreads();
        const bool bytelay = (flag != 0);
        for (int s = threadIdx.x; s < 512; s += 256)
            valid[s] = bytelay ? (int)(m[s] != 0) : (int)(((const int*)m)[s] != 0);
    } else {
        const int l = blockIdx.x - 1;   // 0..2
        const float* Wk = cqkv_w + (size_t)l * 196608 + 65536;
        const float* Wv = cqkv_w + (size_t)l * 196608 + 131072;
        const float* kb = cqkv_b + (size_t)l * 768 + 256;
        const float* vb = cqkv_b + (size_t)l * 768 + 512;
        const int o = threadIdx.x;
        float a = 0.f, c = 0.f;
        for (int cc = 0; cc < 256; cc += 4) {
            const float4 p4 = *(const float4*)(pb + cc);
            const float4 k4 = *(const float4*)(Wk + (size_t)o * 256 + cc);
            const float4 v4 = *(const float4*)(Wv + (size_t)o * 256 + cc);
            a += p4.x * k4.x + p4.y * k4.y + p4.z * k4.z + p4.w * k4.w;
            c += p4.x * v4.x + p4.y * v4.y + p4.z * v4.z + p4.w * v4.w;
        }
        ckv[l * 512 + o]       = a + kb[o];   // ck (unused by cross v2; kept)
        ckv[l * 512 + 256 + o] = c + vb[o];   // cv (epilogue)
    }
}

// ---------- weights fp32 -> bf16 arena (+ contiguous cross-KV repack) ------
__global__ LB void k_wconv(const float* __restrict__ s0, const float* __restrict__ s1,
                           const float* __restrict__ s2, const float* __restrict__ s3,
                           const float* __restrict__ s4, const float* __restrict__ s5,
                           const float* __restrict__ s6, u16* __restrict__ dst)
{
    const int e = blockIdx.x * 256 + threadIdx.x;
    if (e >= 3604480) return;
    float v;
    int i = e;
    if (i < 65536) v = s0[i];
    else if ((i -= 65536) < 589824) v = s1[i];
    else if ((i -= 589824) < 196608) v = s2[i];
    else if ((i -= 196608) < 589824) v = s3[i];
    else if ((i -= 589824) < 196608) v = s4[i];
    else if ((i -= 196608) < 786432) v = s5[i];
    else if ((i -= 786432) < 786432) v = s6[i];
    else {  // wCKV3: [l][512 rows (Wk|Wv)][256] contiguous
        i -= 786432;
        const int l = i / 131072;
        const int r = (i - l * 131072) >> 8;
        const int c = i & 255;
        v = s3[(size_t)l * 196608 + (size_t)(256 + r) * 256 + c];
    }
    dst[e] = f2b(v);
}

// ---------- transpose image (B,C,64,64) -> (B,4096,C) bf16 -----------------
__global__ LB void k_transpose(const float* __restrict__ img, u16* __restrict__ imgTb)
{
    __shared__ float tile[64][65];
    const int b  = blockIdx.z;
    const int c0 = blockIdx.y * 64;
    const int p0 = blockIdx.x * 64;
    const int t  = threadIdx.x;
    const int tr = t >> 6, tc = t & 63;
#pragma unroll
    for (int p = 0; p < 16; ++p) {
        const int i = p * 4 + tr;
        tile[i][tc] = img[((size_t)(b * 256 + c0 + i)) * 4096 + p0 + tc];
    }
    __syncthreads();
#pragma unroll
    for (int p = 0; p < 16; ++p) {
        const int jj = p * 4 + tr;
        imgTb[((size_t)(b * 4096 + p0 + jj)) * 256 + c0 + tc] = f2b(tile[tc][jj]);
    }
}

// ---------- bf16 MFMA GEMM: C[M,N] = A[M,K](bf16) @ W[N,K](bf16)^T + bias --
template<int BM>
__global__ LB void gemm_mfma(const u16* __restrict__ A, const u16* __restrict__ W,
                             const float* __restrict__ bias,
                             float* __restrict__ Cf, u16* __restrict__ Cb,
                             int M, int N, int K, int relu)
{
    constexpr int BN = 128;
    __shared__ u16 lds[2][(BM + BN) * 64];
    const int t = threadIdx.x;
    const int wid = t >> 6, lane = t & 63;
    const int bm = blockIdx.y * BM, bn = blockIdx.x * BN;
    const int KT = K >> 6;

    auto stage = [&](int buf, int kt) {
        const int k0 = kt * 64;
        const int rr = t >> 3;
        const int u  = t & 7;
#pragma unroll
        for (int q = 0; q < BM / 32; ++q) {
            const int r = q * 32 + rr;
            const u16* src = A + (size_t)(bm + r) * K + k0 + ((u ^ (r & 7)) << 3);
            __builtin_amdgcn_global_load_lds(
                (const __attribute__((address_space(1))) void*)src,
                (__attribute__((address_space(3))) void*)&lds[buf][q * 2048 + wid * 512],
                16, 0, 0);
        }
#pragma unroll
        for (int q = 0; q < 4; ++q) {
            const int r = q * 32 + rr;
            const u16* src = W + (size_t)(bn + r) * K + k0 + ((u ^ (r & 7)) << 3);
            __builtin_amdgcn_global_load_lds(
                (const __attribute__((address_space(1))) void*)src,
                (__attribute__((address_space(3))) void*)&lds[buf][BM * 64 + q * 2048 + wid * 512],
                16, 0, 0);
        }
    };

    const int wr = wid >> 1, wc = wid & 1;
    constexpr int MR = BM / 32;
    f32x4 acc[MR][4];
    const f32x4 z = {0.f, 0.f, 0.f, 0.f};
#pragma unroll
    for (int mi = 0; mi < MR; ++mi)
#pragma unroll
        for (int ni = 0; ni < 4; ++ni) acc[mi][ni] = z;

    const int r16 = lane & 15, kg = lane >> 4;

    stage(0, 0);
    int cur = 0;
    for (int kt = 0; kt < KT; ++kt) {
        asm volatile("s_waitcnt vmcnt(0)" ::: "memory");
        __syncthreads();
        if (kt + 1 < KT) stage(cur ^ 1, kt + 1);
        const u16* pA = lds[cur];
        const u16* pB = lds[cur] + BM * 64;
#pragma unroll
        for (int kk = 0; kk < 2; ++kk) {
            const int s = kk * 4 + kg;
            bf16x8 afr[MR], bfr[4];
#pragma unroll
            for (int mi = 0; mi < MR; ++mi) {
                const int r = wr * (BM / 2) + mi * 16 + r16;
                afr[mi] = *(const bf16x8*)(pA + r * 64 + ((s ^ (r & 7)) << 3));
            }
#pragma unroll
            for (int ni = 0; ni < 4; ++ni) {
                const int c = wc * 64 + ni * 16 + r16;
                bfr[ni] = *(const bf16x8*)(pB + c * 64 + ((s ^ (c & 7)) << 3));
            }
#pragma unroll
            for (int mi = 0; mi < MR; ++mi)
#pragma unroll
                for (int ni = 0; ni < 4; ++ni)
                    acc[mi][ni] = __builtin_amdgcn_mfma_f32_16x16x32_bf16(
                        afr[mi], bfr[ni], acc[mi][ni], 0, 0, 0);
        }
        cur ^= 1;
    }

#pragma unroll
    for (int mi = 0; mi < MR; ++mi) {
#pragma unroll
        for (int ni = 0; ni < 4; ++ni) {
            const int col = bn + wc * 64 + ni * 16 + r16;
            const float bs = bias ? bias[col] : 0.0f;
#pragma unroll
            for (int rg = 0; rg < 4; ++rg) {
                const int row = bm + wr * (BM / 2) + mi * 16 + kg * 4 + rg;
                float v = acc[mi][ni][rg] + bs;
                if (relu) v = fmaxf(v, 0.0f);
                if (Cf) Cf[(size_t)row * N + col] = v;
                if (Cb) Cb[(size_t)row * N + col] = f2b(v);
            }
        }
    }
}

// ---------- fused GEMM + residual + LayerNorm ------------------------------
__global__ LB void gemm_ln(const u16* __restrict__ A, const u16* __restrict__ W,
                           const float* __restrict__ bias,
                           float* __restrict__ tgt, u16* __restrict__ tgtb,
                           const float* __restrict__ lnw, const float* __restrict__ lnb,
                           int K)
{
    __shared__ u16 lA[32 * 64];
    __shared__ u16 lB[256 * 64];
    __shared__ float psum[2][32];
    __shared__ float psq[2][32];
    const int t = threadIdx.x;
    const int wid = t >> 6, lane = t & 63;
    const int r16 = lane & 15, kg = lane >> 4;
    const int wr = wid >> 1, wc = wid & 1;
    const int bm = blockIdx.x * 32;
    const int KT = K >> 6;

    f32x4 acc[8];
    const f32x4 z = {0.f, 0.f, 0.f, 0.f};
#pragma unroll
    for (int ni = 0; ni < 8; ++ni) acc[ni] = z;

    for (int kt = 0; kt < KT; ++kt) {
        const int k0 = kt * 64;
        const int rr = t >> 3;
        const int u  = t & 7;
        {
            const int r = rr;
            const u16* src = A + (size_t)(bm + r) * K + k0 + ((u ^ (r & 7)) << 3);
            __builtin_amdgcn_global_load_lds(
                (const __attribute__((address_space(1))) void*)src,
                (__attribute__((address_space(3))) void*)&lA[wid * 512],
                16, 0, 0);
        }
#pragma unroll
        for (int q = 0; q < 8; ++q) {
            const int r = q * 32 + rr;
            const u16* src = W + (size_t)r * K + k0 + ((u ^ (r & 7)) << 3);
            __builtin_amdgcn_global_load_lds(
                (const __attribute__((address_space(1))) void*)src,
                (__attribute__((address_space(3))) void*)&lB[q * 2048 + wid * 512],
                16, 0, 0);
        }
        asm volatile("s_waitcnt vmcnt(0)" ::: "memory");
        __syncthreads();
#pragma unroll
        for (int kk = 0; kk < 2; ++kk) {
            const int s = kk * 4 + kg;
            const int ra = wr * 16 + r16;
            const bf16x8 afr = *(const bf16x8*)(lA + ra * 64 + ((s ^ (ra & 7)) << 3));
#pragma unroll
            for (int ni = 0; ni < 8; ++ni) {
                const int c = wc * 128 + ni * 16 + r16;
                const bf16x8 bfr = *(const bf16x8*)(lB + c * 64 + ((s ^ (c & 7)) << 3));
                acc[ni] = __builtin_amdgcn_mfma_f32_16x16x32_bf16(afr, bfr, acc[ni], 0, 0, 0);
            }
        }
        __syncthreads();
    }

    float xv[4][8];
    float bcol[8], wcol[8], bncol[8];
#pragma unroll
    for (int ni = 0; ni < 8; ++ni) {
        const int c = wc * 128 + ni * 16 + r16;
        bcol[ni]  = bias[c];
        wcol[ni]  = lnw[c];
        bncol[ni] = lnb[c];
    }
#pragma unroll
    for (int rg = 0; rg < 4; ++rg) {
        const int row = bm + wr * 16 + kg * 4 + rg;
#pragma unroll
        for (int ni = 0; ni < 8; ++ni) {
            const int c = wc * 128 + ni * 16 + r16;
            xv[rg][ni] = tgt[(size_t)row * 256 + c] + acc[ni][rg] + bcol[ni];
        }
    }
#pragma unroll
    for (int rg = 0; rg < 4; ++rg) {
        float s = 0.f;
#pragma unroll
        for (int ni = 0; ni < 8; ++ni) s += xv[rg][ni];
#pragma unroll
        for (int m = 1; m < 16; m <<= 1) s += __shfl_xor(s, m);
        if (r16 == 0) psum[wc][wr * 16 + kg * 4 + rg] = s;
    }
    __syncthreads();
    float mu[4];
#pragma unroll
    for (int rg = 0; rg < 4; ++rg) {
        const int rl = wr * 16 + kg * 4 + rg;
        mu[rg] = (psum[0][rl] + psum[1][rl]) * (1.0f / 256.0f);
    }
#pragma unroll
    for (int rg = 0; rg < 4; ++rg) {
        float q = 0.f;
#pragma unroll
        for (int ni = 0; ni < 8; ++ni) {
            const float d = xv[rg][ni] - mu[rg];
            q += d * d;
        }
#pragma unroll
        for (int m = 1; m < 16; m <<= 1) q += __shfl_xor(q, m);
        if (r16 == 0) psq[wc][wr * 16 + kg * 4 + rg] = q;
    }
    __syncthreads();
#pragma unroll
    for (int rg = 0; rg < 4; ++rg) {
        const int rl = wr * 16 + kg * 4 + rg;
        const int row = bm + rl;
        const float var = (psq[0][rl] + psq[1][rl]) * (1.0f / 256.0f);
        const float inv = 1.0f / sqrtf(var + 1e-5f);
#pragma unroll
        for (int ni = 0; ni < 8; ++ni) {
            const int c = wc * 128 + ni * 16 + r16;
            const float o = (xv[rg][ni] - mu[rg]) * inv * wcol[ni] + bncol[ni];
            tgt[(size_t)row * 256 + c]  = o;
            tgtb[(size_t)row * 256 + c] = f2b(o);
        }
    }
}

// ---------- init tgt (fp32 + bf16) -----------------------------------------
__global__ LB void k_init_tgt(float* __restrict__ tgt, u16* __restrict__ tgtb,
                              const float* __restrict__ qe)
{
    const int e = blockIdx.x * 256 + threadIdx.x;
    const int c = e & 255;
    const int row = e >> 8;
    const int i = row & 15;
    const float v = qe[(i << 8) | c];
    tgt[e] = v;
    tgtb[e] = f2b(v);
}

// ---------- self attention: per (seq, head), 16q x 16k, Dh=32; bf16 in/out -
__global__ LB void k_self_attn(const u16* __restrict__ QKV, u16* __restrict__ O)
{
    const int blk = blockIdx.x;
    const int s = blk >> 3, h = blk & 7;
    __shared__ float q_s[16][36], k_s[16][36], v_s[16][36];
    __shared__ float e_s[16][17];
    __shared__ float rsum[16];
    const int t = threadIdx.x;
    const int i = t >> 4, j = t & 15;

    const u16* basep = QKV + (size_t)(s * 16 + i) * 768 + h * 32;
    q_s[i][j]      = b2f(basep[j]);
    q_s[i][j + 16] = b2f(basep[j + 16]);
    k_s[i][j]      = b2f(basep[256 + j]);
    k_s[i][j + 16] = b2f(basep[256 + j + 16]);
    v_s[i][j]      = b2f(basep[512 + j]);
    v_s[i][j + 16] = b2f(basep[512 + j + 16]);
    __syncthreads();

    float acc = 0.0f;
#pragma unroll
    for (int d = 0; d < 32; d += 4) {
        const float4 q4 = *(const float4*)(&q_s[i][d]);
        const float4 k4 = *(const float4*)(&k_s[j][d]);
        acc += q4.x * k4.x + q4.y * k4.y + q4.z * k4.z + q4.w * k4.w;
    }
    const float sc = acc * QSCALE;
    e_s[i][j] = sc;
    __syncthreads();
    float mx = e_s[i][0];
#pragma unroll
    for (int x = 1; x < 16; ++x) mx = fmaxf(mx, e_s[i][x]);
    const float e = __expf(sc - mx);
    __syncthreads();
    e_s[i][j] = e;
    __syncthreads();
    if (j == 0) {
        float sm = 0.0f;
#pragma unroll
        for (int x = 0; x < 16; ++x) sm += e_s[i][x];
        rsum[i] = sm;
    }
    __syncthreads();

    const int oi = t >> 5;
    const int d  = t & 31;
#pragma unroll
    for (int pass = 0; pass < 2; ++pass) {
        const int r = oi + pass * 8;
        float o = 0.0f;
#pragma unroll
        for (int x = 0; x < 16; ++x) o += e_s[r][x] * v_s[x][d];
        O[(size_t)(s * 16 + r) * 256 + h * 32 + d] = f2b(o / rsum[r]);
    }
}

// ---------- cross attention v2: wave-per-head, in-wave chain ---------------
// grid 1024: blk -> s = blk>>1, head group (blk&1)*4 + wid.
// Qb bf16 [8192][256]; KV bf16 [B*4096][kvs] (K at +0, V at +256).
__global__ LB void k_cross_attn(const u16* __restrict__ Qb,
                                const u16* __restrict__ KV, int kvs,
                                const float* __restrict__ ckv,
                                const int* __restrict__ valid,
                                const float* __restrict__ kps,
                                u16* __restrict__ O)
{
    // ---- LDS 64832 B: Wm [225][32] | WmT [16][264] | 4 slots x
    //      { buf [32][32] (Tk then TvT) | p_b [16][264] (QP [16][40] overlay) }
    __shared__ __align__(16) char arena[64832];
    u16* Wm  = (u16*)arena;
    u16* WmT = (u16*)(arena + 14400);

    const int t = threadIdx.x;
    const int lane = t & 63, wid = t >> 6;
    const int r16 = lane & 15, kg = lane >> 4;
    const int blk = blockIdx.x;
    const int s = blk >> 1;
    const int h = (blk & 1) * 4 + wid;
    const int b = s >> 8, n = s & 255;

    u16* buf = (u16*)(arena + 22848 + wid * 10496);           // [32][32]
    u16* p_b = (u16*)(arena + 22848 + wid * 10496 + 2048);    // [16][264]
    u16* QP  = p_b;                                            // [16][40] overlay

    // ---- phase 0: zero entire arena ----
    for (int e = t; e < 16208; e += 256) ((u32*)arena)[e] = 0;
    __syncthreads();

    // ---- keypoint base (all threads; same per block) ----
    const float kpy = kps[(b * 256 + n) * 2 + 0];
    const float kpx = kps[(b * 256 + n) * 2 + 1];
    const float gx0 = rintf(kpx) - 7.0f;
    const float gy0 = rintf(kpy) - 7.0f;
    const float gxn0 = gx0 / 511.0f * 2.0f - 1.0f;
    const float gyn0 = gy0 / 511.0f * 2.0f - 1.0f;
    const float xb = ((gxn0 + 1.f) * 64.f - 1.f) * 0.5f;
    const float yb = ((gyn0 + 1.f) * 64.f - 1.f) * 0.5f;
    const int x0b = (int)floorf(xb);
    const int y0b = (int)floorf(yb);

    // ---- phase 1: W build (t<225) + per-wave Tk load ----
    if (t < 225) {
        const int iy = t / 15, ix = t - iy * 15;
        const float gy = rintf(kpy) + (float)(iy - 7);
        const float gx = rintf(kpx) + (float)(ix - 7);
        const float gxn = gx / 511.0f * 2.0f - 1.0f;
        const float gyn = gy / 511.0f * 2.0f - 1.0f;
        const bool inval = (gxn < -1.f) || (gyn < -1.f) || (gxn > 1.f) || (gyn > 1.f);
        const float x = ((gxn + 1.f) * 64.f - 1.f) * 0.5f;
        const float y = ((gyn + 1.f) * 64.f - 1.f) * 0.5f;
        const float x0f = floorf(x), y0f = floorf(y);
        const float wx = x - x0f, wy = y - y0f;
        const int x0 = (int)x0f, y0 = (int)y0f;
#pragma unroll
        for (int tt = 0; tt < 4; ++tt) {
            const int dy = tt >> 1, dx = tt & 1;
            const int yi = y0 + dy, xi = x0 + dx;
            const bool ok = (yi >= 0) && (yi < 64) && (xi >= 0) && (xi < 64) && !inval;
            const float w = (dy ? wy : 1.f - wy) * (dx ? wx : 1.f - wx);
            if (ok) {
                const int cell = (yi - y0b) * 4 + (xi - x0b);   // [0,16)
                const u16 wb = f2b(w);
                Wm[t * 32 + ((((cell >> 3) ^ (t & 3)) << 3) | (cell & 7))] = wb;
                WmT[cell * 264 + t] = wb;
            }
        }
    }
    // Tk: buf rows 0-15 = cells, cols = 32 ch (wave-local)
    const int cell = lane >> 2, ch8 = (lane & 3) * 8;
    const int cy = cell >> 2, cx = cell & 3;
    const int py = min(max(y0b + cy, 0), 63);
    const int px = min(max(x0b + cx, 0), 63);
    const size_t texidx = (size_t)(b * 4096 + py * 64 + px) * kvs + h * 32 + ch8;
    *(u16x8*)(buf + cell * 32 + ch8) = *(const u16x8*)(KV + texidx);
    const bool vld = valid[s] != 0;
    __syncthreads();

    // ======== in-wave head chain (no more block barriers) ========

    // A) QT = Q @ Tk : [16 q][16 cells] (1 MFMA)
    {
        const bf16x8 qfr = *(const bf16x8*)(Qb + (size_t)(s * 16 + r16) * 256 + h * 32 + kg * 8);
        const bf16x8 tfr = *(const bf16x8*)(buf + r16 * 32 + kg * 8);
        f32x4 aq = {0.f, 0.f, 0.f, 0.f};
        aq = __builtin_amdgcn_mfma_f32_16x16x32_bf16(qfr, tfr, aq, 0, 0, 0);
#pragma unroll
        for (int rg = 0; rg < 4; ++rg)
            QP[(kg * 4 + rg) * 40 + r16] = f2b(aq[rg]);   // [q][cell]
    }

    // B) S = QT @ Wm^T (15 MFMA) -> ev registers; C) in-register softmax
    float ev[4][15];
    {
        const bf16x8 afr = *(const bf16x8*)(QP + r16 * 40 + kg * 8);  // row=q, k=cells
#pragma unroll
        for (int tile = 0; tile < 15; ++tile) {
            const int p = tile * 16 + r16;
            const int rc = p < 225 ? p : 224;
            const bf16x8 bfr = *(const bf16x8*)(Wm + rc * 32 + ((kg ^ (rc & 3)) << 3));
            f32x4 acc = {0.f, 0.f, 0.f, 0.f};
            acc = __builtin_amdgcn_mfma_f32_16x16x32_bf16(afr, bfr, acc, 0, 0, 0);
#pragma unroll
            for (int rg = 0; rg < 4; ++rg) {
                float sv = acc[rg] * QSCALE;
                if (p > 224) sv = -1e30f;
                if (!vld && p > 0) sv = -1e30f;
                ev[rg][tile] = sv;
            }
        }
    }
    float rowsumv[4];
#pragma unroll
    for (int rg = 0; rg < 4; ++rg) {
        float mx = -1e30f;
#pragma unroll
        for (int k = 0; k < 15; ++k) mx = fmaxf(mx, ev[rg][k]);
#pragma unroll
        for (int m = 1; m < 16; m <<= 1) mx = fmaxf(mx, __shfl_xor(mx, m));
        float ps = 0.f;
#pragma unroll
        for (int k = 0; k < 15; ++k) {
            ev[rg][k] = __expf(ev[rg][k] - mx);
            ps += ev[rg][k];
        }
#pragma unroll
        for (int m = 1; m < 16; m <<= 1) ps += __shfl_xor(ps, m);
        rowsumv[rg] = ps;
    }

    // D) P -> p_b bf16 [16][264]; re-zero pad cols 225-255 (QP#1 clobbered them)
#pragma unroll
    for (int rg = 0; rg < 4; ++rg)
#pragma unroll
        for (int k = 0; k < 15; ++k) {
            const int p = k * 16 + r16;
            if (p < 225) p_b[(kg * 4 + rg) * 264 + p] = f2b(ev[rg][k]);
        }
    for (int e = lane; e < 496; e += 64) {
        const int row = e / 31;
        p_b[row * 264 + 225 + (e - row * 31)] = 0;
    }

    // E) TvT into buf (overwrite Tk; rows=ch, cols=cells; zero Tk leftovers)
    {
        const u16x8 v = *(const u16x8*)(KV + texidx + 256);
#pragma unroll
        for (int j = 0; j < 8; ++j)
            buf[(ch8 + j) * 32 + cell] = ((const u16*)&v)[j];
        const int zr = lane & 15, zc0 = 16 + (lane >> 4) * 4;
#pragma unroll
        for (int j = 0; j < 4; ++j) buf[zr * 32 + zc0 + j] = 0;
    }

    // F) PW = P @ W : [16 q][16 cells] (8-chain MFMA)
    f32x4 pw = {0.f, 0.f, 0.f, 0.f};
#pragma unroll
    for (int ks = 0; ks < 8; ++ks) {
        const bf16x8 pa = *(const bf16x8*)(p_b + r16 * 264 + ks * 32 + kg * 8);
        const bf16x8 wb = *(const bf16x8*)(WmT + r16 * 264 + ks * 32 + kg * 8);
        pw = __builtin_amdgcn_mfma_f32_16x16x32_bf16(pa, wb, pw, 0, 0, 0);
    }

    // G) PW -> QP (overlay; re-zero pad cols 16-31 which now hold P data)
#pragma unroll
    for (int rg = 0; rg < 4; ++rg)
        QP[(kg * 4 + rg) * 40 + r16] = f2b(pw[rg]);
    {
        const int zq = lane & 15, zc0 = 16 + (lane >> 4) * 4;
#pragma unroll
        for (int j = 0; j < 4; ++j) QP[zq * 40 + zc0 + j] = 0;
    }

    // H) O = PW @ Tv^T (2 MFMA) ; I) /rowsum + cv, write
#pragma unroll
    for (int ct = 0; ct < 2; ++ct) {
        const bf16x8 pa = *(const bf16x8*)(QP + r16 * 40 + kg * 8);
        const bf16x8 vb = *(const bf16x8*)(buf + (ct * 16 + r16) * 32 + kg * 8);
        f32x4 ao = {0.f, 0.f, 0.f, 0.f};
        ao = __builtin_amdgcn_mfma_f32_16x16x32_bf16(pa, vb, ao, 0, 0, 0);
#pragma unroll
        for (int rg = 0; rg < 4; ++rg) {
            const int q = kg * 4 + rg;
            const int ch = h * 32 + ct * 16 + r16;
            const float val = ao[rg] / rowsumv[rg] + ckv[256 + ch];
            O[(size_t)(s * 16 + q) * 256 + ch] = f2b(val);
        }
    }
}

// ---------- output head: (8192,256) @ (4,256)^T + b ------------------------
__global__ LB void k_out(const float* __restrict__ X, const float* __restrict__ W,
                         const float* __restrict__ bias, float* __restrict__ O)
{
    __shared__ float w_s[4][260];
    const int t = threadIdx.x;
    for (int e = t; e < 1024; e += 256) w_s[e >> 8][e & 255] = W[e];
    __syncthreads();
    const int row = blockIdx.x * 64 + (t >> 2);
    const int j = t & 3;
    const float4* xr = (const float4*)(X + (size_t)row * 256);
    float acc = 0.0f;
#pragma unroll
    for (int k4 = 0; k4 < 64; ++k4) {
        const float4 x = xr[k4];
        acc += x.x * w_s[j][k4 * 4]     + x.y * w_s[j][k4 * 4 + 1]
             + x.z * w_s[j][k4 * 4 + 2] + x.w * w_s[j][k4 * 4 + 3];
    }
    O[(size_t)row * 4 + j] = acc + bias[j];
}

// ---------------------------------------------------------------------------
extern "C" void kernel_launch(void* const* d_in, const int* in_sizes, int n_in,
                              void* d_out, int out_size, void* d_ws, size_t ws_size,
                              hipStream_t stream)
{
    const float* img          = (const float*)d_in[0];
    const float* kps          = (const float*)d_in[1];
    const unsigned char* vmsk = (const unsigned char*)d_in[2];
    const float* proj_w       = (const float*)d_in[3];
    const float* proj_b       = (const float*)d_in[4];
    const float* query_embed  = (const float*)d_in[5];
    const float* self_qkv_w   = (const float*)d_in[6];
    const float* self_qkv_b   = (const float*)d_in[7];
    const float* self_out_w   = (const float*)d_in[8];
    const float* self_out_b   = (const float*)d_in[9];
    const float* cross_qkv_w  = (const float*)d_in[10];
    const float* cross_qkv_b  = (const float*)d_in[11];
    const float* cross_out_w  = (const float*)d_in[12];
    const float* cross_out_b  = (const float*)d_in[13];
    const float* ffn1_w       = (const float*)d_in[14];
    const float* ffn1_b       = (const float*)d_in[15];
    const float* ffn2_w       = (const float*)d_in[16];
    const float* ffn2_b       = (const float*)d_in[17];
    const float* ln1_w        = (const float*)d_in[18];
    const float* ln1_b        = (const float*)d_in[19];
    const float* ln2_w        = (const float*)d_in[20];
    const float* ln2_b        = (const float*)d_in[21];
    const float* ln3_w        = (const float*)d_in[22];
    const float* ln3_b        = (const float*)d_in[23];
    const float* out_w        = (const float*)d_in[24];
    const float* out_b        = (const float*)d_in[25];
    float* out = (float*)d_out;

    // ---- workspace layout (~88 MB) ----
    char* W8 = (char*)d_ws;
    size_t off = 0;
    auto alloc = [&](size_t bytes) { void* p = W8 + off; off += (bytes + 255) & ~(size_t)255; return p; };
    float* tgt   = (float*)alloc(2097152 * 4);
    u16* Qb      = (u16*)alloc(2097152 * 2);     // cross-Q bf16
    u16* Sb16    = (u16*)alloc(6291456 * 2);     // self-QKV bf16 [8192][768]
    float* ckv   = (float*)alloc(3 * 512 * 4);
    u16* imgTb   = (u16*)alloc(2097152 * 2);
    u16* imgPb   = (u16*)alloc(2097152 * 2);
    u16* KVb3    = (u16*)alloc(12582912 * 2);    // [8192][1536] all 3 layers K|V
    u16* tgtb    = (u16*)alloc(2097152 * 2);
    u16* Abuf    = (u16*)alloc(2097152 * 2);
    u16* Hbuf    = (u16*)alloc(8388608 * 2);
    u16* wAll    = (u16*)alloc(3604480 * 2);
    int* valid   = (int*)alloc(512 * 4);

    u16* wProj = wAll;             // 65536
    u16* wSQKV = wProj + 65536;    // 3*768*256
    u16* wSOut = wSQKV + 589824;   // 3*256*256
    u16* wCQKV = wSOut + 196608;   // 3*768*256
    u16* wCOut = wCQKV + 589824;   // 3*256*256
    u16* wF1   = wCOut + 196608;   // 3*1024*256
    u16* wF2   = wF1 + 786432;     // 3*256*1024
    u16* wCKV3 = wF2 + 786432;     // 3*512*256 contiguous cross K|V weights

    k_prep<<<4, 256, 0, stream>>>(vmsk, valid, proj_b, cross_qkv_w, cross_qkv_b, ckv);
    k_wconv<<<14080, 256, 0, stream>>>(proj_w, self_qkv_w, self_out_w, cross_qkv_w,
                                       cross_out_w, ffn1_w, ffn2_w, wAll);
    k_transpose<<<dim3(64, 4, 2), 256, 0, stream>>>(img, imgTb);
    gemm_mfma<64><<<dim3(2, 128), 256, 0, stream>>>(imgTb, wProj, nullptr,
                                                    nullptr, imgPb, 8192, 256, 256, 0);
    gemm_mfma<128><<<dim3(12, 64), 256, 0, stream>>>(imgPb, wCKV3, nullptr,
                                                     nullptr, KVb3, 8192, 1536, 256, 0);
    k_init_tgt<<<8192, 256, 0, stream>>>(tgt, tgtb, query_embed);

    for (int l = 0; l < 3; ++l) {
        // ---- self attention (QKV in bf16) ----
        gemm_mfma<128><<<dim3(6, 64), 256, 0, stream>>>(tgtb, wSQKV + (size_t)l * 196608,
            self_qkv_b + (size_t)l * 768, nullptr, Sb16, 8192, 768, 256, 0);
        k_self_attn<<<4096, 256, 0, stream>>>(Sb16, Abuf);
        gemm_ln<<<256, 256, 0, stream>>>(Abuf, wSOut + (size_t)l * 65536,
            self_out_b + (size_t)l * 256, tgt, tgtb,
            ln1_w + (size_t)l * 256, ln1_b + (size_t)l * 256, 256);

        // ---- cross attention ----
        gemm_mfma<64><<<dim3(2, 128), 256, 0, stream>>>(tgtb, wCQKV + (size_t)l * 196608,
            cross_qkv_b + (size_t)l * 768, nullptr, Qb, 8192, 256, 256, 0);
        k_cross_attn<<<1024, 256, 0, stream>>>(Qb, KVb3 + (size_t)l * 512, 1536,
                                               ckv + (size_t)l * 512, valid, kps, Abuf);
        gemm_ln<<<256, 256, 0, stream>>>(Abuf, wCOut + (size_t)l * 65536,
            cross_out_b + (size_t)l * 256, tgt, tgtb,
            ln2_w + (size_t)l * 256, ln2_b + (size_t)l * 256, 256);

        // ---- FFN ----
        gemm_mfma<128><<<dim3(8, 64), 256, 0, stream>>>(tgtb, wF1 + (size_t)l * 262144,
            ffn1_b + (size_t)l * 1024, nullptr, Hbuf, 8192, 1024, 256, 1);
        gemm_ln<<<256, 256, 0, stream>>>(Hbuf, wF2 + (size_t)l * 262144,
            ffn2_b + (size_t)l * 256, tgt, tgtb,
            ln3_w + (size_t)l * 256, ln3_b + (size_t)l * 256, 1024);
    }

    k_out<<<128, 256, 0, stream>>>(tgt, out_w, out_b, out);
}

// Round 16
// 382.643 us; speedup vs baseline: 1.2163x; 1.0639x over previous
//
#include <hip/hip_runtime.h>
#include <hip/hip_fp16.h>

#define LB __launch_bounds__(256)

typedef unsigned short u16;
typedef unsigned int   u32;
typedef __attribute__((ext_vector_type(8))) short bf16x8;   // 8 bf16 (4 VGPRs)
typedef __attribute__((ext_vector_type(4))) float f32x4;
typedef __attribute__((ext_vector_type(8))) u16  u16x8;

__device__ __forceinline__ u16 f2b(float f) {
    u32 u = __float_as_uint(f);
    u32 r = (u + 0x7fffu + ((u >> 16) & 1u)) >> 16;
    return (u16)r;
}
__device__ __forceinline__ float b2f(u16 h) {
    return __uint_as_float((u32)h << 16);
}

#define QSCALE 0.17677669529663687f

// ---------------------------------------------------------------------------
// B=2 N=256 C=256 HF=WF=64 ROI=15(225) HID=256 HEADS=8 Dh=32 DEPTH=3 FFN=1024
// NQ=16 -> seqs S=512, MT=8192.
// Cross-attn v2 (r15-verified): wave-per-head, in-wave MFMA chain, ck dropped.
// NEW r16: self-attn v2 wave-per-head (zero block barriers, 4 MFMA);
// selfQKV/ffn1 GEMMs switched to BM=64 for 3/CU / 4/CU balanced grids.
// ---------------------------------------------------------------------------

// ---------- fused prep: mask dtype detect + per-layer ck/cv ----------------
__global__ void k_prep(const unsigned char* __restrict__ m, int* __restrict__ valid,
                       const float* __restrict__ pb,
                       const float* __restrict__ cqkv_w,
                       const float* __restrict__ cqkv_b,
                       float* __restrict__ ckv)
{
    if (blockIdx.x == 0) {
        __shared__ int flag;
        if (threadIdx.x == 0) flag = 0;
        __syncthreads();
        int loc = 0;
        for (int off = threadIdx.x; off < 512; off += 256)
            if ((off & 3) != 0 && m[off] != 0) loc = 1;
        if (loc) atomicOr(&flag, 1);
        __syncthreads();
        const bool bytelay = (flag != 0);
        for (int s = threadIdx.x; s < 512; s += 256)
            valid[s] = bytelay ? (int)(m[s] != 0) : (int)(((const int*)m)[s] != 0);
    } else {
        const int l = blockIdx.x - 1;   // 0..2
        const float* Wk = cqkv_w + (size_t)l * 196608 + 65536;
        const float* Wv = cqkv_w + (size_t)l * 196608 + 131072;
        const float* kb = cqkv_b + (size_t)l * 768 + 256;
        const float* vb = cqkv_b + (size_t)l * 768 + 512;
        const int o = threadIdx.x;
        float a = 0.f, c = 0.f;
        for (int cc = 0; cc < 256; cc += 4) {
            const float4 p4 = *(const float4*)(pb + cc);
            const float4 k4 = *(const float4*)(Wk + (size_t)o * 256 + cc);
            const float4 v4 = *(const float4*)(Wv + (size_t)o * 256 + cc);
            a += p4.x * k4.x + p4.y * k4.y + p4.z * k4.z + p4.w * k4.w;
            c += p4.x * v4.x + p4.y * v4.y + p4.z * v4.z + p4.w * v4.w;
        }
        ckv[l * 512 + o]       = a + kb[o];   // ck (unused by cross v2; kept)
        ckv[l * 512 + 256 + o] = c + vb[o];   // cv (epilogue)
    }
}

// ---------- weights fp32 -> bf16 arena (+ contiguous cross-KV repack) ------
__global__ LB void k_wconv(const float* __restrict__ s0, const float* __restrict__ s1,
                           const float* __restrict__ s2, const float* __restrict__ s3,
                           const float* __restrict__ s4, const float* __restrict__ s5,
                           const float* __restrict__ s6, u16* __restrict__ dst)
{
    const int e = blockIdx.x * 256 + threadIdx.x;
    if (e >= 3604480) return;
    float v;
    int i = e;
    if (i < 65536) v = s0[i];
    else if ((i -= 65536) < 589824) v = s1[i];
    else if ((i -= 589824) < 196608) v = s2[i];
    else if ((i -= 196608) < 589824) v = s3[i];
    else if ((i -= 589824) < 196608) v = s4[i];
    else if ((i -= 196608) < 786432) v = s5[i];
    else if ((i -= 786432) < 786432) v = s6[i];
    else {  // wCKV3: [l][512 rows (Wk|Wv)][256] contiguous
        i -= 786432;
        const int l = i / 131072;
        const int r = (i - l * 131072) >> 8;
        const int c = i & 255;
        v = s3[(size_t)l * 196608 + (size_t)(256 + r) * 256 + c];
    }
    dst[e] = f2b(v);
}

// ---------- transpose image (B,C,64,64) -> (B,4096,C) bf16 -----------------
__global__ LB void k_transpose(const float* __restrict__ img, u16* __restrict__ imgTb)
{
    __shared__ float tile[64][65];
    const int b  = blockIdx.z;
    const int c0 = blockIdx.y * 64;
    const int p0 = blockIdx.x * 64;
    const int t  = threadIdx.x;
    const int tr = t >> 6, tc = t & 63;
#pragma unroll
    for (int p = 0; p < 16; ++p) {
        const int i = p * 4 + tr;
        tile[i][tc] = img[((size_t)(b * 256 + c0 + i)) * 4096 + p0 + tc];
    }
    __syncthreads();
#pragma unroll
    for (int p = 0; p < 16; ++p) {
        const int jj = p * 4 + tr;
        imgTb[((size_t)(b * 4096 + p0 + jj)) * 256 + c0 + tc] = f2b(tile[tc][jj]);
    }
}

// ---------- bf16 MFMA GEMM: C[M,N] = A[M,K](bf16) @ W[N,K](bf16)^T + bias --
template<int BM>
__global__ LB void gemm_mfma(const u16* __restrict__ A, const u16* __restrict__ W,
                             const float* __restrict__ bias,
                             float* __restrict__ Cf, u16* __restrict__ Cb,
                             int M, int N, int K, int relu)
{
    constexpr int BN = 128;
    __shared__ u16 lds[2][(BM + BN) * 64];
    const int t = threadIdx.x;
    const int wid = t >> 6, lane = t & 63;
    const int bm = blockIdx.y * BM, bn = blockIdx.x * BN;
    const int KT = K >> 6;

    auto stage = [&](int buf, int kt) {
        const int k0 = kt * 64;
        const int rr = t >> 3;
        const int u  = t & 7;
#pragma unroll
        for (int q = 0; q < BM / 32; ++q) {
            const int r = q * 32 + rr;
            const u16* src = A + (size_t)(bm + r) * K + k0 + ((u ^ (r & 7)) << 3);
            __builtin_amdgcn_global_load_lds(
                (const __attribute__((address_space(1))) void*)src,
                (__attribute__((address_space(3))) void*)&lds[buf][q * 2048 + wid * 512],
                16, 0, 0);
        }
#pragma unroll
        for (int q = 0; q < 4; ++q) {
            const int r = q * 32 + rr;
            const u16* src = W + (size_t)(bn + r) * K + k0 + ((u ^ (r & 7)) << 3);
            __builtin_amdgcn_global_load_lds(
                (const __attribute__((address_space(1))) void*)src,
                (__attribute__((address_space(3))) void*)&lds[buf][BM * 64 + q * 2048 + wid * 512],
                16, 0, 0);
        }
    };

    const int wr = wid >> 1, wc = wid & 1;
    constexpr int MR = BM / 32;
    f32x4 acc[MR][4];
    const f32x4 z = {0.f, 0.f, 0.f, 0.f};
#pragma unroll
    for (int mi = 0; mi < MR; ++mi)
#pragma unroll
        for (int ni = 0; ni < 4; ++ni) acc[mi][ni] = z;

    const int r16 = lane & 15, kg = lane >> 4;

    stage(0, 0);
    int cur = 0;
    for (int kt = 0; kt < KT; ++kt) {
        asm volatile("s_waitcnt vmcnt(0)" ::: "memory");
        __syncthreads();
        if (kt + 1 < KT) stage(cur ^ 1, kt + 1);
        const u16* pA = lds[cur];
        const u16* pB = lds[cur] + BM * 64;
#pragma unroll
        for (int kk = 0; kk < 2; ++kk) {
            const int s = kk * 4 + kg;
            bf16x8 afr[MR], bfr[4];
#pragma unroll
            for (int mi = 0; mi < MR; ++mi) {
                const int r = wr * (BM / 2) + mi * 16 + r16;
                afr[mi] = *(const bf16x8*)(pA + r * 64 + ((s ^ (r & 7)) << 3));
            }
#pragma unroll
            for (int ni = 0; ni < 4; ++ni) {
                const int c = wc * 64 + ni * 16 + r16;
                bfr[ni] = *(const bf16x8*)(pB + c * 64 + ((s ^ (c & 7)) << 3));
            }
#pragma unroll
            for (int mi = 0; mi < MR; ++mi)
#pragma unroll
                for (int ni = 0; ni < 4; ++ni)
                    acc[mi][ni] = __builtin_amdgcn_mfma_f32_16x16x32_bf16(
                        afr[mi], bfr[ni], acc[mi][ni], 0, 0, 0);
        }
        cur ^= 1;
    }

#pragma unroll
    for (int mi = 0; mi < MR; ++mi) {
#pragma unroll
        for (int ni = 0; ni < 4; ++ni) {
            const int col = bn + wc * 64 + ni * 16 + r16;
            const float bs = bias ? bias[col] : 0.0f;
#pragma unroll
            for (int rg = 0; rg < 4; ++rg) {
                const int row = bm + wr * (BM / 2) + mi * 16 + kg * 4 + rg;
                float v = acc[mi][ni][rg] + bs;
                if (relu) v = fmaxf(v, 0.0f);
                if (Cf) Cf[(size_t)row * N + col] = v;
                if (Cb) Cb[(size_t)row * N + col] = f2b(v);
            }
        }
    }
}

// ---------- fused GEMM + residual + LayerNorm ------------------------------
__global__ LB void gemm_ln(const u16* __restrict__ A, const u16* __restrict__ W,
                           const float* __restrict__ bias,
                           float* __restrict__ tgt, u16* __restrict__ tgtb,
                           const float* __restrict__ lnw, const float* __restrict__ lnb,
                           int K)
{
    __shared__ u16 lA[32 * 64];
    __shared__ u16 lB[256 * 64];
    __shared__ float psum[2][32];
    __shared__ float psq[2][32];
    const int t = threadIdx.x;
    const int wid = t >> 6, lane = t & 63;
    const int r16 = lane & 15, kg = lane >> 4;
    const int wr = wid >> 1, wc = wid & 1;
    const int bm = blockIdx.x * 32;
    const int KT = K >> 6;

    f32x4 acc[8];
    const f32x4 z = {0.f, 0.f, 0.f, 0.f};
#pragma unroll
    for (int ni = 0; ni < 8; ++ni) acc[ni] = z;

    for (int kt = 0; kt < KT; ++kt) {
        const int k0 = kt * 64;
        const int rr = t >> 3;
        const int u  = t & 7;
        {
            const int r = rr;
            const u16* src = A + (size_t)(bm + r) * K + k0 + ((u ^ (r & 7)) << 3);
            __builtin_amdgcn_global_load_lds(
                (const __attribute__((address_space(1))) void*)src,
                (__attribute__((address_space(3))) void*)&lA[wid * 512],
                16, 0, 0);
        }
#pragma unroll
        for (int q = 0; q < 8; ++q) {
            const int r = q * 32 + rr;
            const u16* src = W + (size_t)r * K + k0 + ((u ^ (r & 7)) << 3);
            __builtin_amdgcn_global_load_lds(
                (const __attribute__((address_space(1))) void*)src,
                (__attribute__((address_space(3))) void*)&lB[q * 2048 + wid * 512],
                16, 0, 0);
        }
        asm volatile("s_waitcnt vmcnt(0)" ::: "memory");
        __syncthreads();
#pragma unroll
        for (int kk = 0; kk < 2; ++kk) {
            const int s = kk * 4 + kg;
            const int ra = wr * 16 + r16;
            const bf16x8 afr = *(const bf16x8*)(lA + ra * 64 + ((s ^ (ra & 7)) << 3));
#pragma unroll
            for (int ni = 0; ni < 8; ++ni) {
                const int c = wc * 128 + ni * 16 + r16;
                const bf16x8 bfr = *(const bf16x8*)(lB + c * 64 + ((s ^ (c & 7)) << 3));
                acc[ni] = __builtin_amdgcn_mfma_f32_16x16x32_bf16(afr, bfr, acc[ni], 0, 0, 0);
            }
        }
        __syncthreads();
    }

    float xv[4][8];
    float bcol[8], wcol[8], bncol[8];
#pragma unroll
    for (int ni = 0; ni < 8; ++ni) {
        const int c = wc * 128 + ni * 16 + r16;
        bcol[ni]  = bias[c];
        wcol[ni]  = lnw[c];
        bncol[ni] = lnb[c];
    }
#pragma unroll
    for (int rg = 0; rg < 4; ++rg) {
        const int row = bm + wr * 16 + kg * 4 + rg;
#pragma unroll
        for (int ni = 0; ni < 8; ++ni) {
            const int c = wc * 128 + ni * 16 + r16;
            xv[rg][ni] = tgt[(size_t)row * 256 + c] + acc[ni][rg] + bcol[ni];
        }
    }
#pragma unroll
    for (int rg = 0; rg < 4; ++rg) {
        float s = 0.f;
#pragma unroll
        for (int ni = 0; ni < 8; ++ni) s += xv[rg][ni];
#pragma unroll
        for (int m = 1; m < 16; m <<= 1) s += __shfl_xor(s, m);
        if (r16 == 0) psum[wc][wr * 16 + kg * 4 + rg] = s;
    }
    __syncthreads();
    float mu[4];
#pragma unroll
    for (int rg = 0; rg < 4; ++rg) {
        const int rl = wr * 16 + kg * 4 + rg;
        mu[rg] = (psum[0][rl] + psum[1][rl]) * (1.0f / 256.0f);
    }
#pragma unroll
    for (int rg = 0; rg < 4; ++rg) {
        float q = 0.f;
#pragma unroll
        for (int ni = 0; ni < 8; ++ni) {
            const float d = xv[rg][ni] - mu[rg];
            q += d * d;
        }
#pragma unroll
        for (int m = 1; m < 16; m <<= 1) q += __shfl_xor(q, m);
        if (r16 == 0) psq[wc][wr * 16 + kg * 4 + rg] = q;
    }
    __syncthreads();
#pragma unroll
    for (int rg = 0; rg < 4; ++rg) {
        const int rl = wr * 16 + kg * 4 + rg;
        const int row = bm + rl;
        const float var = (psq[0][rl] + psq[1][rl]) * (1.0f / 256.0f);
        const float inv = 1.0f / sqrtf(var + 1e-5f);
#pragma unroll
        for (int ni = 0; ni < 8; ++ni) {
            const int c = wc * 128 + ni * 16 + r16;
            const float o = (xv[rg][ni] - mu[rg]) * inv * wcol[ni] + bncol[ni];
            tgt[(size_t)row * 256 + c]  = o;
            tgtb[(size_t)row * 256 + c] = f2b(o);
        }
    }
}

// ---------- init tgt (fp32 + bf16) -----------------------------------------
__global__ LB void k_init_tgt(float* __restrict__ tgt, u16* __restrict__ tgtb,
                              const float* __restrict__ qe)
{
    const int e = blockIdx.x * 256 + threadIdx.x;
    const int c = e & 255;
    const int row = e >> 8;
    const int i = row & 15;
    const float v = qe[(i << 8) | c];
    tgt[e] = v;
    tgtb[e] = f2b(v);
}

// ---------- self attention v2: wave-per-head, in-wave MFMA chain -----------
// grid 1024: s = blk>>1, h = (blk&1)*4 + wid. QKV bf16 [8192][768].
// S = mfma(Q,K) (1); 16-lane shuffle softmax; P via 1KB LDS; O = mfma(P,V^T).
__global__ LB void k_self_attn(const u16* __restrict__ QKV, u16* __restrict__ O)
{
    __shared__ __align__(16) u16 arena[4][1536];   // per wave: p_lds[16][32] | vT[32][32]
    const int t = threadIdx.x;
    const int lane = t & 63, wid = t >> 6;
    const int r16 = lane & 15, kg = lane >> 4;
    const int blk = blockIdx.x;
    const int s = blk >> 1;
    const int h = (blk & 1) * 4 + wid;

    u16* p_lds = &arena[wid][0];      // [16 q][32 k] (k 16..31 zero)
    u16* vT    = &arena[wid][512];    // [32 ch][32 k] (k 16..31 zero)

    // A) S = Q @ K^T : 1 MFMA, fragments straight from global
    const bf16x8 qfr = *(const bf16x8*)(QKV + (size_t)(s * 16 + r16) * 768 + h * 32 + kg * 8);
    const bf16x8 kfr = *(const bf16x8*)(QKV + (size_t)(s * 16 + r16) * 768 + 256 + h * 32 + kg * 8);
    f32x4 sv = {0.f, 0.f, 0.f, 0.f};
    sv = __builtin_amdgcn_mfma_f32_16x16x32_bf16(qfr, kfr, sv, 0, 0, 0);

    // B) softmax across 16 key-cols (r16 lanes), per row q = kg*4+rg
    float ev[4], rowsum[4];
#pragma unroll
    for (int rg = 0; rg < 4; ++rg) ev[rg] = sv[rg] * QSCALE;
#pragma unroll
    for (int rg = 0; rg < 4; ++rg) {
        float mx = ev[rg];
#pragma unroll
        for (int m = 1; m < 16; m <<= 1) mx = fmaxf(mx, __shfl_xor(mx, m));
        ev[rg] = __expf(ev[rg] - mx);
        float ps = ev[rg];
#pragma unroll
        for (int m = 1; m < 16; m <<= 1) ps += __shfl_xor(ps, m);
        rowsum[rg] = ps;
    }

    // C) P -> p_lds bf16 [q][k]; zero pad k=16..31. V^T stage [ch][k], pad 0.
#pragma unroll
    for (int rg = 0; rg < 4; ++rg)
        p_lds[(kg * 4 + rg) * 32 + r16] = f2b(ev[rg]);
    {
        const int zq = lane & 15, zc = 16 + (lane >> 4) * 4;
#pragma unroll
        for (int j = 0; j < 4; ++j) p_lds[zq * 32 + zc + j] = 0;
    }
    {
        const int key = lane >> 2, ch8 = (lane & 3) * 8;
        const u16x8 v = *(const u16x8*)(QKV + (size_t)(s * 16 + key) * 768 + 512 + h * 32 + ch8);
#pragma unroll
        for (int j = 0; j < 8; ++j)
            vT[(ch8 + j) * 32 + key] = ((const u16*)&v)[j];
        // zero keys 16..31: 32 ch x 16 = 512 entries / 64 lanes = 8 each
        const int zc0 = lane >> 1, zk0 = 16 + (lane & 1) * 8;
#pragma unroll
        for (int j = 0; j < 8; ++j) vT[zc0 * 32 + zk0 + j] = 0;
    }

    // D) O = P @ V^T : 2 MFMA; divide by rowsum, write
#pragma unroll
    for (int ct = 0; ct < 2; ++ct) {
        const bf16x8 pa = *(const bf16x8*)(p_lds + r16 * 32 + kg * 8);
        const bf16x8 vb = *(const bf16x8*)(vT + (ct * 16 + r16) * 32 + kg * 8);
        f32x4 ao = {0.f, 0.f, 0.f, 0.f};
        ao = __builtin_amdgcn_mfma_f32_16x16x32_bf16(pa, vb, ao, 0, 0, 0);
#pragma unroll
        for (int rg = 0; rg < 4; ++rg) {
            const int q = kg * 4 + rg;
            O[(size_t)(s * 16 + q) * 256 + h * 32 + ct * 16 + r16] = f2b(ao[rg] / rowsum[rg]);
        }
    }
}

// ---------- cross attention v2: wave-per-head, in-wave chain (r15) ---------
__global__ LB void k_cross_attn(const u16* __restrict__ Qb,
                                const u16* __restrict__ KV, int kvs,
                                const float* __restrict__ ckv,
                                const int* __restrict__ valid,
                                const float* __restrict__ kps,
                                u16* __restrict__ O)
{
    __shared__ __align__(16) char arena[64832];
    u16* Wm  = (u16*)arena;
    u16* WmT = (u16*)(arena + 14400);

    const int t = threadIdx.x;
    const int lane = t & 63, wid = t >> 6;
    const int r16 = lane & 15, kg = lane >> 4;
    const int blk = blockIdx.x;
    const int s = blk >> 1;
    const int h = (blk & 1) * 4 + wid;
    const int b = s >> 8, n = s & 255;

    u16* buf = (u16*)(arena + 22848 + wid * 10496);           // [32][32]
    u16* p_b = (u16*)(arena + 22848 + wid * 10496 + 2048);    // [16][264]
    u16* QP  = p_b;                                            // [16][40] overlay

    for (int e = t; e < 16208; e += 256) ((u32*)arena)[e] = 0;
    __syncthreads();

    const float kpy = kps[(b * 256 + n) * 2 + 0];
    const float kpx = kps[(b * 256 + n) * 2 + 1];
    const float gx0 = rintf(kpx) - 7.0f;
    const float gy0 = rintf(kpy) - 7.0f;
    const float gxn0 = gx0 / 511.0f * 2.0f - 1.0f;
    const float gyn0 = gy0 / 511.0f * 2.0f - 1.0f;
    const float xb = ((gxn0 + 1.f) * 64.f - 1.f) * 0.5f;
    const float yb = ((gyn0 + 1.f) * 64.f - 1.f) * 0.5f;
    const int x0b = (int)floorf(xb);
    const int y0b = (int)floorf(yb);

    if (t < 225) {
        const int iy = t / 15, ix = t - iy * 15;
        const float gy = rintf(kpy) + (float)(iy - 7);
        const float gx = rintf(kpx) + (float)(ix - 7);
        const float gxn = gx / 511.0f * 2.0f - 1.0f;
        const float gyn = gy / 511.0f * 2.0f - 1.0f;
        const bool inval = (gxn < -1.f) || (gyn < -1.f) || (gxn > 1.f) || (gyn > 1.f);
        const float x = ((gxn + 1.f) * 64.f - 1.f) * 0.5f;
        const float y = ((gyn + 1.f) * 64.f - 1.f) * 0.5f;
        const float x0f = floorf(x), y0f = floorf(y);
        const float wx = x - x0f, wy = y - y0f;
        const int x0 = (int)x0f, y0 = (int)y0f;
#pragma unroll
        for (int tt = 0; tt < 4; ++tt) {
            const int dy = tt >> 1, dx = tt & 1;
            const int yi = y0 + dy, xi = x0 + dx;
            const bool ok = (yi >= 0) && (yi < 64) && (xi >= 0) && (xi < 64) && !inval;
            const float w = (dy ? wy : 1.f - wy) * (dx ? wx : 1.f - wx);
            if (ok) {
                const int cell = (yi - y0b) * 4 + (xi - x0b);   // [0,16)
                const u16 wb = f2b(w);
                Wm[t * 32 + ((((cell >> 3) ^ (t & 3)) << 3) | (cell & 7))] = wb;
                WmT[cell * 264 + t] = wb;
            }
        }
    }
    const int cell = lane >> 2, ch8 = (lane & 3) * 8;
    const int cy = cell >> 2, cx = cell & 3;
    const int py = min(max(y0b + cy, 0), 63);
    const int px = min(max(x0b + cx, 0), 63);
    const size_t texidx = (size_t)(b * 4096 + py * 64 + px) * kvs + h * 32 + ch8;
    *(u16x8*)(buf + cell * 32 + ch8) = *(const u16x8*)(KV + texidx);
    const bool vld = valid[s] != 0;
    __syncthreads();

    // A) QT = Q @ Tk
    {
        const bf16x8 qfr = *(const bf16x8*)(Qb + (size_t)(s * 16 + r16) * 256 + h * 32 + kg * 8);
        const bf16x8 tfr = *(const bf16x8*)(buf + r16 * 32 + kg * 8);
        f32x4 aq = {0.f, 0.f, 0.f, 0.f};
        aq = __builtin_amdgcn_mfma_f32_16x16x32_bf16(qfr, tfr, aq, 0, 0, 0);
#pragma unroll
        for (int rg = 0; rg < 4; ++rg)
            QP[(kg * 4 + rg) * 40 + r16] = f2b(aq[rg]);
    }

    // B) S = QT @ Wm^T -> ev; C) in-register softmax
    float ev[4][15];
    {
        const bf16x8 afr = *(const bf16x8*)(QP + r16 * 40 + kg * 8);
#pragma unroll
        for (int tile = 0; tile < 15; ++tile) {
            const int p = tile * 16 + r16;
            const int rc = p < 225 ? p : 224;
            const bf16x8 bfr = *(const bf16x8*)(Wm + rc * 32 + ((kg ^ (rc & 3)) << 3));
            f32x4 acc = {0.f, 0.f, 0.f, 0.f};
            acc = __builtin_amdgcn_mfma_f32_16x16x32_bf16(afr, bfr, acc, 0, 0, 0);
#pragma unroll
            for (int rg = 0; rg < 4; ++rg) {
                float sv = acc[rg] * QSCALE;
                if (p > 224) sv = -1e30f;
                if (!vld && p > 0) sv = -1e30f;
                ev[rg][tile] = sv;
            }
        }
    }
    float rowsumv[4];
#pragma unroll
    for (int rg = 0; rg < 4; ++rg) {
        float mx = -1e30f;
#pragma unroll
        for (int k = 0; k < 15; ++k) mx = fmaxf(mx, ev[rg][k]);
#pragma unroll
        for (int m = 1; m < 16; m <<= 1) mx = fmaxf(mx, __shfl_xor(mx, m));
        float ps = 0.f;
#pragma unroll
        for (int k = 0; k < 15; ++k) {
            ev[rg][k] = __expf(ev[rg][k] - mx);
            ps += ev[rg][k];
        }
#pragma unroll
        for (int m = 1; m < 16; m <<= 1) ps += __shfl_xor(ps, m);
        rowsumv[rg] = ps;
    }

    // D) P -> p_b; re-zero pad cols 225-255
#pragma unroll
    for (int rg = 0; rg < 4; ++rg)
#pragma unroll
        for (int k = 0; k < 15; ++k) {
            const int p = k * 16 + r16;
            if (p < 225) p_b[(kg * 4 + rg) * 264 + p] = f2b(ev[rg][k]);
        }
    for (int e = lane; e < 496; e += 64) {
        const int row = e / 31;
        p_b[row * 264 + 225 + (e - row * 31)] = 0;
    }

    // E) TvT into buf (overwrite Tk; zero leftover cols)
    {
        const u16x8 v = *(const u16x8*)(KV + texidx + 256);
#pragma unroll
        for (int j = 0; j < 8; ++j)
            buf[(ch8 + j) * 32 + cell] = ((const u16*)&v)[j];
        const int zr = lane & 15, zc0 = 16 + (lane >> 4) * 4;
#pragma unroll
        for (int j = 0; j < 4; ++j) buf[zr * 32 + zc0 + j] = 0;
    }

    // F) PW = P @ W (8-chain)
    f32x4 pw = {0.f, 0.f, 0.f, 0.f};
#pragma unroll
    for (int ks = 0; ks < 8; ++ks) {
        const bf16x8 pa = *(const bf16x8*)(p_b + r16 * 264 + ks * 32 + kg * 8);
        const bf16x8 wb = *(const bf16x8*)(WmT + r16 * 264 + ks * 32 + kg * 8);
        pw = __builtin_amdgcn_mfma_f32_16x16x32_bf16(pa, wb, pw, 0, 0, 0);
    }

    // G) PW -> QP; re-zero pad cols 16-31
#pragma unroll
    for (int rg = 0; rg < 4; ++rg)
        QP[(kg * 4 + rg) * 40 + r16] = f2b(pw[rg]);
    {
        const int zq = lane & 15, zc0 = 16 + (lane >> 4) * 4;
#pragma unroll
        for (int j = 0; j < 4; ++j) QP[zq * 40 + zc0 + j] = 0;
    }

    // H) O = PW @ Tv^T ; I) /rowsum + cv, write
#pragma unroll
    for (int ct = 0; ct < 2; ++ct) {
        const bf16x8 pa = *(const bf16x8*)(QP + r16 * 40 + kg * 8);
        const bf16x8 vb = *(const bf16x8*)(buf + (ct * 16 + r16) * 32 + kg * 8);
        f32x4 ao = {0.f, 0.f, 0.f, 0.f};
        ao = __builtin_amdgcn_mfma_f32_16x16x32_bf16(pa, vb, ao, 0, 0, 0);
#pragma unroll
        for (int rg = 0; rg < 4; ++rg) {
            const int q = kg * 4 + rg;
            const int ch = h * 32 + ct * 16 + r16;
            const float val = ao[rg] / rowsumv[rg] + ckv[256 + ch];
            O[(size_t)(s * 16 + q) * 256 + ch] = f2b(val);
        }
    }
}

// ---------- output head: (8192,256) @ (4,256)^T + b ------------------------
__global__ LB void k_out(const float* __restrict__ X, const float* __restrict__ W,
                         const float* __restrict__ bias, float* __restrict__ O)
{
    __shared__ float w_s[4][260];
    const int t = threadIdx.x;
    for (int e = t; e < 1024; e += 256) w_s[e >> 8][e & 255] = W[e];
    __syncthreads();
    const int row = blockIdx.x * 64 + (t >> 2);
    const int j = t & 3;
    const float4* xr = (const float4*)(X + (size_t)row * 256);
    float acc = 0.0f;
#pragma unroll
    for (int k4 = 0; k4 < 64; ++k4) {
        const float4 x = xr[k4];
        acc += x.x * w_s[j][k4 * 4]     + x.y * w_s[j][k4 * 4 + 1]
             + x.z * w_s[j][k4 * 4 + 2] + x.w * w_s[j][k4 * 4 + 3];
    }
    O[(size_t)row * 4 + j] = acc + bias[j];
}

// ---------------------------------------------------------------------------
extern "C" void kernel_launch(void* const* d_in, const int* in_sizes, int n_in,
                              void* d_out, int out_size, void* d_ws, size_t ws_size,
                              hipStream_t stream)
{
    const float* img          = (const float*)d_in[0];
    const float* kps          = (const float*)d_in[1];
    const unsigned char* vmsk = (const unsigned char*)d_in[2];
    const float* proj_w       = (const float*)d_in[3];
    const float* proj_b       = (const float*)d_in[4];
    const float* query_embed  = (const float*)d_in[5];
    const float* self_qkv_w   = (const float*)d_in[6];
    const float* self_qkv_b   = (const float*)d_in[7];
    const float* self_out_w   = (const float*)d_in[8];
    const float* self_out_b   = (const float*)d_in[9];
    const float* cross_qkv_w  = (const float*)d_in[10];
    const float* cross_qkv_b  = (const float*)d_in[11];
    const float* cross_out_w  = (const float*)d_in[12];
    const float* cross_out_b  = (const float*)d_in[13];
    const float* ffn1_w       = (const float*)d_in[14];
    const float* ffn1_b       = (const float*)d_in[15];
    const float* ffn2_w       = (const float*)d_in[16];
    const float* ffn2_b       = (const float*)d_in[17];
    const float* ln1_w        = (const float*)d_in[18];
    const float* ln1_b        = (const float*)d_in[19];
    const float* ln2_w        = (const float*)d_in[20];
    const float* ln2_b        = (const float*)d_in[21];
    const float* ln3_w        = (const float*)d_in[22];
    const float* ln3_b        = (const float*)d_in[23];
    const float* out_w        = (const float*)d_in[24];
    const float* out_b        = (const float*)d_in[25];
    float* out = (float*)d_out;

    // ---- workspace layout (~88 MB) ----
    char* W8 = (char*)d_ws;
    size_t off = 0;
    auto alloc = [&](size_t bytes) { void* p = W8 + off; off += (bytes + 255) & ~(size_t)255; return p; };
    float* tgt   = (float*)alloc(2097152 * 4);
    u16* Qb      = (u16*)alloc(2097152 * 2);     // cross-Q bf16
    u16* Sb16    = (u16*)alloc(6291456 * 2);     // self-QKV bf16 [8192][768]
    float* ckv   = (float*)alloc(3 * 512 * 4);
    u16* imgTb   = (u16*)alloc(2097152 * 2);
    u16* imgPb   = (u16*)alloc(2097152 * 2);
    u16* KVb3    = (u16*)alloc(12582912 * 2);    // [8192][1536] all 3 layers K|V
    u16* tgtb    = (u16*)alloc(2097152 * 2);
    u16* Abuf    = (u16*)alloc(2097152 * 2);
    u16* Hbuf    = (u16*)alloc(8388608 * 2);
    u16* wAll    = (u16*)alloc(3604480 * 2);
    int* valid   = (int*)alloc(512 * 4);

    u16* wProj = wAll;             // 65536
    u16* wSQKV = wProj + 65536;    // 3*768*256
    u16* wSOut = wSQKV + 589824;   // 3*256*256
    u16* wCQKV = wSOut + 196608;   // 3*768*256
    u16* wCOut = wCQKV + 589824;   // 3*256*256
    u16* wF1   = wCOut + 196608;   // 3*1024*256
    u16* wF2   = wF1 + 786432;     // 3*256*1024
    u16* wCKV3 = wF2 + 786432;     // 3*512*256 contiguous cross K|V weights

    k_prep<<<4, 256, 0, stream>>>(vmsk, valid, proj_b, cross_qkv_w, cross_qkv_b, ckv);
    k_wconv<<<14080, 256, 0, stream>>>(proj_w, self_qkv_w, self_out_w, cross_qkv_w,
                                       cross_out_w, ffn1_w, ffn2_w, wAll);
    k_transpose<<<dim3(64, 4, 2), 256, 0, stream>>>(img, imgTb);
    gemm_mfma<64><<<dim3(2, 128), 256, 0, stream>>>(imgTb, wProj, nullptr,
                                                    nullptr, imgPb, 8192, 256, 256, 0);
    gemm_mfma<128><<<dim3(12, 64), 256, 0, stream>>>(imgPb, wCKV3, nullptr,
                                                     nullptr, KVb3, 8192, 1536, 256, 0);
    k_init_tgt<<<8192, 256, 0, stream>>>(tgt, tgtb, query_embed);

    for (int l = 0; l < 3; ++l) {
        // ---- self attention (QKV in bf16; BM=64 -> 3 blocks/CU) ----
        gemm_mfma<64><<<dim3(6, 128), 256, 0, stream>>>(tgtb, wSQKV + (size_t)l * 196608,
            self_qkv_b + (size_t)l * 768, nullptr, Sb16, 8192, 768, 256, 0);
        k_self_attn<<<1024, 256, 0, stream>>>(Sb16, Abuf);
        gemm_ln<<<256, 256, 0, stream>>>(Abuf, wSOut + (size_t)l * 65536,
            self_out_b + (size_t)l * 256, tgt, tgtb,
            ln1_w + (size_t)l * 256, ln1_b + (size_t)l * 256, 256);

        // ---- cross attention ----
        gemm_mfma<64><<<dim3(2, 128), 256, 0, stream>>>(tgtb, wCQKV + (size_t)l * 196608,
            cross_qkv_b + (size_t)l * 768, nullptr, Qb, 8192, 256, 256, 0);
        k_cross_attn<<<1024, 256, 0, stream>>>(Qb, KVb3 + (size_t)l * 512, 1536,
                                               ckv + (size_t)l * 512, valid, kps, Abuf);
        gemm_ln<<<256, 256, 0, stream>>>(Abuf, wCOut + (size_t)l * 65536,
            cross_out_b + (size_t)l * 256, tgt, tgtb,
            ln2_w + (size_t)l * 256, ln2_b + (size_t)l * 256, 256);

        // ---- FFN (ffn1 BM=64 -> 4 blocks/CU) ----
        gemm_mfma<64><<<dim3(8, 128), 256, 0, stream>>>(tgtb, wF1 + (size_t)l * 262144,
            ffn1_b + (size_t)l * 1024, nullptr, Hbuf, 8192, 1024, 256, 1);
        gemm_ln<<<256, 256, 0, stream>>>(Hbuf, wF2 + (size_t)l * 262144,
            ffn2_b + (size_t)l * 256, tgt, tgtb,
            ln3_w + (size_t)l * 256, ln3_b + (size_t)l * 256, 1024);
    }

    k_out<<<128, 256, 0, stream>>>(tgt, out_w, out_b, out);
}

// Round 17
// 378.322 us; speedup vs baseline: 1.2301x; 1.0114x over previous
//
#include <hip/hip_runtime.h>
#include <hip/hip_fp16.h>

#define LB __launch_bounds__(256)

typedef unsigned short u16;
typedef unsigned int   u32;
typedef __attribute__((ext_vector_type(8))) short bf16x8;   // 8 bf16 (4 VGPRs)
typedef __attribute__((ext_vector_type(4))) float f32x4;
typedef __attribute__((ext_vector_type(8))) u16  u16x8;

__device__ __forceinline__ u16 f2b(float f) {
    u32 u = __float_as_uint(f);
    u32 r = (u + 0x7fffu + ((u >> 16) & 1u)) >> 16;
    return (u16)r;
}
__device__ __forceinline__ float b2f(u16 h) {
    return __uint_as_float((u32)h << 16);
}

#define QSCALE 0.17677669529663687f

// ---------------------------------------------------------------------------
// B=2 N=256 C=256 HF=WF=64 ROI=15(225) HID=256 HEADS=8 Dh=32 DEPTH=3 FFN=1024
// NQ=16 -> seqs S=512, MT=8192.
// r17: proj folded into cross-KV weights (Wcomb = wCKV3 @ proj, one tiny
// weight GEMM; deletes the 8192-row proj GEMM); output head fused into the
// final gemm_ln (deletes k_out). Attention v2 kernels r15/r16-verified.
// ---------------------------------------------------------------------------

// ---------- fused prep: mask dtype detect + per-layer ck/cv ----------------
__global__ void k_prep(const unsigned char* __restrict__ m, int* __restrict__ valid,
                       const float* __restrict__ pb,
                       const float* __restrict__ cqkv_w,
                       const float* __restrict__ cqkv_b,
                       float* __restrict__ ckv)
{
    if (blockIdx.x == 0) {
        __shared__ int flag;
        if (threadIdx.x == 0) flag = 0;
        __syncthreads();
        int loc = 0;
        for (int off = threadIdx.x; off < 512; off += 256)
            if ((off & 3) != 0 && m[off] != 0) loc = 1;
        if (loc) atomicOr(&flag, 1);
        __syncthreads();
        const bool bytelay = (flag != 0);
        for (int s = threadIdx.x; s < 512; s += 256)
            valid[s] = bytelay ? (int)(m[s] != 0) : (int)(((const int*)m)[s] != 0);
    } else {
        const int l = blockIdx.x - 1;   // 0..2
        const float* Wk = cqkv_w + (size_t)l * 196608 + 65536;
        const float* Wv = cqkv_w + (size_t)l * 196608 + 131072;
        const float* kb = cqkv_b + (size_t)l * 768 + 256;
        const float* vb = cqkv_b + (size_t)l * 768 + 512;
        const int o = threadIdx.x;
        float a = 0.f, c = 0.f;
        for (int cc = 0; cc < 256; cc += 4) {
            const float4 p4 = *(const float4*)(pb + cc);
            const float4 k4 = *(const float4*)(Wk + (size_t)o * 256 + cc);
            const float4 v4 = *(const float4*)(Wv + (size_t)o * 256 + cc);
            a += p4.x * k4.x + p4.y * k4.y + p4.z * k4.z + p4.w * k4.w;
            c += p4.x * v4.x + p4.y * v4.y + p4.z * v4.z + p4.w * v4.w;
        }
        ckv[l * 512 + o]       = a + kb[o];   // ck (unused by cross v2; kept)
        ckv[l * 512 + 256 + o] = c + vb[o];   // cv (epilogue)
    }
}

// ---------- weights fp32 -> bf16 arena (+ cross-KV repack + projT) ---------
__global__ LB void k_wconv(const float* __restrict__ s0, const float* __restrict__ s1,
                           const float* __restrict__ s2, const float* __restrict__ s3,
                           const float* __restrict__ s4, const float* __restrict__ s5,
                           const float* __restrict__ s6, u16* __restrict__ dst)
{
    const int e = blockIdx.x * 256 + threadIdx.x;
    if (e >= 3670016) return;
    float v;
    int i = e;
    if (i < 65536) v = s0[i];
    else if ((i -= 65536) < 589824) v = s1[i];
    else if ((i -= 589824) < 196608) v = s2[i];
    else if ((i -= 196608) < 589824) v = s3[i];
    else if ((i -= 589824) < 196608) v = s4[i];
    else if ((i -= 196608) < 786432) v = s5[i];
    else if ((i -= 786432) < 786432) v = s6[i];
    else if ((i -= 786432) < 393216) {  // wCKV3: [l][512 rows (Wk|Wv)][256]
        const int l = i / 131072;
        const int r = (i - l * 131072) >> 8;
        const int c = i & 255;
        v = s3[(size_t)l * 196608 + (size_t)(256 + r) * 256 + c];
    } else {                            // projT: [c][o] = proj_w[o][c]
        i -= 393216;
        v = s0[(i & 255) * 256 + (i >> 8)];
    }
    dst[e] = f2b(v);
}

// ---------- transpose image (B,C,64,64) -> (B,4096,C) bf16 -----------------
__global__ LB void k_transpose(const float* __restrict__ img, u16* __restrict__ imgTb)
{
    __shared__ float tile[64][65];
    const int b  = blockIdx.z;
    const int c0 = blockIdx.y * 64;
    const int p0 = blockIdx.x * 64;
    const int t  = threadIdx.x;
    const int tr = t >> 6, tc = t & 63;
#pragma unroll
    for (int p = 0; p < 16; ++p) {
        const int i = p * 4 + tr;
        tile[i][tc] = img[((size_t)(b * 256 + c0 + i)) * 4096 + p0 + tc];
    }
    __syncthreads();
#pragma unroll
    for (int p = 0; p < 16; ++p) {
        const int jj = p * 4 + tr;
        imgTb[((size_t)(b * 4096 + p0 + jj)) * 256 + c0 + tc] = f2b(tile[tc][jj]);
    }
}

// ---------- bf16 MFMA GEMM: C[M,N] = A[M,K](bf16) @ W[N,K](bf16)^T + bias --
template<int BM>
__global__ LB void gemm_mfma(const u16* __restrict__ A, const u16* __restrict__ W,
                             const float* __restrict__ bias,
                             float* __restrict__ Cf, u16* __restrict__ Cb,
                             int M, int N, int K, int relu)
{
    constexpr int BN = 128;
    __shared__ u16 lds[2][(BM + BN) * 64];
    const int t = threadIdx.x;
    const int wid = t >> 6, lane = t & 63;
    const int bm = blockIdx.y * BM, bn = blockIdx.x * BN;
    const int KT = K >> 6;

    auto stage = [&](int buf, int kt) {
        const int k0 = kt * 64;
        const int rr = t >> 3;
        const int u  = t & 7;
#pragma unroll
        for (int q = 0; q < BM / 32; ++q) {
            const int r = q * 32 + rr;
            const u16* src = A + (size_t)(bm + r) * K + k0 + ((u ^ (r & 7)) << 3);
            __builtin_amdgcn_global_load_lds(
                (const __attribute__((address_space(1))) void*)src,
                (__attribute__((address_space(3))) void*)&lds[buf][q * 2048 + wid * 512],
                16, 0, 0);
        }
#pragma unroll
        for (int q = 0; q < 4; ++q) {
            const int r = q * 32 + rr;
            const u16* src = W + (size_t)(bn + r) * K + k0 + ((u ^ (r & 7)) << 3);
            __builtin_amdgcn_global_load_lds(
                (const __attribute__((address_space(1))) void*)src,
                (__attribute__((address_space(3))) void*)&lds[buf][BM * 64 + q * 2048 + wid * 512],
                16, 0, 0);
        }
    };

    const int wr = wid >> 1, wc = wid & 1;
    constexpr int MR = BM / 32;
    f32x4 acc[MR][4];
    const f32x4 z = {0.f, 0.f, 0.f, 0.f};
#pragma unroll
    for (int mi = 0; mi < MR; ++mi)
#pragma unroll
        for (int ni = 0; ni < 4; ++ni) acc[mi][ni] = z;

    const int r16 = lane & 15, kg = lane >> 4;

    stage(0, 0);
    int cur = 0;
    for (int kt = 0; kt < KT; ++kt) {
        asm volatile("s_waitcnt vmcnt(0)" ::: "memory");
        __syncthreads();
        if (kt + 1 < KT) stage(cur ^ 1, kt + 1);
        const u16* pA = lds[cur];
        const u16* pB = lds[cur] + BM * 64;
#pragma unroll
        for (int kk = 0; kk < 2; ++kk) {
            const int s = kk * 4 + kg;
            bf16x8 afr[MR], bfr[4];
#pragma unroll
            for (int mi = 0; mi < MR; ++mi) {
                const int r = wr * (BM / 2) + mi * 16 + r16;
                afr[mi] = *(const bf16x8*)(pA + r * 64 + ((s ^ (r & 7)) << 3));
            }
#pragma unroll
            for (int ni = 0; ni < 4; ++ni) {
                const int c = wc * 64 + ni * 16 + r16;
                bfr[ni] = *(const bf16x8*)(pB + c * 64 + ((s ^ (c & 7)) << 3));
            }
#pragma unroll
            for (int mi = 0; mi < MR; ++mi)
#pragma unroll
                for (int ni = 0; ni < 4; ++ni)
                    acc[mi][ni] = __builtin_amdgcn_mfma_f32_16x16x32_bf16(
                        afr[mi], bfr[ni], acc[mi][ni], 0, 0, 0);
        }
        cur ^= 1;
    }

#pragma unroll
    for (int mi = 0; mi < MR; ++mi) {
#pragma unroll
        for (int ni = 0; ni < 4; ++ni) {
            const int col = bn + wc * 64 + ni * 16 + r16;
            const float bs = bias ? bias[col] : 0.0f;
#pragma unroll
            for (int rg = 0; rg < 4; ++rg) {
                const int row = bm + wr * (BM / 2) + mi * 16 + kg * 4 + rg;
                float v = acc[mi][ni][rg] + bs;
                if (relu) v = fmaxf(v, 0.0f);
                if (Cf) Cf[(size_t)row * N + col] = v;
                if (Cb) Cb[(size_t)row * N + col] = f2b(v);
            }
        }
    }
}

// ---------- fused GEMM + residual + LayerNorm (+ optional output head) -----
__global__ LB void gemm_ln(const u16* __restrict__ A, const u16* __restrict__ W,
                           const float* __restrict__ bias,
                           float* __restrict__ tgt, u16* __restrict__ tgtb,
                           const float* __restrict__ lnw, const float* __restrict__ lnb,
                           int K,
                           const float* __restrict__ ow, const float* __restrict__ ob,
                           float* __restrict__ outp)
{
    __shared__ u16 lA[32 * 64];
    __shared__ u16 lB[256 * 64];
    __shared__ float psum[2][32];
    __shared__ float psq[2][32];
    __shared__ float hsum[2][32][4];
    const int t = threadIdx.x;
    const int wid = t >> 6, lane = t & 63;
    const int r16 = lane & 15, kg = lane >> 4;
    const int wr = wid >> 1, wc = wid & 1;
    const int bm = blockIdx.x * 32;
    const int KT = K >> 6;

    f32x4 acc[8];
    const f32x4 z = {0.f, 0.f, 0.f, 0.f};
#pragma unroll
    for (int ni = 0; ni < 8; ++ni) acc[ni] = z;

    for (int kt = 0; kt < KT; ++kt) {
        const int k0 = kt * 64;
        const int rr = t >> 3;
        const int u  = t & 7;
        {
            const int r = rr;
            const u16* src = A + (size_t)(bm + r) * K + k0 + ((u ^ (r & 7)) << 3);
            __builtin_amdgcn_global_load_lds(
                (const __attribute__((address_space(1))) void*)src,
                (__attribute__((address_space(3))) void*)&lA[wid * 512],
                16, 0, 0);
        }
#pragma unroll
        for (int q = 0; q < 8; ++q) {
            const int r = q * 32 + rr;
            const u16* src = W + (size_t)r * K + k0 + ((u ^ (r & 7)) << 3);
            __builtin_amdgcn_global_load_lds(
                (const __attribute__((address_space(1))) void*)src,
                (__attribute__((address_space(3))) void*)&lB[q * 2048 + wid * 512],
                16, 0, 0);
        }
        asm volatile("s_waitcnt vmcnt(0)" ::: "memory");
        __syncthreads();
#pragma unroll
        for (int kk = 0; kk < 2; ++kk) {
            const int s = kk * 4 + kg;
            const int ra = wr * 16 + r16;
            const bf16x8 afr = *(const bf16x8*)(lA + ra * 64 + ((s ^ (ra & 7)) << 3));
#pragma unroll
            for (int ni = 0; ni < 8; ++ni) {
                const int c = wc * 128 + ni * 16 + r16;
                const bf16x8 bfr = *(const bf16x8*)(lB + c * 64 + ((s ^ (c & 7)) << 3));
                acc[ni] = __builtin_amdgcn_mfma_f32_16x16x32_bf16(afr, bfr, acc[ni], 0, 0, 0);
            }
        }
        __syncthreads();
    }

    float xv[4][8];
    float bcol[8], wcol[8], bncol[8];
#pragma unroll
    for (int ni = 0; ni < 8; ++ni) {
        const int c = wc * 128 + ni * 16 + r16;
        bcol[ni]  = bias[c];
        wcol[ni]  = lnw[c];
        bncol[ni] = lnb[c];
    }
#pragma unroll
    for (int rg = 0; rg < 4; ++rg) {
        const int row = bm + wr * 16 + kg * 4 + rg;
#pragma unroll
        for (int ni = 0; ni < 8; ++ni) {
            const int c = wc * 128 + ni * 16 + r16;
            xv[rg][ni] = tgt[(size_t)row * 256 + c] + acc[ni][rg] + bcol[ni];
        }
    }
#pragma unroll
    for (int rg = 0; rg < 4; ++rg) {
        float s = 0.f;
#pragma unroll
        for (int ni = 0; ni < 8; ++ni) s += xv[rg][ni];
#pragma unroll
        for (int m = 1; m < 16; m <<= 1) s += __shfl_xor(s, m);
        if (r16 == 0) psum[wc][wr * 16 + kg * 4 + rg] = s;
    }
    __syncthreads();
    float mu[4];
#pragma unroll
    for (int rg = 0; rg < 4; ++rg) {
        const int rl = wr * 16 + kg * 4 + rg;
        mu[rg] = (psum[0][rl] + psum[1][rl]) * (1.0f / 256.0f);
    }
#pragma unroll
    for (int rg = 0; rg < 4; ++rg) {
        float q = 0.f;
#pragma unroll
        for (int ni = 0; ni < 8; ++ni) {
            const float d = xv[rg][ni] - mu[rg];
            q += d * d;
        }
#pragma unroll
        for (int m = 1; m < 16; m <<= 1) q += __shfl_xor(q, m);
        if (r16 == 0) psq[wc][wr * 16 + kg * 4 + rg] = q;
    }
    __syncthreads();
    float onorm[4][8];
#pragma unroll
    for (int rg = 0; rg < 4; ++rg) {
        const int rl = wr * 16 + kg * 4 + rg;
        const int row = bm + rl;
        const float var = (psq[0][rl] + psq[1][rl]) * (1.0f / 256.0f);
        const float inv = 1.0f / sqrtf(var + 1e-5f);
#pragma unroll
        for (int ni = 0; ni < 8; ++ni) {
            const int c = wc * 128 + ni * 16 + r16;
            const float o = (xv[rg][ni] - mu[rg]) * inv * wcol[ni] + bncol[ni];
            onorm[rg][ni] = o;
            tgt[(size_t)row * 256 + c]  = o;
            tgtb[(size_t)row * 256 + c] = f2b(o);
        }
    }

    // ---- optional fused output head: out[row][j] = o . ow[j] + ob[j] ----
    if (outp) {
#pragma unroll
        for (int j = 0; j < 4; ++j) {
            float wj[8];
#pragma unroll
            for (int ni = 0; ni < 8; ++ni)
                wj[ni] = ow[j * 256 + wc * 128 + ni * 16 + r16];
#pragma unroll
            for (int rg = 0; rg < 4; ++rg) {
                float p = 0.f;
#pragma unroll
                for (int ni = 0; ni < 8; ++ni) p += onorm[rg][ni] * wj[ni];
#pragma unroll
                for (int m = 1; m < 16; m <<= 1) p += __shfl_xor(p, m);
                if (r16 == 0) hsum[wc][wr * 16 + kg * 4 + rg][j] = p;
            }
        }
        __syncthreads();
        if (t < 128) {
            const int row = t >> 2, j = t & 3;
            outp[(size_t)(bm + row) * 4 + j] =
                hsum[0][row][j] + hsum[1][row][j] + ob[j];
        }
    }
}

// ---------- init tgt (fp32 + bf16) -----------------------------------------
__global__ LB void k_init_tgt(float* __restrict__ tgt, u16* __restrict__ tgtb,
                              const float* __restrict__ qe)
{
    const int e = blockIdx.x * 256 + threadIdx.x;
    const int c = e & 255;
    const int row = e >> 8;
    const int i = row & 15;
    const float v = qe[(i << 8) | c];
    tgt[e] = v;
    tgtb[e] = f2b(v);
}

// ---------- self attention v2: wave-per-head, in-wave MFMA chain -----------
__global__ LB void k_self_attn(const u16* __restrict__ QKV, u16* __restrict__ O)
{
    __shared__ __align__(16) u16 arena[4][1536];   // per wave: p_lds[16][32] | vT[32][32]
    const int t = threadIdx.x;
    const int lane = t & 63, wid = t >> 6;
    const int r16 = lane & 15, kg = lane >> 4;
    const int blk = blockIdx.x;
    const int s = blk >> 1;
    const int h = (blk & 1) * 4 + wid;

    u16* p_lds = &arena[wid][0];
    u16* vT    = &arena[wid][512];

    const bf16x8 qfr = *(const bf16x8*)(QKV + (size_t)(s * 16 + r16) * 768 + h * 32 + kg * 8);
    const bf16x8 kfr = *(const bf16x8*)(QKV + (size_t)(s * 16 + r16) * 768 + 256 + h * 32 + kg * 8);
    f32x4 sv = {0.f, 0.f, 0.f, 0.f};
    sv = __builtin_amdgcn_mfma_f32_16x16x32_bf16(qfr, kfr, sv, 0, 0, 0);

    float ev[4], rowsum[4];
#pragma unroll
    for (int rg = 0; rg < 4; ++rg) ev[rg] = sv[rg] * QSCALE;
#pragma unroll
    for (int rg = 0; rg < 4; ++rg) {
        float mx = ev[rg];
#pragma unroll
        for (int m = 1; m < 16; m <<= 1) mx = fmaxf(mx, __shfl_xor(mx, m));
        ev[rg] = __expf(ev[rg] - mx);
        float ps = ev[rg];
#pragma unroll
        for (int m = 1; m < 16; m <<= 1) ps += __shfl_xor(ps, m);
        rowsum[rg] = ps;
    }

#pragma unroll
    for (int rg = 0; rg < 4; ++rg)
        p_lds[(kg * 4 + rg) * 32 + r16] = f2b(ev[rg]);
    {
        const int zq = lane & 15, zc = 16 + (lane >> 4) * 4;
#pragma unroll
        for (int j = 0; j < 4; ++j) p_lds[zq * 32 + zc + j] = 0;
    }
    {
        const int key = lane >> 2, ch8 = (lane & 3) * 8;
        const u16x8 v = *(const u16x8*)(QKV + (size_t)(s * 16 + key) * 768 + 512 + h * 32 + ch8);
#pragma unroll
        for (int j = 0; j < 8; ++j)
            vT[(ch8 + j) * 32 + key] = ((const u16*)&v)[j];
        const int zc0 = lane >> 1, zk0 = 16 + (lane & 1) * 8;
#pragma unroll
        for (int j = 0; j < 8; ++j) vT[zc0 * 32 + zk0 + j] = 0;
    }

#pragma unroll
    for (int ct = 0; ct < 2; ++ct) {
        const bf16x8 pa = *(const bf16x8*)(p_lds + r16 * 32 + kg * 8);
        const bf16x8 vb = *(const bf16x8*)(vT + (ct * 16 + r16) * 32 + kg * 8);
        f32x4 ao = {0.f, 0.f, 0.f, 0.f};
        ao = __builtin_amdgcn_mfma_f32_16x16x32_bf16(pa, vb, ao, 0, 0, 0);
#pragma unroll
        for (int rg = 0; rg < 4; ++rg) {
            const int q = kg * 4 + rg;
            O[(size_t)(s * 16 + q) * 256 + h * 32 + ct * 16 + r16] = f2b(ao[rg] / rowsum[rg]);
        }
    }
}

// ---------- cross attention v2: wave-per-head, in-wave chain (r15) ---------
__global__ LB void k_cross_attn(const u16* __restrict__ Qb,
                                const u16* __restrict__ KV, int kvs,
                                const float* __restrict__ ckv,
                                const int* __restrict__ valid,
                                const float* __restrict__ kps,
                                u16* __restrict__ O)
{
    __shared__ __align__(16) char arena[64832];
    u16* Wm  = (u16*)arena;
    u16* WmT = (u16*)(arena + 14400);

    const int t = threadIdx.x;
    const int lane = t & 63, wid = t >> 6;
    const int r16 = lane & 15, kg = lane >> 4;
    const int blk = blockIdx.x;
    const int s = blk >> 1;
    const int h = (blk & 1) * 4 + wid;
    const int b = s >> 8, n = s & 255;

    u16* buf = (u16*)(arena + 22848 + wid * 10496);
    u16* p_b = (u16*)(arena + 22848 + wid * 10496 + 2048);
    u16* QP  = p_b;

    for (int e = t; e < 16208; e += 256) ((u32*)arena)[e] = 0;
    __syncthreads();

    const float kpy = kps[(b * 256 + n) * 2 + 0];
    const float kpx = kps[(b * 256 + n) * 2 + 1];
    const float gx0 = rintf(kpx) - 7.0f;
    const float gy0 = rintf(kpy) - 7.0f;
    const float gxn0 = gx0 / 511.0f * 2.0f - 1.0f;
    const float gyn0 = gy0 / 511.0f * 2.0f - 1.0f;
    const float xb = ((gxn0 + 1.f) * 64.f - 1.f) * 0.5f;
    const float yb = ((gyn0 + 1.f) * 64.f - 1.f) * 0.5f;
    const int x0b = (int)floorf(xb);
    const int y0b = (int)floorf(yb);

    if (t < 225) {
        const int iy = t / 15, ix = t - iy * 15;
        const float gy = rintf(kpy) + (float)(iy - 7);
        const float gx = rintf(kpx) + (float)(ix - 7);
        const float gxn = gx / 511.0f * 2.0f - 1.0f;
        const float gyn = gy / 511.0f * 2.0f - 1.0f;
        const bool inval = (gxn < -1.f) || (gyn < -1.f) || (gxn > 1.f) || (gyn > 1.f);
        const float x = ((gxn + 1.f) * 64.f - 1.f) * 0.5f;
        const float y = ((gyn + 1.f) * 64.f - 1.f) * 0.5f;
        const float x0f = floorf(x), y0f = floorf(y);
        const float wx = x - x0f, wy = y - y0f;
        const int x0 = (int)x0f, y0 = (int)y0f;
#pragma unroll
        for (int tt = 0; tt < 4; ++tt) {
            const int dy = tt >> 1, dx = tt & 1;
            const int yi = y0 + dy, xi = x0 + dx;
            const bool ok = (yi >= 0) && (yi < 64) && (xi >= 0) && (xi < 64) && !inval;
            const float w = (dy ? wy : 1.f - wy) * (dx ? wx : 1.f - wx);
            if (ok) {
                const int cell = (yi - y0b) * 4 + (xi - x0b);
                const u16 wb = f2b(w);
                Wm[t * 32 + ((((cell >> 3) ^ (t & 3)) << 3) | (cell & 7))] = wb;
                WmT[cell * 264 + t] = wb;
            }
        }
    }
    const int cell = lane >> 2, ch8 = (lane & 3) * 8;
    const int cy = cell >> 2, cx = cell & 3;
    const int py = min(max(y0b + cy, 0), 63);
    const int px = min(max(x0b + cx, 0), 63);
    const size_t texidx = (size_t)(b * 4096 + py * 64 + px) * kvs + h * 32 + ch8;
    *(u16x8*)(buf + cell * 32 + ch8) = *(const u16x8*)(KV + texidx);
    const bool vld = valid[s] != 0;
    __syncthreads();

    {
        const bf16x8 qfr = *(const bf16x8*)(Qb + (size_t)(s * 16 + r16) * 256 + h * 32 + kg * 8);
        const bf16x8 tfr = *(const bf16x8*)(buf + r16 * 32 + kg * 8);
        f32x4 aq = {0.f, 0.f, 0.f, 0.f};
        aq = __builtin_amdgcn_mfma_f32_16x16x32_bf16(qfr, tfr, aq, 0, 0, 0);
#pragma unroll
        for (int rg = 0; rg < 4; ++rg)
            QP[(kg * 4 + rg) * 40 + r16] = f2b(aq[rg]);
    }

    float ev[4][15];
    {
        const bf16x8 afr = *(const bf16x8*)(QP + r16 * 40 + kg * 8);
#pragma unroll
        for (int tile = 0; tile < 15; ++tile) {
            const int p = tile * 16 + r16;
            const int rc = p < 225 ? p : 224;
            const bf16x8 bfr = *(const bf16x8*)(Wm + rc * 32 + ((kg ^ (rc & 3)) << 3));
            f32x4 acc = {0.f, 0.f, 0.f, 0.f};
            acc = __builtin_amdgcn_mfma_f32_16x16x32_bf16(afr, bfr, acc, 0, 0, 0);
#pragma unroll
            for (int rg = 0; rg < 4; ++rg) {
                float sv = acc[rg] * QSCALE;
                if (p > 224) sv = -1e30f;
                if (!vld && p > 0) sv = -1e30f;
                ev[rg][tile] = sv;
            }
        }
    }
    float rowsumv[4];
#pragma unroll
    for (int rg = 0; rg < 4; ++rg) {
        float mx = -1e30f;
#pragma unroll
        for (int k = 0; k < 15; ++k) mx = fmaxf(mx, ev[rg][k]);
#pragma unroll
        for (int m = 1; m < 16; m <<= 1) mx = fmaxf(mx, __shfl_xor(mx, m));
        float ps = 0.f;
#pragma unroll
        for (int k = 0; k < 15; ++k) {
            ev[rg][k] = __expf(ev[rg][k] - mx);
            ps += ev[rg][k];
        }
#pragma unroll
        for (int m = 1; m < 16; m <<= 1) ps += __shfl_xor(ps, m);
        rowsumv[rg] = ps;
    }

#pragma unroll
    for (int rg = 0; rg < 4; ++rg)
#pragma unroll
        for (int k = 0; k < 15; ++k) {
            const int p = k * 16 + r16;
            if (p < 225) p_b[(kg * 4 + rg) * 264 + p] = f2b(ev[rg][k]);
        }
    for (int e = lane; e < 496; e += 64) {
        const int row = e / 31;
        p_b[row * 264 + 225 + (e - row * 31)] = 0;
    }

    {
        const u16x8 v = *(const u16x8*)(KV + texidx + 256);
#pragma unroll
        for (int j = 0; j < 8; ++j)
            buf[(ch8 + j) * 32 + cell] = ((const u16*)&v)[j];
        const int zr = lane & 15, zc0 = 16 + (lane >> 4) * 4;
#pragma unroll
        for (int j = 0; j < 4; ++j) buf[zr * 32 + zc0 + j] = 0;
    }

    f32x4 pw = {0.f, 0.f, 0.f, 0.f};
#pragma unroll
    for (int ks = 0; ks < 8; ++ks) {
        const bf16x8 pa = *(const bf16x8*)(p_b + r16 * 264 + ks * 32 + kg * 8);
        const bf16x8 wb = *(const bf16x8*)(WmT + r16 * 264 + ks * 32 + kg * 8);
        pw = __builtin_amdgcn_mfma_f32_16x16x32_bf16(pa, wb, pw, 0, 0, 0);
    }

#pragma unroll
    for (int rg = 0; rg < 4; ++rg)
        QP[(kg * 4 + rg) * 40 + r16] = f2b(pw[rg]);
    {
        const int zq = lane & 15, zc0 = 16 + (lane >> 4) * 4;
#pragma unroll
        for (int j = 0; j < 4; ++j) QP[zq * 40 + zc0 + j] = 0;
    }

#pragma unroll
    for (int ct = 0; ct < 2; ++ct) {
        const bf16x8 pa = *(const bf16x8*)(QP + r16 * 40 + kg * 8);
        const bf16x8 vb = *(const bf16x8*)(buf + (ct * 16 + r16) * 32 + kg * 8);
        f32x4 ao = {0.f, 0.f, 0.f, 0.f};
        ao = __builtin_amdgcn_mfma_f32_16x16x32_bf16(pa, vb, ao, 0, 0, 0);
#pragma unroll
        for (int rg = 0; rg < 4; ++rg) {
            const int q = kg * 4 + rg;
            const int ch = h * 32 + ct * 16 + r16;
            const float val = ao[rg] / rowsumv[rg] + ckv[256 + ch];
            O[(size_t)(s * 16 + q) * 256 + ch] = f2b(val);
        }
    }
}

// ---------------------------------------------------------------------------
extern "C" void kernel_launch(void* const* d_in, const int* in_sizes, int n_in,
                              void* d_out, int out_size, void* d_ws, size_t ws_size,
                              hipStream_t stream)
{
    const float* img          = (const float*)d_in[0];
    const float* kps          = (const float*)d_in[1];
    const unsigned char* vmsk = (const unsigned char*)d_in[2];
    const float* proj_w       = (const float*)d_in[3];
    const float* proj_b       = (const float*)d_in[4];
    const float* query_embed  = (const float*)d_in[5];
    const float* self_qkv_w   = (const float*)d_in[6];
    const float* self_qkv_b   = (const float*)d_in[7];
    const float* self_out_w   = (const float*)d_in[8];
    const float* self_out_b   = (const float*)d_in[9];
    const float* cross_qkv_w  = (const float*)d_in[10];
    const float* cross_qkv_b  = (const float*)d_in[11];
    const float* cross_out_w  = (const float*)d_in[12];
    const float* cross_out_b  = (const float*)d_in[13];
    const float* ffn1_w       = (const float*)d_in[14];
    const float* ffn1_b       = (const float*)d_in[15];
    const float* ffn2_w       = (const float*)d_in[16];
    const float* ffn2_b       = (const float*)d_in[17];
    const float* ln1_w        = (const float*)d_in[18];
    const float* ln1_b        = (const float*)d_in[19];
    const float* ln2_w        = (const float*)d_in[20];
    const float* ln2_b        = (const float*)d_in[21];
    const float* ln3_w        = (const float*)d_in[22];
    const float* ln3_b        = (const float*)d_in[23];
    const float* out_w        = (const float*)d_in[24];
    const float* out_b        = (const float*)d_in[25];
    float* out = (float*)d_out;

    // ---- workspace layout (~84 MB) ----
    char* W8 = (char*)d_ws;
    size_t off = 0;
    auto alloc = [&](size_t bytes) { void* p = W8 + off; off += (bytes + 255) & ~(size_t)255; return p; };
    float* tgt   = (float*)alloc(2097152 * 4);
    u16* Qb      = (u16*)alloc(2097152 * 2);     // cross-Q bf16
    u16* Sb16    = (u16*)alloc(6291456 * 2);     // self-QKV bf16 [8192][768]
    float* ckv   = (float*)alloc(3 * 512 * 4);
    u16* imgTb   = (u16*)alloc(2097152 * 2);
    u16* KVb3    = (u16*)alloc(12582912 * 2);    // [8192][1536] all 3 layers K|V
    u16* tgtb    = (u16*)alloc(2097152 * 2);
    u16* Abuf    = (u16*)alloc(2097152 * 2);
    u16* Hbuf    = (u16*)alloc(8388608 * 2);
    u16* wAll    = (u16*)alloc(3670016 * 2);
    u16* WcombB  = (u16*)alloc(393216 * 2);      // (wCKV3 @ proj)^T-form weights
    int* valid   = (int*)alloc(512 * 4);

    u16* wProj  = wAll;             // 65536 (unused directly now; kept for layout)
    u16* wSQKV  = wProj + 65536;    // 3*768*256
    u16* wSOut  = wSQKV + 589824;   // 3*256*256
    u16* wCQKV  = wSOut + 196608;   // 3*768*256
    u16* wCOut  = wCQKV + 589824;   // 3*256*256
    u16* wF1    = wCOut + 196608;   // 3*1024*256
    u16* wF2    = wF1 + 786432;     // 3*256*1024
    u16* wCKV3  = wF2 + 786432;     // 3*512*256 cross K|V weights
    u16* wProjT = wCKV3 + 393216;   // 256*256 proj^T

    k_prep<<<4, 256, 0, stream>>>(vmsk, valid, proj_b, cross_qkv_w, cross_qkv_b, ckv);
    k_wconv<<<14336, 256, 0, stream>>>(proj_w, self_qkv_w, self_out_w, cross_qkv_w,
                                       cross_out_w, ffn1_w, ffn2_w, wAll);
    k_transpose<<<dim3(64, 4, 2), 256, 0, stream>>>(img, imgTb);
    // Wcomb[n][c] = sum_o wCKV3[n][o] * proj_w[o][c]  (proj folded into KV)
    gemm_mfma<64><<<dim3(2, 24), 256, 0, stream>>>(wCKV3, wProjT, nullptr,
                                                   nullptr, WcombB, 1536, 256, 256, 0);
    // all 3 layers' KV projections straight from imgT (one N=1536 GEMM)
    gemm_mfma<128><<<dim3(12, 64), 256, 0, stream>>>(imgTb, WcombB, nullptr,
                                                     nullptr, KVb3, 8192, 1536, 256, 0);
    k_init_tgt<<<8192, 256, 0, stream>>>(tgt, tgtb, query_embed);

    for (int l = 0; l < 3; ++l) {
        const int last = (l == 2);
        // ---- self attention ----
        gemm_mfma<64><<<dim3(6, 128), 256, 0, stream>>>(tgtb, wSQKV + (size_t)l * 196608,
            self_qkv_b + (size_t)l * 768, nullptr, Sb16, 8192, 768, 256, 0);
        k_self_attn<<<1024, 256, 0, stream>>>(Sb16, Abuf);
        gemm_ln<<<256, 256, 0, stream>>>(Abuf, wSOut + (size_t)l * 65536,
            self_out_b + (size_t)l * 256, tgt, tgtb,
            ln1_w + (size_t)l * 256, ln1_b + (size_t)l * 256, 256,
            nullptr, nullptr, nullptr);

        // ---- cross attention ----
        gemm_mfma<64><<<dim3(2, 128), 256, 0, stream>>>(tgtb, wCQKV + (size_t)l * 196608,
            cross_qkv_b + (size_t)l * 768, nullptr, Qb, 8192, 256, 256, 0);
        k_cross_attn<<<1024, 256, 0, stream>>>(Qb, KVb3 + (size_t)l * 512, 1536,
                                               ckv + (size_t)l * 512, valid, kps, Abuf);
        gemm_ln<<<256, 256, 0, stream>>>(Abuf, wCOut + (size_t)l * 65536,
            cross_out_b + (size_t)l * 256, tgt, tgtb,
            ln2_w + (size_t)l * 256, ln2_b + (size_t)l * 256, 256,
            nullptr, nullptr, nullptr);

        // ---- FFN (final layer fuses the output head) ----
        gemm_mfma<64><<<dim3(8, 128), 256, 0, stream>>>(tgtb, wF1 + (size_t)l * 262144,
            ffn1_b + (size_t)l * 1024, nullptr, Hbuf, 8192, 1024, 256, 1);
        gemm_ln<<<256, 256, 0, stream>>>(Hbuf, wF2 + (size_t)l * 262144,
            ffn2_b + (size_t)l * 256, tgt, tgtb,
            ln3_w + (size_t)l * 256, ln3_b + (size_t)l * 256, 1024,
            last ? out_w : nullptr, last ? out_b : nullptr, last ? out : nullptr);
    }
}

// Round 18
// 370.951 us; speedup vs baseline: 1.2546x; 1.0199x over previous
//
#include <hip/hip_runtime.h>
#include <hip/hip_fp16.h>

#define LB __launch_bounds__(256)

typedef unsigned short u16;
typedef unsigned int   u32;
typedef __attribute__((ext_vector_type(8))) short bf16x8;   // 8 bf16 (4 VGPRs)
typedef __attribute__((ext_vector_type(4))) float f32x4;
typedef __attribute__((ext_vector_type(8))) u16  u16x8;

__device__ __forceinline__ u16 f2b(float f) {
    u32 u = __float_as_uint(f);
    u32 r = (u + 0x7fffu + ((u >> 16) & 1u)) >> 16;
    return (u16)r;
}
__device__ __forceinline__ float b2f(u16 h) {
    return __uint_as_float((u32)h << 16);
}

#define QSCALE 0.17677669529663687f

// ---------------------------------------------------------------------------
// B=2 N=256 C=256 HF=WF=64 ROI=15(225) HID=256 HEADS=8 Dh=32 DEPTH=3 FFN=1024
// NQ=16 -> seqs S=512, MT=8192.
// r18: cross-Q projection fused INTO cross-attn v2 (in-wave 16-MFMA Q' chain;
// deletes 3 GEMM dispatches + Qb buffer); k_prep merged into k_wconv.
// Layout audit: Wm XOR swizzle self-cancels on B-frag reads; all stale-LDS
// positions multiply explicitly-zeroed B operands (QP cols16-31 x Wm cells
// 16-31=0; p_b cols256-263 never read by PW; G re-zeroes QP 16-31 before H).
// ---------------------------------------------------------------------------

// ---------- weights fp32 -> bf16 arena + repack + (tail blocks) prep -------
__global__ LB void k_wconv(const float* __restrict__ s0, const float* __restrict__ s1,
                           const float* __restrict__ s2, const float* __restrict__ s3,
                           const float* __restrict__ s4, const float* __restrict__ s5,
                           const float* __restrict__ s6, u16* __restrict__ dst,
                           const unsigned char* __restrict__ m, int* __restrict__ valid,
                           const float* __restrict__ pb,
                           const float* __restrict__ cqkv_b,
                           float* __restrict__ ckv)
{
    if (blockIdx.x >= 14336) {
        const int pblk = blockIdx.x - 14336;
        if (pblk == 0) {
            __shared__ int flag;
            if (threadIdx.x == 0) flag = 0;
            __syncthreads();
            int loc = 0;
            for (int off = threadIdx.x; off < 512; off += 256)
                if ((off & 3) != 0 && m[off] != 0) loc = 1;
            if (loc) atomicOr(&flag, 1);
            __syncthreads();
            const bool bytelay = (flag != 0);
            for (int s = threadIdx.x; s < 512; s += 256)
                valid[s] = bytelay ? (int)(m[s] != 0) : (int)(((const int*)m)[s] != 0);
        } else {
            const int l = pblk - 1;   // 0..2
            const float* Wv = s3 + (size_t)l * 196608 + 131072;
            const float* vb = cqkv_b + (size_t)l * 768 + 512;
            const int o = threadIdx.x;
            float c = 0.f;
            for (int cc = 0; cc < 256; cc += 4) {
                const float4 p4 = *(const float4*)(pb + cc);
                const float4 v4 = *(const float4*)(Wv + (size_t)o * 256 + cc);
                c += p4.x * v4.x + p4.y * v4.y + p4.z * v4.z + p4.w * v4.w;
            }
            ckv[l * 512 + o]       = cqkv_b[(size_t)l * 768 + o];  // bq (fused Q-proj)
            ckv[l * 512 + 256 + o] = c + vb[o];                    // cv (epilogue)
        }
        return;
    }
    const int e = blockIdx.x * 256 + threadIdx.x;
    if (e >= 3670016) return;
    float v;
    int i = e;
    if (i < 65536) v = s0[i];
    else if ((i -= 65536) < 589824) v = s1[i];
    else if ((i -= 589824) < 196608) v = s2[i];
    else if ((i -= 196608) < 589824) v = s3[i];
    else if ((i -= 589824) < 196608) v = s4[i];
    else if ((i -= 196608) < 786432) v = s5[i];
    else if ((i -= 786432) < 786432) v = s6[i];
    else if ((i -= 786432) < 393216) {  // wCKV3: [l][512 rows (Wk|Wv)][256]
        const int l = i / 131072;
        const int r = (i - l * 131072) >> 8;
        const int c = i & 255;
        v = s3[(size_t)l * 196608 + (size_t)(256 + r) * 256 + c];
    } else {                            // projT: [c][o] = proj_w[o][c]
        i -= 393216;
        v = s0[(i & 255) * 256 + (i >> 8)];
    }
    dst[e] = f2b(v);
}

// ---------- transpose image (B,C,64,64) -> (B,4096,C) bf16 -----------------
__global__ LB void k_transpose(const float* __restrict__ img, u16* __restrict__ imgTb)
{
    __shared__ float tile[64][65];
    const int b  = blockIdx.z;
    const int c0 = blockIdx.y * 64;
    const int p0 = blockIdx.x * 64;
    const int t  = threadIdx.x;
    const int tr = t >> 6, tc = t & 63;
#pragma unroll
    for (int p = 0; p < 16; ++p) {
        const int i = p * 4 + tr;
        tile[i][tc] = img[((size_t)(b * 256 + c0 + i)) * 4096 + p0 + tc];
    }
    __syncthreads();
#pragma unroll
    for (int p = 0; p < 16; ++p) {
        const int jj = p * 4 + tr;
        imgTb[((size_t)(b * 4096 + p0 + jj)) * 256 + c0 + tc] = f2b(tile[tc][jj]);
    }
}

// ---------- bf16 MFMA GEMM: C[M,N] = A[M,K](bf16) @ W[N,K](bf16)^T + bias --
template<int BM>
__global__ LB void gemm_mfma(const u16* __restrict__ A, const u16* __restrict__ W,
                             const float* __restrict__ bias,
                             float* __restrict__ Cf, u16* __restrict__ Cb,
                             int M, int N, int K, int relu)
{
    constexpr int BN = 128;
    __shared__ u16 lds[2][(BM + BN) * 64];
    const int t = threadIdx.x;
    const int wid = t >> 6, lane = t & 63;
    const int bm = blockIdx.y * BM, bn = blockIdx.x * BN;
    const int KT = K >> 6;

    auto stage = [&](int buf, int kt) {
        const int k0 = kt * 64;
        const int rr = t >> 3;
        const int u  = t & 7;
#pragma unroll
        for (int q = 0; q < BM / 32; ++q) {
            const int r = q * 32 + rr;
            const u16* src = A + (size_t)(bm + r) * K + k0 + ((u ^ (r & 7)) << 3);
            __builtin_amdgcn_global_load_lds(
                (const __attribute__((address_space(1))) void*)src,
                (__attribute__((address_space(3))) void*)&lds[buf][q * 2048 + wid * 512],
                16, 0, 0);
        }
#pragma unroll
        for (int q = 0; q < 4; ++q) {
            const int r = q * 32 + rr;
            const u16* src = W + (size_t)(bn + r) * K + k0 + ((u ^ (r & 7)) << 3);
            __builtin_amdgcn_global_load_lds(
                (const __attribute__((address_space(1))) void*)src,
                (__attribute__((address_space(3))) void*)&lds[buf][BM * 64 + q * 2048 + wid * 512],
                16, 0, 0);
        }
    };

    const int wr = wid >> 1, wc = wid & 1;
    constexpr int MR = BM / 32;
    f32x4 acc[MR][4];
    const f32x4 z = {0.f, 0.f, 0.f, 0.f};
#pragma unroll
    for (int mi = 0; mi < MR; ++mi)
#pragma unroll
        for (int ni = 0; ni < 4; ++ni) acc[mi][ni] = z;

    const int r16 = lane & 15, kg = lane >> 4;

    stage(0, 0);
    int cur = 0;
    for (int kt = 0; kt < KT; ++kt) {
        asm volatile("s_waitcnt vmcnt(0)" ::: "memory");
        __syncthreads();
        if (kt + 1 < KT) stage(cur ^ 1, kt + 1);
        const u16* pA = lds[cur];
        const u16* pB = lds[cur] + BM * 64;
#pragma unroll
        for (int kk = 0; kk < 2; ++kk) {
            const int s = kk * 4 + kg;
            bf16x8 afr[MR], bfr[4];
#pragma unroll
            for (int mi = 0; mi < MR; ++mi) {
                const int r = wr * (BM / 2) + mi * 16 + r16;
                afr[mi] = *(const bf16x8*)(pA + r * 64 + ((s ^ (r & 7)) << 3));
            }
#pragma unroll
            for (int ni = 0; ni < 4; ++ni) {
                const int c = wc * 64 + ni * 16 + r16;
                bfr[ni] = *(const bf16x8*)(pB + c * 64 + ((s ^ (c & 7)) << 3));
            }
#pragma unroll
            for (int mi = 0; mi < MR; ++mi)
#pragma unroll
                for (int ni = 0; ni < 4; ++ni)
                    acc[mi][ni] = __builtin_amdgcn_mfma_f32_16x16x32_bf16(
                        afr[mi], bfr[ni], acc[mi][ni], 0, 0, 0);
        }
        cur ^= 1;
    }

#pragma unroll
    for (int mi = 0; mi < MR; ++mi) {
#pragma unroll
        for (int ni = 0; ni < 4; ++ni) {
            const int col = bn + wc * 64 + ni * 16 + r16;
            const float bs = bias ? bias[col] : 0.0f;
#pragma unroll
            for (int rg = 0; rg < 4; ++rg) {
                const int row = bm + wr * (BM / 2) + mi * 16 + kg * 4 + rg;
                float v = acc[mi][ni][rg] + bs;
                if (relu) v = fmaxf(v, 0.0f);
                if (Cf) Cf[(size_t)row * N + col] = v;
                if (Cb) Cb[(size_t)row * N + col] = f2b(v);
            }
        }
    }
}

// ---------- fused GEMM + residual + LayerNorm (+ optional output head) -----
__global__ LB void gemm_ln(const u16* __restrict__ A, const u16* __restrict__ W,
                           const float* __restrict__ bias,
                           float* __restrict__ tgt, u16* __restrict__ tgtb,
                           const float* __restrict__ lnw, const float* __restrict__ lnb,
                           int K,
                           const float* __restrict__ ow, const float* __restrict__ ob,
                           float* __restrict__ outp)
{
    __shared__ u16 lA[32 * 64];
    __shared__ u16 lB[256 * 64];
    __shared__ float psum[2][32];
    __shared__ float psq[2][32];
    __shared__ float hsum[2][32][4];
    const int t = threadIdx.x;
    const int wid = t >> 6, lane = t & 63;
    const int r16 = lane & 15, kg = lane >> 4;
    const int wr = wid >> 1, wc = wid & 1;
    const int bm = blockIdx.x * 32;
    const int KT = K >> 6;

    f32x4 acc[8];
    const f32x4 z = {0.f, 0.f, 0.f, 0.f};
#pragma unroll
    for (int ni = 0; ni < 8; ++ni) acc[ni] = z;

    for (int kt = 0; kt < KT; ++kt) {
        const int k0 = kt * 64;
        const int rr = t >> 3;
        const int u  = t & 7;
        {
            const int r = rr;
            const u16* src = A + (size_t)(bm + r) * K + k0 + ((u ^ (r & 7)) << 3);
            __builtin_amdgcn_global_load_lds(
                (const __attribute__((address_space(1))) void*)src,
                (__attribute__((address_space(3))) void*)&lA[wid * 512],
                16, 0, 0);
        }
#pragma unroll
        for (int q = 0; q < 8; ++q) {
            const int r = q * 32 + rr;
            const u16* src = W + (size_t)r * K + k0 + ((u ^ (r & 7)) << 3);
            __builtin_amdgcn_global_load_lds(
                (const __attribute__((address_space(1))) void*)src,
                (__attribute__((address_space(3))) void*)&lB[q * 2048 + wid * 512],
                16, 0, 0);
        }
        asm volatile("s_waitcnt vmcnt(0)" ::: "memory");
        __syncthreads();
#pragma unroll
        for (int kk = 0; kk < 2; ++kk) {
            const int s = kk * 4 + kg;
            const int ra = wr * 16 + r16;
            const bf16x8 afr = *(const bf16x8*)(lA + ra * 64 + ((s ^ (ra & 7)) << 3));
#pragma unroll
            for (int ni = 0; ni < 8; ++ni) {
                const int c = wc * 128 + ni * 16 + r16;
                const bf16x8 bfr = *(const bf16x8*)(lB + c * 64 + ((s ^ (c & 7)) << 3));
                acc[ni] = __builtin_amdgcn_mfma_f32_16x16x32_bf16(afr, bfr, acc[ni], 0, 0, 0);
            }
        }
        __syncthreads();
    }

    float xv[4][8];
    float bcol[8], wcol[8], bncol[8];
#pragma unroll
    for (int ni = 0; ni < 8; ++ni) {
        const int c = wc * 128 + ni * 16 + r16;
        bcol[ni]  = bias[c];
        wcol[ni]  = lnw[c];
        bncol[ni] = lnb[c];
    }
#pragma unroll
    for (int rg = 0; rg < 4; ++rg) {
        const int row = bm + wr * 16 + kg * 4 + rg;
#pragma unroll
        for (int ni = 0; ni < 8; ++ni) {
            const int c = wc * 128 + ni * 16 + r16;
            xv[rg][ni] = tgt[(size_t)row * 256 + c] + acc[ni][rg] + bcol[ni];
        }
    }
#pragma unroll
    for (int rg = 0; rg < 4; ++rg) {
        float s = 0.f;
#pragma unroll
        for (int ni = 0; ni < 8; ++ni) s += xv[rg][ni];
#pragma unroll
        for (int m = 1; m < 16; m <<= 1) s += __shfl_xor(s, m);
        if (r16 == 0) psum[wc][wr * 16 + kg * 4 + rg] = s;
    }
    __syncthreads();
    float mu[4];
#pragma unroll
    for (int rg = 0; rg < 4; ++rg) {
        const int rl = wr * 16 + kg * 4 + rg;
        mu[rg] = (psum[0][rl] + psum[1][rl]) * (1.0f / 256.0f);
    }
#pragma unroll
    for (int rg = 0; rg < 4; ++rg) {
        float q = 0.f;
#pragma unroll
        for (int ni = 0; ni < 8; ++ni) {
            const float d = xv[rg][ni] - mu[rg];
            q += d * d;
        }
#pragma unroll
        for (int m = 1; m < 16; m <<= 1) q += __shfl_xor(q, m);
        if (r16 == 0) psq[wc][wr * 16 + kg * 4 + rg] = q;
    }
    __syncthreads();
    float onorm[4][8];
#pragma unroll
    for (int rg = 0; rg < 4; ++rg) {
        const int rl = wr * 16 + kg * 4 + rg;
        const int row = bm + rl;
        const float var = (psq[0][rl] + psq[1][rl]) * (1.0f / 256.0f);
        const float inv = 1.0f / sqrtf(var + 1e-5f);
#pragma unroll
        for (int ni = 0; ni < 8; ++ni) {
            const int c = wc * 128 + ni * 16 + r16;
            const float o = (xv[rg][ni] - mu[rg]) * inv * wcol[ni] + bncol[ni];
            onorm[rg][ni] = o;
            tgt[(size_t)row * 256 + c]  = o;
            tgtb[(size_t)row * 256 + c] = f2b(o);
        }
    }

    if (outp) {
#pragma unroll
        for (int j = 0; j < 4; ++j) {
            float wj[8];
#pragma unroll
            for (int ni = 0; ni < 8; ++ni)
                wj[ni] = ow[j * 256 + wc * 128 + ni * 16 + r16];
#pragma unroll
            for (int rg = 0; rg < 4; ++rg) {
                float p = 0.f;
#pragma unroll
                for (int ni = 0; ni < 8; ++ni) p += onorm[rg][ni] * wj[ni];
#pragma unroll
                for (int m = 1; m < 16; m <<= 1) p += __shfl_xor(p, m);
                if (r16 == 0) hsum[wc][wr * 16 + kg * 4 + rg][j] = p;
            }
        }
        __syncthreads();
        if (t < 128) {
            const int row = t >> 2, j = t & 3;
            outp[(size_t)(bm + row) * 4 + j] =
                hsum[0][row][j] + hsum[1][row][j] + ob[j];
        }
    }
}

// ---------- init tgt (fp32 + bf16) -----------------------------------------
__global__ LB void k_init_tgt(float* __restrict__ tgt, u16* __restrict__ tgtb,
                              const float* __restrict__ qe)
{
    const int e = blockIdx.x * 256 + threadIdx.x;
    const int c = e & 255;
    const int row = e >> 8;
    const int i = row & 15;
    const float v = qe[(i << 8) | c];
    tgt[e] = v;
    tgtb[e] = f2b(v);
}

// ---------- self attention v2: wave-per-head, in-wave MFMA chain -----------
__global__ LB void k_self_attn(const u16* __restrict__ QKV, u16* __restrict__ O)
{
    __shared__ __align__(16) u16 arena[4][1536];   // per wave: p_lds[16][32] | vT[32][32]
    const int t = threadIdx.x;
    const int lane = t & 63, wid = t >> 6;
    const int r16 = lane & 15, kg = lane >> 4;
    const int blk = blockIdx.x;
    const int s = blk >> 1;
    const int h = (blk & 1) * 4 + wid;

    u16* p_lds = &arena[wid][0];
    u16* vT    = &arena[wid][512];

    const bf16x8 qfr = *(const bf16x8*)(QKV + (size_t)(s * 16 + r16) * 768 + h * 32 + kg * 8);
    const bf16x8 kfr = *(const bf16x8*)(QKV + (size_t)(s * 16 + r16) * 768 + 256 + h * 32 + kg * 8);
    f32x4 sv = {0.f, 0.f, 0.f, 0.f};
    sv = __builtin_amdgcn_mfma_f32_16x16x32_bf16(qfr, kfr, sv, 0, 0, 0);

    float ev[4], rowsum[4];
#pragma unroll
    for (int rg = 0; rg < 4; ++rg) ev[rg] = sv[rg] * QSCALE;
#pragma unroll
    for (int rg = 0; rg < 4; ++rg) {
        float mx = ev[rg];
#pragma unroll
        for (int m = 1; m < 16; m <<= 1) mx = fmaxf(mx, __shfl_xor(mx, m));
        ev[rg] = __expf(ev[rg] - mx);
        float ps = ev[rg];
#pragma unroll
        for (int m = 1; m < 16; m <<= 1) ps += __shfl_xor(ps, m);
        rowsum[rg] = ps;
    }

#pragma unroll
    for (int rg = 0; rg < 4; ++rg)
        p_lds[(kg * 4 + rg) * 32 + r16] = f2b(ev[rg]);
    {
        const int zq = lane & 15, zc = 16 + (lane >> 4) * 4;
#pragma unroll
        for (int j = 0; j < 4; ++j) p_lds[zq * 32 + zc + j] = 0;
    }
    {
        const int key = lane >> 2, ch8 = (lane & 3) * 8;
        const u16x8 v = *(const u16x8*)(QKV + (size_t)(s * 16 + key) * 768 + 512 + h * 32 + ch8);
#pragma unroll
        for (int j = 0; j < 8; ++j)
            vT[(ch8 + j) * 32 + key] = ((const u16*)&v)[j];
        const int zc0 = lane >> 1, zk0 = 16 + (lane & 1) * 8;
#pragma unroll
        for (int j = 0; j < 8; ++j) vT[zc0 * 32 + zk0 + j] = 0;
    }

#pragma unroll
    for (int ct = 0; ct < 2; ++ct) {
        const bf16x8 pa = *(const bf16x8*)(p_lds + r16 * 32 + kg * 8);
        const bf16x8 vb = *(const bf16x8*)(vT + (ct * 16 + r16) * 32 + kg * 8);
        f32x4 ao = {0.f, 0.f, 0.f, 0.f};
        ao = __builtin_amdgcn_mfma_f32_16x16x32_bf16(pa, vb, ao, 0, 0, 0);
#pragma unroll
        for (int rg = 0; rg < 4; ++rg) {
            const int q = kg * 4 + rg;
            O[(size_t)(s * 16 + q) * 256 + h * 32 + ct * 16 + r16] = f2b(ao[rg] / rowsum[rg]);
        }
    }
}

// ---------- cross attention v3: fused Q-proj + wave-per-head chain ---------
// tgtb bf16 [8192][256]; wQ [256][256] bf16 (this layer's Q rows);
// KV bf16 [B*4096][kvs]; ckv[0:256]=bq, ckv[256:512]=cv.
__global__ LB void k_cross_attn(const u16* __restrict__ tgtb,
                                const u16* __restrict__ wQ,
                                const u16* __restrict__ KV, int kvs,
                                const float* __restrict__ ckv,
                                const int* __restrict__ valid,
                                const float* __restrict__ kps,
                                u16* __restrict__ O)
{
    __shared__ __align__(16) char arena[64832];
    u16* Wm  = (u16*)arena;
    u16* WmT = (u16*)(arena + 14400);

    const int t = threadIdx.x;
    const int lane = t & 63, wid = t >> 6;
    const int r16 = lane & 15, kg = lane >> 4;
    const int blk = blockIdx.x;
    const int s = blk >> 1;
    const int h = (blk & 1) * 4 + wid;
    const int b = s >> 8, n = s & 255;

    u16* buf = (u16*)(arena + 22848 + wid * 10496);           // [32][32]
    u16* p_b = (u16*)(arena + 22848 + wid * 10496 + 2048);    // [16][264]
    u16* QP  = p_b;                                            // [16][40] overlay

    for (int e = t; e < 16208; e += 256) ((u32*)arena)[e] = 0;
    __syncthreads();

    const float kpy = kps[(b * 256 + n) * 2 + 0];
    const float kpx = kps[(b * 256 + n) * 2 + 1];
    const float gx0 = rintf(kpx) - 7.0f;
    const float gy0 = rintf(kpy) - 7.0f;
    const float gxn0 = gx0 / 511.0f * 2.0f - 1.0f;
    const float gyn0 = gy0 / 511.0f * 2.0f - 1.0f;
    const float xb = ((gxn0 + 1.f) * 64.f - 1.f) * 0.5f;
    const float yb = ((gyn0 + 1.f) * 64.f - 1.f) * 0.5f;
    const int x0b = (int)floorf(xb);
    const int y0b = (int)floorf(yb);

    // ---- phase 1: W build (t<225) ∥ per-wave fused Q-proj + Tk load -------
    if (t < 225) {
        const int iy = t / 15, ix = t - iy * 15;
        const float gy = rintf(kpy) + (float)(iy - 7);
        const float gx = rintf(kpx) + (float)(ix - 7);
        const float gxn = gx / 511.0f * 2.0f - 1.0f;
        const float gyn = gy / 511.0f * 2.0f - 1.0f;
        const bool inval = (gxn < -1.f) || (gyn < -1.f) || (gxn > 1.f) || (gyn > 1.f);
        const float x = ((gxn + 1.f) * 64.f - 1.f) * 0.5f;
        const float y = ((gyn + 1.f) * 64.f - 1.f) * 0.5f;
        const float x0f = floorf(x), y0f = floorf(y);
        const float wx = x - x0f, wy = y - y0f;
        const int x0 = (int)x0f, y0 = (int)y0f;
#pragma unroll
        for (int tt = 0; tt < 4; ++tt) {
            const int dy = tt >> 1, dx = tt & 1;
            const int yi = y0 + dy, xi = x0 + dx;
            const bool ok = (yi >= 0) && (yi < 64) && (xi >= 0) && (xi < 64) && !inval;
            const float w = (dy ? wy : 1.f - wy) * (dx ? wx : 1.f - wx);
            if (ok) {
                const int cell = (yi - y0b) * 4 + (xi - x0b);
                const u16 wb = f2b(w);
                Wm[t * 32 + ((((cell >> 3) ^ (t & 3)) << 3) | (cell & 7))] = wb;
                WmT[cell * 264 + t] = wb;
            }
        }
    }
    // fused Q-proj: Q'[16 q][32 ch] = tgt[16,256] @ wQ_h^T + bq  (16 MFMA)
#pragma unroll
    for (int ct = 0; ct < 2; ++ct) {
        f32x4 aq = {0.f, 0.f, 0.f, 0.f};
#pragma unroll
        for (int ks = 0; ks < 8; ++ks) {
            const bf16x8 ta = *(const bf16x8*)(tgtb + (size_t)(s * 16 + r16) * 256 + ks * 32 + kg * 8);
            const bf16x8 wb = *(const bf16x8*)(wQ + (size_t)(h * 32 + ct * 16 + r16) * 256 + ks * 32 + kg * 8);
            aq = __builtin_amdgcn_mfma_f32_16x16x32_bf16(ta, wb, aq, 0, 0, 0);
        }
        const float bq = ckv[h * 32 + ct * 16 + r16];
#pragma unroll
        for (int rg = 0; rg < 4; ++rg)
            QP[(kg * 4 + rg) * 40 + ct * 16 + r16] = f2b(aq[rg] + bq);
    }
    // Tk load (wave-local)
    const int cell = lane >> 2, ch8 = (lane & 3) * 8;
    const int cy = cell >> 2, cx = cell & 3;
    const int py = min(max(y0b + cy, 0), 63);
    const int px = min(max(x0b + cx, 0), 63);
    const size_t texidx = (size_t)(b * 4096 + py * 64 + px) * kvs + h * 32 + ch8;
    *(u16x8*)(buf + cell * 32 + ch8) = *(const u16x8*)(KV + texidx);
    const bool vld = valid[s] != 0;
    __syncthreads();

    // A) QT = Q' @ Tk (1 MFMA): reads QP cols 0-31, writes QP cols 0-15
    {
        const bf16x8 qfr = *(const bf16x8*)(QP + r16 * 40 + kg * 8);
        const bf16x8 tfr = *(const bf16x8*)(buf + r16 * 32 + kg * 8);
        f32x4 aq = {0.f, 0.f, 0.f, 0.f};
        aq = __builtin_amdgcn_mfma_f32_16x16x32_bf16(qfr, tfr, aq, 0, 0, 0);
#pragma unroll
        for (int rg = 0; rg < 4; ++rg)
            QP[(kg * 4 + rg) * 40 + r16] = f2b(aq[rg]);
    }

    // B) S = QT @ Wm^T (stale QP cols 16-31 x zeroed Wm cells 16-31 = safe)
    float ev[4][15];
    {
        const bf16x8 afr = *(const bf16x8*)(QP + r16 * 40 + kg * 8);
#pragma unroll
        for (int tile = 0; tile < 15; ++tile) {
            const int p = tile * 16 + r16;
            const int rc = p < 225 ? p : 224;
            const bf16x8 bfr = *(const bf16x8*)(Wm + rc * 32 + ((kg ^ (rc & 3)) << 3));
            f32x4 acc = {0.f, 0.f, 0.f, 0.f};
            acc = __builtin_amdgcn_mfma_f32_16x16x32_bf16(afr, bfr, acc, 0, 0, 0);
#pragma unroll
            for (int rg = 0; rg < 4; ++rg) {
                float sv = acc[rg] * QSCALE;
                if (p > 224) sv = -1e30f;
                if (!vld && p > 0) sv = -1e30f;
                ev[rg][tile] = sv;
            }
        }
    }
    float rowsumv[4];
#pragma unroll
    for (int rg = 0; rg < 4; ++rg) {
        float mx = -1e30f;
#pragma unroll
        for (int k = 0; k < 15; ++k) mx = fmaxf(mx, ev[rg][k]);
#pragma unroll
        for (int m = 1; m < 16; m <<= 1) mx = fmaxf(mx, __shfl_xor(mx, m));
        float ps = 0.f;
#pragma unroll
        for (int k = 0; k < 15; ++k) {
            ev[rg][k] = __expf(ev[rg][k] - mx);
            ps += ev[rg][k];
        }
#pragma unroll
        for (int m = 1; m < 16; m <<= 1) ps += __shfl_xor(ps, m);
        rowsumv[rg] = ps;
    }

    // D) P -> p_b; re-zero pad cols 225-255 (cols 256-263 never read by PW)
#pragma unroll
    for (int rg = 0; rg < 4; ++rg)
#pragma unroll
        for (int k = 0; k < 15; ++k) {
            const int p = k * 16 + r16;
            if (p < 225) p_b[(kg * 4 + rg) * 264 + p] = f2b(ev[rg][k]);
        }
    for (int e = lane; e < 496; e += 64) {
        const int row = e / 31;
        p_b[row * 264 + 225 + (e - row * 31)] = 0;
    }

    // E) TvT into buf (overwrite Tk; zero leftover cols)
    {
        const u16x8 v = *(const u16x8*)(KV + texidx + 256);
#pragma unroll
        for (int j = 0; j < 8; ++j)
            buf[(ch8 + j) * 32 + cell] = ((const u16*)&v)[j];
        const int zr = lane & 15, zc0 = 16 + (lane >> 4) * 4;
#pragma unroll
        for (int j = 0; j < 4; ++j) buf[zr * 32 + zc0 + j] = 0;
    }

    // F) PW = P @ W (8-chain)
    f32x4 pw = {0.f, 0.f, 0.f, 0.f};
#pragma unroll
    for (int ks = 0; ks < 8; ++ks) {
        const bf16x8 pa = *(const bf16x8*)(p_b + r16 * 264 + ks * 32 + kg * 8);
        const bf16x8 wb = *(const bf16x8*)(WmT + r16 * 264 + ks * 32 + kg * 8);
        pw = __builtin_amdgcn_mfma_f32_16x16x32_bf16(pa, wb, pw, 0, 0, 0);
    }

    // G) PW -> QP; re-zero cols 16-31 (held P data)
#pragma unroll
    for (int rg = 0; rg < 4; ++rg)
        QP[(kg * 4 + rg) * 40 + r16] = f2b(pw[rg]);
    {
        const int zq = lane & 15, zc0 = 16 + (lane >> 4) * 4;
#pragma unroll
        for (int j = 0; j < 4; ++j) QP[zq * 40 + zc0 + j] = 0;
    }

    // H) O = PW @ Tv^T ; I) /rowsum + cv, write
#pragma unroll
    for (int ct = 0; ct < 2; ++ct) {
        const bf16x8 pa = *(const bf16x8*)(QP + r16 * 40 + kg * 8);
        const bf16x8 vb = *(const bf16x8*)(buf + (ct * 16 + r16) * 32 + kg * 8);
        f32x4 ao = {0.f, 0.f, 0.f, 0.f};
        ao = __builtin_amdgcn_mfma_f32_16x16x32_bf16(pa, vb, ao, 0, 0, 0);
#pragma unroll
        for (int rg = 0; rg < 4; ++rg) {
            const int q = kg * 4 + rg;
            const int ch = h * 32 + ct * 16 + r16;
            const float val = ao[rg] / rowsumv[rg] + ckv[256 + ch];
            O[(size_t)(s * 16 + q) * 256 + ch] = f2b(val);
        }
    }
}

// ---------------------------------------------------------------------------
extern "C" void kernel_launch(void* const* d_in, const int* in_sizes, int n_in,
                              void* d_out, int out_size, void* d_ws, size_t ws_size,
                              hipStream_t stream)
{
    const float* img          = (const float*)d_in[0];
    const float* kps          = (const float*)d_in[1];
    const unsigned char* vmsk = (const unsigned char*)d_in[2];
    const float* proj_w       = (const float*)d_in[3];
    const float* proj_b       = (const float*)d_in[4];
    const float* query_embed  = (const float*)d_in[5];
    const float* self_qkv_w   = (const float*)d_in[6];
    const float* self_qkv_b   = (const float*)d_in[7];
    const float* self_out_w   = (const float*)d_in[8];
    const float* self_out_b   = (const float*)d_in[9];
    const float* cross_qkv_w  = (const float*)d_in[10];
    const float* cross_qkv_b  = (const float*)d_in[11];
    const float* cross_out_w  = (const float*)d_in[12];
    const float* cross_out_b  = (const float*)d_in[13];
    const float* ffn1_w       = (const float*)d_in[14];
    const float* ffn1_b       = (const float*)d_in[15];
    const float* ffn2_w       = (const float*)d_in[16];
    const float* ffn2_b       = (const float*)d_in[17];
    const float* ln1_w        = (const float*)d_in[18];
    const float* ln1_b        = (const float*)d_in[19];
    const float* ln2_w        = (const float*)d_in[20];
    const float* ln2_b        = (const float*)d_in[21];
    const float* ln3_w        = (const float*)d_in[22];
    const float* ln3_b        = (const float*)d_in[23];
    const float* out_w        = (const float*)d_in[24];
    const float* out_b        = (const float*)d_in[25];
    float* out = (float*)d_out;

    // ---- workspace layout (~80 MB) ----
    char* W8 = (char*)d_ws;
    size_t off = 0;
    auto alloc = [&](size_t bytes) { void* p = W8 + off; off += (bytes + 255) & ~(size_t)255; return p; };
    float* tgt   = (float*)alloc(2097152 * 4);
    u16* Sb16    = (u16*)alloc(6291456 * 2);     // self-QKV bf16 [8192][768]
    float* ckv   = (float*)alloc(3 * 512 * 4);
    u16* imgTb   = (u16*)alloc(2097152 * 2);
    u16* KVb3    = (u16*)alloc(12582912 * 2);    // [8192][1536] all 3 layers K|V
    u16* tgtb    = (u16*)alloc(2097152 * 2);
    u16* Abuf    = (u16*)alloc(2097152 * 2);
    u16* Hbuf    = (u16*)alloc(8388608 * 2);
    u16* wAll    = (u16*)alloc(3670016 * 2);
    u16* WcombB  = (u16*)alloc(393216 * 2);      // (wCKV3 @ proj) weights
    int* valid   = (int*)alloc(512 * 4);

    u16* wProj  = wAll;             // 65536 (layout keeper)
    u16* wSQKV  = wProj + 65536;    // 3*768*256
    u16* wSOut  = wSQKV + 589824;   // 3*256*256
    u16* wCQKV  = wSOut + 196608;   // 3*768*256 (rows 0-255 of each layer = Wq)
    u16* wCOut  = wCQKV + 589824;   // 3*256*256
    u16* wF1    = wCOut + 196608;   // 3*1024*256
    u16* wF2    = wF1 + 786432;     // 3*256*1024
    u16* wCKV3  = wF2 + 786432;     // 3*512*256 cross K|V weights
    u16* wProjT = wCKV3 + 393216;   // 256*256 proj^T

    k_wconv<<<14340, 256, 0, stream>>>(proj_w, self_qkv_w, self_out_w, cross_qkv_w,
                                       cross_out_w, ffn1_w, ffn2_w, wAll,
                                       vmsk, valid, proj_b, cross_qkv_b, ckv);
    k_transpose<<<dim3(64, 4, 2), 256, 0, stream>>>(img, imgTb);
    gemm_mfma<64><<<dim3(2, 24), 256, 0, stream>>>(wCKV3, wProjT, nullptr,
                                                   nullptr, WcombB, 1536, 256, 256, 0);
    gemm_mfma<128><<<dim3(12, 64), 256, 0, stream>>>(imgTb, WcombB, nullptr,
                                                     nullptr, KVb3, 8192, 1536, 256, 0);
    k_init_tgt<<<8192, 256, 0, stream>>>(tgt, tgtb, query_embed);

    for (int l = 0; l < 3; ++l) {
        const int last = (l == 2);
        // ---- self attention ----
        gemm_mfma<64><<<dim3(6, 128), 256, 0, stream>>>(tgtb, wSQKV + (size_t)l * 196608,
            self_qkv_b + (size_t)l * 768, nullptr, Sb16, 8192, 768, 256, 0);
        k_self_attn<<<1024, 256, 0, stream>>>(Sb16, Abuf);
        gemm_ln<<<256, 256, 0, stream>>>(Abuf, wSOut + (size_t)l * 65536,
            self_out_b + (size_t)l * 256, tgt, tgtb,
            ln1_w + (size_t)l * 256, ln1_b + (size_t)l * 256, 256,
            nullptr, nullptr, nullptr);

        // ---- cross attention (Q-proj fused in-wave) ----
        k_cross_attn<<<1024, 256, 0, stream>>>(tgtb, wCQKV + (size_t)l * 196608,
                                               KVb3 + (size_t)l * 512, 1536,
                                               ckv + (size_t)l * 512, valid, kps, Abuf);
        gemm_ln<<<256, 256, 0, stream>>>(Abuf, wCOut + (size_t)l * 65536,
            cross_out_b + (size_t)l * 256, tgt, tgtb,
            ln2_w + (size_t)l * 256, ln2_b + (size_t)l * 256, 256,
            nullptr, nullptr, nullptr);

        // ---- FFN (final layer fuses the output head) ----
        gemm_mfma<64><<<dim3(8, 128), 256, 0, stream>>>(tgtb, wF1 + (size_t)l * 262144,
            ffn1_b + (size_t)l * 1024, nullptr, Hbuf, 8192, 1024, 256, 1);
        gemm_ln<<<256, 256, 0, stream>>>(Hbuf, wF2 + (size_t)l * 262144,
            ffn2_b + (size_t)l * 256, tgt, tgtb,
            ln3_w + (size_t)l * 256, ln3_b + (size_t)l * 256, 1024,
            last ? out_w : nullptr, last ? out_b : nullptr, last ? out : nullptr);
    }
}